// Round 5
// baseline (42817.169 us; speedup 1.0000x reference)
//
#include <hip/hip_runtime.h>
#include <math.h>

constexpr int cB = 64, cT = 600, cD = 512, cE = 640, cH = 1024, cA = 1024,
              cP = 1024, cV = 10025, cN = 64;
constexpr int cBT = cB * cT;       // 38400
constexpr int cKr = cH + cE + cD;  // 2176
constexpr int cM  = cB * cN;       // 4096
constexpr int cVp = 10112;         // V padded to 79*128
constexpr int cG3 = 3 * cH;        // 3072 (i,g,o)
constexpr int cGRID = 512;         // loop grid: 2 blocks/CU x 256 CUs, all co-resident

typedef __attribute__((ext_vector_type(8))) short bf16x8;
typedef __attribute__((ext_vector_type(4))) float f32x4;

__device__ __forceinline__ float bfu(unsigned short s) {
  return __uint_as_float(((unsigned int)s) << 16);
}
__device__ __forceinline__ unsigned short f2bf(float f) {
  unsigned int x = __float_as_uint(f);
  x += 0x7fffu + ((x >> 16) & 1u);
  return (unsigned short)(x >> 16);
}
__device__ __forceinline__ float fsig(float x) { return 1.0f / (1.0f + __expf(-x)); }
__device__ __forceinline__ float ftanh(float x) {
  float e = __expf(2.0f * x);
  return 1.0f - 2.0f / (e + 1.0f);
}

#define GLD(g, s)                                                          \
  __builtin_amdgcn_global_load_lds(                                       \
      (const __attribute__((address_space(1))) void*)(g),                 \
      (__attribute__((address_space(3))) void*)(s), 16, 0, 0)

__device__ __forceinline__ int xcd_swizzle(int bid, int nwg) {
  int q = nwg >> 3, r = nwg & 7;
  int x = bid & 7, loc = bid >> 3;
  return (x < r ? x * (q + 1) : r * (q + 1) + (x - r) * q) + loc;
}

// Hand-rolled device-wide barrier: agent-scope fence + atomic counter.
// Per MI355X_MICROARCH "Correctness boundaries": per-XCD L2s are non-coherent;
// cross-workgroup communication requires device-scope atomics/fences.
__device__ __forceinline__ void gridbar(unsigned* bar, unsigned target) {
  __threadfence();   // release this block's writes at agent scope
  __syncthreads();
  if (threadIdx.x == 0) {
    __hip_atomic_fetch_add(bar, 1u, __ATOMIC_ACQ_REL, __HIP_MEMORY_SCOPE_AGENT);
    while (__hip_atomic_load(bar, __ATOMIC_ACQUIRE, __HIP_MEMORY_SCOPE_AGENT) < target) {
      __builtin_amdgcn_s_sleep(8);
    }
  }
  __syncthreads();
  __threadfence();   // acquire side
}

// ---------------- precompute / casts ----------------

__global__ __launch_bounds__(256) void cast_kernel(const float* __restrict__ in,
                                                   unsigned short* __restrict__ out) {
  int i = blockIdx.x * 256 + threadIdx.x;
  float4 v = reinterpret_cast<const float4*>(in)[i];
  ushort4 o;
  o.x = f2bf(v.x); o.y = f2bf(v.y); o.z = f2bf(v.z); o.w = f2bf(v.w);
  reinterpret_cast<ushort4*>(out)[i] = o;
}

__global__ __launch_bounds__(256) void cast_hl_kernel(const float* __restrict__ in,
                                                      unsigned short* __restrict__ hi,
                                                      unsigned short* __restrict__ lo) {
  int i = blockIdx.x * 256 + threadIdx.x;
  float4 v = reinterpret_cast<const float4*>(in)[i];
  ushort4 h, l;
  h.x = f2bf(v.x); h.y = f2bf(v.y); h.z = f2bf(v.z); h.w = f2bf(v.w);
  l.x = f2bf(v.x - bfu(h.x)); l.y = f2bf(v.y - bfu(h.y));
  l.z = f2bf(v.z - bfu(h.z)); l.w = f2bf(v.w - bfu(h.w));
  reinterpret_cast<ushort4*>(hi)[i] = h;
  reinterpret_cast<ushort4*>(lo)[i] = l;
}

__global__ __launch_bounds__(256) void cast_wo_kernel(const float* __restrict__ in,
                                                      unsigned short* __restrict__ hi,
                                                      unsigned short* __restrict__ lo) {
  int idx = blockIdx.x * 256 + threadIdx.x;
  int row = idx >> 7;
  int k = (idx & 127) * 4;
  float4 v = (row < cV) ? *reinterpret_cast<const float4*>(&in[(size_t)row * cD + k])
                        : make_float4(0.f, 0.f, 0.f, 0.f);
  ushort4 h, l;
  h.x = f2bf(v.x); h.y = f2bf(v.y); h.z = f2bf(v.z); h.w = f2bf(v.w);
  l.x = f2bf(v.x - bfu(h.x)); l.y = f2bf(v.y - bfu(h.y));
  l.z = f2bf(v.z - bfu(h.z)); l.w = f2bf(v.w - bfu(h.w));
  reinterpret_cast<ushort4*>(hi)[idx] = h;
  reinterpret_cast<ushort4*>(lo)[idx] = l;
}

__global__ __launch_bounds__(256) void fert_kernel(const float* __restrict__ enc,
                                                   const float* __restrict__ W_fert,
                                                   float* __restrict__ inv_fert) {
  int wave = threadIdx.x >> 6, lane = threadIdx.x & 63;
  int row = blockIdx.x * 4 + wave;
  const float* r = enc + (size_t)row * cD;
  float s = 0.0f;
#pragma unroll
  for (int i = 0; i < 8; ++i) s += r[lane + 64 * i] * W_fert[lane + 64 * i];
#pragma unroll
  for (int o = 32; o; o >>= 1) s += __shfl_xor(s, o);
  if (lane == 0) inv_fert[row] = 1.0f / (1.0f + __expf(-s));
}

// shifted embeddings of labels -> hi/lo bf16 [4096][640]
__global__ __launch_bounds__(256) void build_aemb(const float* __restrict__ embed,
                                                  const int* __restrict__ labels,
                                                  unsigned short* __restrict__ Ah,
                                                  unsigned short* __restrict__ Al) {
  int idx = blockIdx.x * 256 + threadIdx.x;  // per 4 elems
  int row = idx / (cE / 4);
  int k = (idx % (cE / 4)) * 4;
  int b = row >> 6, tt = row & 63;
  float4 v = make_float4(0.f, 0.f, 0.f, 0.f);
  if (tt > 0) {
    int lab = labels[b * cN + tt - 1];
    v = *reinterpret_cast<const float4*>(&embed[(size_t)lab * cE + k]);
  }
  ushort4 h, l;
  h.x = f2bf(v.x); h.y = f2bf(v.y); h.z = f2bf(v.z); h.w = f2bf(v.w);
  l.x = f2bf(v.x - bfu(h.x)); l.y = f2bf(v.y - bfu(h.y));
  l.z = f2bf(v.z - bfu(h.z)); l.w = f2bf(v.w - bfu(h.w));
  *reinterpret_cast<ushort4*>(&Ah[(size_t)row * cE + k]) = h;
  *reinterpret_cast<ushort4*>(&Al[(size_t)row * cE + k]) = l;
}

// W_ih rows (i,g,o) x cols [0,640) -> hi/lo bf16 [3072][640]
__global__ __launch_bounds__(256) void cast_wihe(const float* __restrict__ W_ih,
                                                 unsigned short* __restrict__ Wh,
                                                 unsigned short* __restrict__ Wl) {
  int idx = blockIdx.x * 256 + threadIdx.x;
  int jcol = idx / (cE / 4);
  int k = (idx % (cE / 4)) * 4;
  int r = (jcol < cH) ? jcol : jcol + cH;  // i: rows 0..1023; g: 2048..; o: 3072..
  float4 v = *reinterpret_cast<const float4*>(&W_ih[(size_t)r * (cE + cD) + k]);
  ushort4 h, l;
  h.x = f2bf(v.x); h.y = f2bf(v.y); h.z = f2bf(v.z); h.w = f2bf(v.w);
  l.x = f2bf(v.x - bfu(h.x)); l.y = f2bf(v.y - bfu(h.y));
  l.z = f2bf(v.z - bfu(h.z)); l.w = f2bf(v.w - bfu(h.w));
  *reinterpret_cast<ushort4*>(&Wh[(size_t)jcol * cE + k]) = h;
  *reinterpret_cast<ushort4*>(&Wl[(size_t)jcol * cE + k]) = l;
}

// concat(sT-gather, emb, ctx_seq) -> Ar hi/lo bf16 [4096][2176]
__global__ __launch_bounds__(256) void build_ar_kernel(
    const float* __restrict__ s_seqT, const float* __restrict__ ctx_seq,
    const float* __restrict__ embed, const int* __restrict__ labels,
    unsigned short* __restrict__ Ah, unsigned short* __restrict__ Al) {
  int idx = blockIdx.x * 256 + threadIdx.x;
  int row = idx / (cKr / 4);
  int k = (idx % (cKr / 4)) * 4;
  int b = row >> 6, tt = row & 63;
  float4 v;
  if (k < cH) {
    v.x = s_seqT[((size_t)tt * cH + k + 0) * cB + b];
    v.y = s_seqT[((size_t)tt * cH + k + 1) * cB + b];
    v.z = s_seqT[((size_t)tt * cH + k + 2) * cB + b];
    v.w = s_seqT[((size_t)tt * cH + k + 3) * cB + b];
  } else if (k < cH + cE) {
    if (tt == 0) {
      v = make_float4(0.f, 0.f, 0.f, 0.f);
    } else {
      int lab = labels[b * cN + tt - 1];
      v = *reinterpret_cast<const float4*>(&embed[(size_t)lab * cE + (k - cH)]);
    }
  } else {
    v = *reinterpret_cast<const float4*>(&ctx_seq[(size_t)row * cD + (k - cH - cE)]);
  }
  ushort4 h, l;
  h.x = f2bf(v.x); h.y = f2bf(v.y); h.z = f2bf(v.z); h.w = f2bf(v.w);
  l.x = f2bf(v.x - bfu(h.x)); l.y = f2bf(v.y - bfu(h.y));
  l.z = f2bf(v.z - bfu(h.z)); l.w = f2bf(v.w - bfu(h.w));
  *reinterpret_cast<ushort4*>(&Ah[(size_t)row * cKr + k]) = h;
  *reinterpret_cast<ushort4*>(&Al[(size_t)row * cKr + k]) = l;
}

// ---------------- MFMA GEMMs ----------------

// enc_ctx = enc_bf @ W_enc_bf^T + b_enc  -> bf16 [38400][1024]
__global__ __launch_bounds__(256) void mfma_encctx(const unsigned short* __restrict__ A,
                                                   const unsigned short* __restrict__ Bm,
                                                   const float* __restrict__ bias,
                                                   unsigned short* __restrict__ C) {
  __shared__ unsigned short sA[4096], sB[4096];
  constexpr int nbx = cA / 128;
  int bid = xcd_swizzle(blockIdx.x, gridDim.x);
  int by = bid / nbx, bx = bid % nbx;
  int tid = threadIdx.x;
  int w = tid >> 6, l = tid & 63;
  int m0 = by * 128, n0 = bx * 128;
  int wr = w >> 1, wc = w & 1;
  f32x4 acc[4][4] = {};
  int srow = tid >> 2, scol = (tid & 3) * 8;
  for (int k0 = 0; k0 < cD; k0 += 32) {
    __syncthreads();
    GLD(&A[(size_t)(m0 + srow) * cD + k0 + scol], &sA[tid * 8]);
    GLD(&A[(size_t)(m0 + 64 + srow) * cD + k0 + scol], &sA[2048 + tid * 8]);
    GLD(&Bm[(size_t)(n0 + srow) * cD + k0 + scol], &sB[tid * 8]);
    GLD(&Bm[(size_t)(n0 + 64 + srow) * cD + k0 + scol], &sB[2048 + tid * 8]);
    __syncthreads();
    int rA = wr * 64 + (l & 15);
    int rB = wc * 64 + (l & 15);
    int kg = (l >> 4) * 8;
    bf16x8 a[4], b[4];
#pragma unroll
    for (int i = 0; i < 4; ++i) a[i] = *(const bf16x8*)&sA[(rA + i * 16) * 32 + kg];
#pragma unroll
    for (int j = 0; j < 4; ++j) b[j] = *(const bf16x8*)&sB[(rB + j * 16) * 32 + kg];
#pragma unroll
    for (int i = 0; i < 4; ++i)
#pragma unroll
      for (int j = 0; j < 4; ++j)
        acc[i][j] = __builtin_amdgcn_mfma_f32_16x16x32_bf16(a[i], b[j], acc[i][j], 0, 0, 0);
  }
  int rbase = m0 + wr * 64 + ((l >> 4) * 4);
  int cbase = n0 + wc * 64 + (l & 15);
  float bv[4];
#pragma unroll
  for (int j = 0; j < 4; ++j) bv[j] = bias[cbase + j * 16];
#pragma unroll
  for (int i = 0; i < 4; ++i)
#pragma unroll
    for (int q = 0; q < 4; ++q) {
      int row = rbase + i * 16 + q;
#pragma unroll
      for (int j = 0; j < 4; ++j)
        C[(size_t)row * cA + cbase + j * 16] = f2bf(acc[i][j][q] + bv[j]);
    }
}

// C = (Ah+Al)@(Bh+Bl)^T via split-bf16 MFMA products.
// EP=0: readout (bias+maxout -> bf16 hi/lo). EP=1: logits (bias, col<cV, fp32).
// EP=2: embg (no bias, 4 products, scatter-store [t][col][b] fp32)
template <int EP>
__global__ __launch_bounds__(256) void mfma_gemm3(
    const unsigned short* __restrict__ Ah, const unsigned short* __restrict__ Al,
    const unsigned short* __restrict__ Bh, const unsigned short* __restrict__ Bl,
    const float* __restrict__ bias, void* __restrict__ outv, int K, int nbx) {
  __shared__ unsigned short sAh[4096], sAl[4096], sBh[4096], sBl[4096];
  int bid = xcd_swizzle(blockIdx.x, gridDim.x);
  int by = bid / nbx, bx = bid % nbx;
  int tid = threadIdx.x;
  int w = tid >> 6, l = tid & 63;
  int m0 = by * 128, n0 = bx * 128;
  int wr = w >> 1, wc = w & 1;
  f32x4 acc[4][4] = {};
  int srow = tid >> 2, scol = (tid & 3) * 8;
  for (int k0 = 0; k0 < K; k0 += 32) {
    __syncthreads();
    GLD(&Ah[(size_t)(m0 + srow) * K + k0 + scol], &sAh[tid * 8]);
    GLD(&Ah[(size_t)(m0 + 64 + srow) * K + k0 + scol], &sAh[2048 + tid * 8]);
    GLD(&Al[(size_t)(m0 + srow) * K + k0 + scol], &sAl[tid * 8]);
    GLD(&Al[(size_t)(m0 + 64 + srow) * K + k0 + scol], &sAl[2048 + tid * 8]);
    GLD(&Bh[(size_t)(n0 + srow) * K + k0 + scol], &sBh[tid * 8]);
    GLD(&Bh[(size_t)(n0 + 64 + srow) * K + k0 + scol], &sBh[2048 + tid * 8]);
    GLD(&Bl[(size_t)(n0 + srow) * K + k0 + scol], &sBl[tid * 8]);
    GLD(&Bl[(size_t)(n0 + 64 + srow) * K + k0 + scol], &sBl[2048 + tid * 8]);
    __syncthreads();
    int rA = wr * 64 + (l & 15);
    int rB = wc * 64 + (l & 15);
    int kg = (l >> 4) * 8;
    bf16x8 bh[4], bl[4];
#pragma unroll
    for (int j = 0; j < 4; ++j) {
      bh[j] = *(const bf16x8*)&sBh[(rB + j * 16) * 32 + kg];
      bl[j] = *(const bf16x8*)&sBl[(rB + j * 16) * 32 + kg];
    }
#pragma unroll
    for (int i = 0; i < 4; ++i) {
      bf16x8 ah = *(const bf16x8*)&sAh[(rA + i * 16) * 32 + kg];
      bf16x8 al = *(const bf16x8*)&sAl[(rA + i * 16) * 32 + kg];
#pragma unroll
      for (int j = 0; j < 4; ++j) {
        acc[i][j] = __builtin_amdgcn_mfma_f32_16x16x32_bf16(ah, bh[j], acc[i][j], 0, 0, 0);
        acc[i][j] = __builtin_amdgcn_mfma_f32_16x16x32_bf16(ah, bl[j], acc[i][j], 0, 0, 0);
        acc[i][j] = __builtin_amdgcn_mfma_f32_16x16x32_bf16(al, bh[j], acc[i][j], 0, 0, 0);
        if (EP == 2)
          acc[i][j] = __builtin_amdgcn_mfma_f32_16x16x32_bf16(al, bl[j], acc[i][j], 0, 0, 0);
      }
    }
  }
  int rbase = m0 + wr * 64 + ((l >> 4) * 4);
  int cbase = n0 + wc * 64 + (l & 15);
  if (EP == 0) {
    unsigned short* mo_h = (unsigned short*)outv;
    unsigned short* mo_l = mo_h + (size_t)cM * (cP / 2);
#pragma unroll
    for (int i = 0; i < 4; ++i)
#pragma unroll
      for (int q = 0; q < 4; ++q) {
        int row = rbase + i * 16 + q;
#pragma unroll
        for (int j = 0; j < 4; ++j) {
          float v = acc[i][j][q] + bias[cbase + j * 16];
          float o = fmaxf(v, __shfl_xor(v, 1));
          if (!(l & 1)) {
            int ch = (cbase + j * 16) >> 1;
            unsigned short h = f2bf(o);
            mo_h[(size_t)row * (cP / 2) + ch] = h;
            mo_l[(size_t)row * (cP / 2) + ch] = f2bf(o - bfu(h));
          }
        }
      }
  } else if (EP == 1) {
    float* out = (float*)outv;
#pragma unroll
    for (int i = 0; i < 4; ++i)
#pragma unroll
      for (int q = 0; q < 4; ++q) {
        int row = rbase + i * 16 + q;
#pragma unroll
        for (int j = 0; j < 4; ++j) {
          int col = cbase + j * 16;
          if (col < cV) out[(size_t)row * cV + col] = acc[i][j][q] + bias[col];
        }
      }
  } else {
    float* out = (float*)outv;  // embg [64 t][3072 col][64 b]
#pragma unroll
    for (int i = 0; i < 4; ++i)
#pragma unroll
      for (int q = 0; q < 4; ++q) {
        int row = rbase + i * 16 + q;
        int b = row >> 6, tt = row & 63;
#pragma unroll
        for (int j = 0; j < 4; ++j) {
          int col = cbase + j * 16;
          out[((size_t)tt * cG3 + col) * cB + b] = acc[i][j][q];
        }
      }
  }
}

// ---------------- the fused step loop (normal launch + own grid barrier) ----------------

struct CoopArgs {
  const unsigned short* enc_ctx;  // bf16 [38400][1024]
  const unsigned short* enc_bf;   // bf16 [38400][512]
  const float* inv_fert;          // [38400]
  const float* W_ih;              // [4096][1152]
  const float* b_ih;
  const float* b_hh;
  const float* W_s;               // [1024][1024]
  const float* v_att;
  const float* W_fb;
  const int* slen;
  const float* embg;              // [64][3072][64]
  float* accum;                   // [64][600]
  float* hT0;                     // [1024][64]
  float* hT1;
  float* ctxT;                    // [512][64]
  float* qp;                      // [2][64][1024]
  float* ebuf;                    // [64][600]
  float* s_seqT;                  // [64][1024][64]
  float* ctx_seq;                 // [4096][512]
  unsigned* bar;                  // grid barrier counter
};

__global__ __launch_bounds__(256, 2) void coop_loop(CoopArgs A) {
  __shared__ union {
    float qvf[3][cA];                                       // P3: q, v_att, W_fb
    struct { float w[cT]; float red[8]; float part[4][64]; } p4;
  } sm;
  const int bid = blockIdx.x, tid = threadIdx.x;
  const int wv = tid >> 6, ln = tid & 63;
  const int gw = bid * 4 + wv;       // 0..2047
  const int b3 = bid >> 3;           // 0..63
  const int sub = bid & 7;           // 0..7
  const int len = A.slen[b3];
  unsigned tgt = 0;

  for (int t = 0; t < cN; ++t) {
    float* wbuf = (t & 1) ? A.hT1 : A.hT0;
    const float* rbuf = (t & 1) ? A.hT0 : A.hT1;

    // ---- P1: h_j for all j (wave j computes i,g,o dots over ctx) ----
    if (gw < cH) {
      const int j = gw;
      const float* wi = A.W_ih + (size_t)j * 1152 + cE;
      const float* wg = A.W_ih + (size_t)(j + 2048) * 1152 + cE;
      const float* wo = A.W_ih + (size_t)(j + 3072) * 1152 + cE;
      float ai = 0.f, ag = 0.f, ao = 0.f;
#pragma unroll 8
      for (int k = 0; k < cD; k += 4) {
        float c0 = A.ctxT[(k + 0) * cB + ln];
        float c1 = A.ctxT[(k + 1) * cB + ln];
        float c2 = A.ctxT[(k + 2) * cB + ln];
        float c3 = A.ctxT[(k + 3) * cB + ln];
        float4 vi = *(const float4*)(wi + k);
        float4 vg = *(const float4*)(wg + k);
        float4 vo = *(const float4*)(wo + k);
        ai += vi.x * c0 + vi.y * c1 + vi.z * c2 + vi.w * c3;
        ag += vg.x * c0 + vg.y * c1 + vg.z * c2 + vg.w * c3;
        ao += vo.x * c0 + vo.y * c1 + vo.z * c2 + vo.w * c3;
      }
      const float* eg = A.embg + ((size_t)t * cG3 + j) * cB + ln;
      float gi = ai + A.b_ih[j] + A.b_hh[j] + eg[0];
      float gg = ag + A.b_ih[j + 2048] + A.b_hh[j + 2048] + eg[(size_t)cH * cB];
      float go = ao + A.b_ih[j + 3072] + A.b_hh[j + 3072] + eg[(size_t)2 * cH * cB];
      float hnew = fsig(go) * ftanh(fsig(gi) * ftanh(gg));
      float h = 0.05f * rbuf[j * cB + ln] + 0.95f * hnew;
      wbuf[j * cB + ln] = h;
      A.s_seqT[((size_t)t * cH + j) * cB + ln] = h;
    }
    tgt += cGRID; gridbar(A.bar, tgt);

    // ---- P2: q partials (wave -> (a, k-half)) ----
    {
      const int a = gw >> 1, kh = gw & 1;
      const float* ws = A.W_s + (size_t)a * cH + kh * 512;
      const float* hb = wbuf + (size_t)kh * 512 * cB;
      float acc = 0.f;
#pragma unroll 8
      for (int k = 0; k < 512; k += 4) {
        float4 w4 = *(const float4*)(ws + k);
        acc += w4.x * hb[(k + 0) * cB + ln] + w4.y * hb[(k + 1) * cB + ln] +
               w4.z * hb[(k + 2) * cB + ln] + w4.w * hb[(k + 3) * cB + ln];
      }
      A.qp[(size_t)kh * cB * cA + ln * cA + a] = acc;
    }
    tgt += cGRID; gridbar(A.bar, tgt);

    // ---- P3: energies e[b3, sub*75 .. +75) ----
    for (int i = tid; i < cA; i += 256) {
      sm.qvf[0][i] = A.qp[b3 * cA + i] + A.qp[(size_t)cB * cA + b3 * cA + i];
      sm.qvf[1][i] = A.v_att[i];
      sm.qvf[2][i] = A.W_fb[i];
    }
    __syncthreads();
    for (int i = wv; i < 75; i += 4) {
      int tt = sub * 75 + i;
      if (tt >= len) {
        if (ln == 0) A.ebuf[b3 * cT + tt] = -__builtin_inff();
        continue;
      }
      float fb = A.accum[b3 * cT + tt];
      const unsigned short* row = A.enc_ctx + ((size_t)(b3 * cT + tt)) * cA;
      float acc = 0.f;
#pragma unroll
      for (int k2 = 0; k2 < 8; ++k2) {
        int a0 = 2 * ln + 128 * k2;
        unsigned int u = *reinterpret_cast<const unsigned int*>(&row[a0]);
        float c0 = __uint_as_float((u & 0xffffu) << 16);
        float c1 = __uint_as_float(u & 0xffff0000u);
        acc += sm.qvf[1][a0] * ftanh(c0 + sm.qvf[0][a0] + fb * sm.qvf[2][a0]);
        acc += sm.qvf[1][a0 + 1] * ftanh(c1 + sm.qvf[0][a0 + 1] + fb * sm.qvf[2][a0 + 1]);
      }
#pragma unroll
      for (int o = 32; o; o >>= 1) acc += __shfl_xor(acc, o);
      if (ln == 0) A.ebuf[b3 * cT + tt] = acc;
    }
    tgt += cGRID; gridbar(A.bar, tgt);

    // ---- P4: softmax + ctx + accum; block=(b3, d-chunk=sub) ----
    {
      const float* eb = A.ebuf + b3 * cT;
      float m = -__builtin_inff();
      for (int i = tid; i < cT; i += 256) m = fmaxf(m, eb[i]);
#pragma unroll
      for (int o = 32; o; o >>= 1) m = fmaxf(m, __shfl_xor(m, o));
      if (ln == 0) sm.p4.red[wv] = m;
      __syncthreads();
      m = fmaxf(fmaxf(sm.p4.red[0], sm.p4.red[1]), fmaxf(sm.p4.red[2], sm.p4.red[3]));
      float s = 0.f;
      for (int i = tid; i < cT; i += 256) {
        float w = __expf(eb[i] - m);
        sm.p4.w[i] = w;
        s += w;
      }
#pragma unroll
      for (int o = 32; o; o >>= 1) s += __shfl_xor(s, o);
      if (ln == 0) sm.p4.red[4 + wv] = s;
      __syncthreads();
      float inv_l = 1.0f / (sm.p4.red[4] + sm.p4.red[5] + sm.p4.red[6] + sm.p4.red[7]);
      int d = sub * 64 + ln;
      const unsigned short* ebase = A.enc_bf + (size_t)b3 * cT * cD + d;
      float acc0 = 0.f, acc1 = 0.f;
#pragma unroll 4
      for (int r = 0; r < 150; r += 2) {
        int t0 = wv + 4 * r;
        acc0 += sm.p4.w[t0] * bfu(ebase[(size_t)t0 * cD]);
        acc1 += sm.p4.w[t0 + 4] * bfu(ebase[(size_t)(t0 + 4) * cD]);
      }
      sm.p4.part[wv][ln] = acc0 + acc1;
      __syncthreads();
      if (wv == 0) {
        float c = (sm.p4.part[0][ln] + sm.p4.part[1][ln] +
                   sm.p4.part[2][ln] + sm.p4.part[3][ln]) * inv_l;
        A.ctx_seq[((size_t)(b3 * cN + t)) * cD + d] = c;
        A.ctxT[d * cB + b3] = c;
      }
      if (sub == 0) {
        for (int i = tid; i < cT; i += 256)
          A.accum[b3 * cT + i] += sm.p4.w[i] * inv_l * A.inv_fert[b3 * cT + i] * 0.5f;
      }
    }
    tgt += cGRID; gridbar(A.bar, tgt);
  }
}

// ---------------- launcher ----------------

extern "C" void kernel_launch(void* const* d_in, const int* in_sizes, int n_in,
                              void* d_out, int out_size, void* d_ws, size_t ws_size,
                              hipStream_t stream) {
  (void)in_sizes; (void)n_in; (void)out_size; (void)ws_size;
  const float* enc    = (const float*)d_in[0];
  const int*   labels = (const int*)d_in[1];
  const int*   slen   = (const int*)d_in[2];
  const float* embed  = (const float*)d_in[3];
  const float* W_ih   = (const float*)d_in[4];
  const float* b_ih   = (const float*)d_in[5];
  const float* b_hh   = (const float*)d_in[6];
  const float* W_s    = (const float*)d_in[7];
  const float* W_enc  = (const float*)d_in[8];
  const float* b_enc  = (const float*)d_in[9];
  const float* v_att  = (const float*)d_in[10];
  const float* W_fert = (const float*)d_in[11];
  const float* W_fb   = (const float*)d_in[12];
  const float* W_r    = (const float*)d_in[13];
  const float* b_r    = (const float*)d_in[14];
  const float* W_o    = (const float*)d_in[15];
  const float* b_o    = (const float*)d_in[16];
  float* out = (float*)d_out;

  char* ws = (char*)d_ws;
  size_t off = 0;
  auto alloc = [&](size_t bytes) -> char* {
    char* p = ws + off;
    off = (off + bytes + 255) & ~(size_t)255;
    return p;
  };
  unsigned short* enc_ctx = (unsigned short*)alloc((size_t)cBT * cA * 2);
  unsigned short* enc_bf  = (unsigned short*)alloc((size_t)cBT * cD * 2);
  unsigned short* wencb   = (unsigned short*)alloc((size_t)cA * cD * 2);
  float* inv_fert = (float*)alloc((size_t)cBT * 4);
  float* accum    = (float*)alloc((size_t)cBT * 4);
  float* ebuf     = (float*)alloc((size_t)cBT * 4);
  float* hT0      = (float*)alloc((size_t)cH * cB * 4);
  float* hT1      = (float*)alloc((size_t)cH * cB * 4);
  float* ctxT     = (float*)alloc((size_t)cD * cB * 4);
  float* qp       = (float*)alloc((size_t)2 * cB * cA * 4);
  float* embg     = (float*)alloc((size_t)cN * cG3 * cB * 4);
  float* s_seqT   = (float*)alloc((size_t)cN * cH * cB * 4);
  float* ctx_seq  = (float*)alloc((size_t)cM * cD * 4);
  unsigned* bar   = (unsigned*)alloc(256);
  unsigned short* Aemb_h = (unsigned short*)alloc((size_t)cM * cE * 2);
  unsigned short* Aemb_l = (unsigned short*)alloc((size_t)cM * cE * 2);
  unsigned short* Wihe_h = (unsigned short*)alloc((size_t)cG3 * cE * 2);
  unsigned short* Wihe_l = (unsigned short*)alloc((size_t)cG3 * cE * 2);
  unsigned short* Ar_h = (unsigned short*)alloc((size_t)cM * cKr * 2);
  unsigned short* Ar_l = (unsigned short*)alloc((size_t)cM * cKr * 2);
  unsigned short* Wr_h = (unsigned short*)alloc((size_t)cP * cKr * 2);
  unsigned short* Wr_l = (unsigned short*)alloc((size_t)cP * cKr * 2);
  unsigned short* mo_hl = (unsigned short*)alloc((size_t)2 * cM * (cP / 2) * 2);
  unsigned short* Wo_h = (unsigned short*)alloc((size_t)cVp * cD * 2);
  unsigned short* Wo_l = (unsigned short*)alloc((size_t)cVp * cD * 2);

  hipMemsetAsync(accum, 0, (size_t)cB * cT * 4, stream);
  hipMemsetAsync(ctxT, 0, (size_t)cD * cB * 4, stream);
  hipMemsetAsync(hT0, 0, (size_t)cH * cB * 4, stream);
  hipMemsetAsync(hT1, 0, (size_t)cH * cB * 4, stream);
  hipMemsetAsync(bar, 0, 256, stream);
  hipMemsetAsync(s_seqT, 0, (size_t)cN * cH * cB * 4, stream);
  hipMemsetAsync(ctx_seq, 0, (size_t)cM * cD * 4, stream);

  cast_kernel<<<(cBT * cD) / 1024, 256, 0, stream>>>(enc, enc_bf);
  cast_kernel<<<(cA * cD) / 1024, 256, 0, stream>>>(W_enc, wencb);
  fert_kernel<<<cBT / 4, 256, 0, stream>>>(enc, W_fert, inv_fert);
  mfma_encctx<<<(cBT / 128) * (cA / 128), 256, 0, stream>>>(enc_bf, wencb, b_enc, enc_ctx);
  build_aemb<<<(cM * cE / 4) / 256, 256, 0, stream>>>(embed, labels, Aemb_h, Aemb_l);
  cast_wihe<<<(cG3 * cE / 4) / 256, 256, 0, stream>>>(W_ih, Wihe_h, Wihe_l);
  cast_hl_kernel<<<(cP * cKr) / 1024, 256, 0, stream>>>(W_r, Wr_h, Wr_l);
  cast_wo_kernel<<<(cVp * cD) / 1024, 256, 0, stream>>>(W_o, Wo_h, Wo_l);
  mfma_gemm3<2><<<(cM / 128) * (cG3 / 128), 256, 0, stream>>>(
      Aemb_h, Aemb_l, Wihe_h, Wihe_l, nullptr, (void*)embg, cE, cG3 / 128);

  CoopArgs ca;
  ca.enc_ctx = enc_ctx; ca.enc_bf = enc_bf; ca.inv_fert = inv_fert;
  ca.W_ih = W_ih; ca.b_ih = b_ih; ca.b_hh = b_hh; ca.W_s = W_s;
  ca.v_att = v_att; ca.W_fb = W_fb; ca.slen = slen; ca.embg = embg;
  ca.accum = accum; ca.hT0 = hT0; ca.hT1 = hT1; ca.ctxT = ctxT;
  ca.qp = qp; ca.ebuf = ebuf; ca.s_seqT = s_seqT; ca.ctx_seq = ctx_seq;
  ca.bar = bar;
  // Normal launch (cooperative launch failed silently on this harness).
  // __launch_bounds__(256,2) => 2 blocks/CU guaranteed => 512 blocks co-resident.
  coop_loop<<<dim3(cGRID), dim3(256), 0, stream>>>(ca);

  build_ar_kernel<<<(cM * cKr) / 1024, 256, 0, stream>>>(s_seqT, ctx_seq, embed, labels,
                                                         Ar_h, Ar_l);
  mfma_gemm3<0><<<(cM / 128) * (cP / 128), 256, 0, stream>>>(Ar_h, Ar_l, Wr_h, Wr_l, b_r,
                                                             (void*)mo_hl, cKr, cP / 128);
  unsigned short* mo_h = mo_hl;
  unsigned short* mo_l = mo_hl + (size_t)cM * (cP / 2);
  mfma_gemm3<1><<<(cM / 128) * (cVp / 128), 256, 0, stream>>>(mo_h, mo_l, Wo_h, Wo_l, b_o,
                                                              (void*)out, cP / 2, cVp / 128);
}

// Round 6
// 13032.320 us; speedup vs baseline: 3.2855x; 3.2855x over previous
//
#include <hip/hip_runtime.h>
#include <math.h>

constexpr int cB = 64, cT = 600, cD = 512, cE = 640, cH = 1024, cA = 1024,
              cP = 1024, cV = 10025, cN = 64;
constexpr int cBT = cB * cT;       // 38400
constexpr int cKr = cH + cE + cD;  // 2176
constexpr int cM  = cB * cN;       // 4096
constexpr int cVp = 10112;         // V padded to 79*128
constexpr int cG3 = 3 * cH;        // 3072 (i,g,o)

typedef __attribute__((ext_vector_type(8))) short bf16x8;
typedef __attribute__((ext_vector_type(4))) float f32x4;

__device__ __forceinline__ float bfu(unsigned short s) {
  return __uint_as_float(((unsigned int)s) << 16);
}
__device__ __forceinline__ unsigned short f2bf(float f) {
  unsigned int x = __float_as_uint(f);
  x += 0x7fffu + ((x >> 16) & 1u);
  return (unsigned short)(x >> 16);
}
__device__ __forceinline__ float fsig(float x) { return 1.0f / (1.0f + __expf(-x)); }
__device__ __forceinline__ float ftanh(float x) {
  float e = __expf(2.0f * x);
  return 1.0f - 2.0f / (e + 1.0f);
}

#define GLD(g, s)                                                          \
  __builtin_amdgcn_global_load_lds(                                       \
      (const __attribute__((address_space(1))) void*)(g),                 \
      (__attribute__((address_space(3))) void*)(s), 16, 0, 0)

__device__ __forceinline__ int xcd_swizzle(int bid, int nwg) {
  int q = nwg >> 3, r = nwg & 7;
  int x = bid & 7, loc = bid >> 3;
  return (x < r ? x * (q + 1) : r * (q + 1) + (x - r) * q) + loc;
}

// ---------------- precompute / casts ----------------

__global__ __launch_bounds__(256) void cast_kernel(const float* __restrict__ in,
                                                   unsigned short* __restrict__ out) {
  int i = blockIdx.x * 256 + threadIdx.x;
  float4 v = reinterpret_cast<const float4*>(in)[i];
  ushort4 o;
  o.x = f2bf(v.x); o.y = f2bf(v.y); o.z = f2bf(v.z); o.w = f2bf(v.w);
  reinterpret_cast<ushort4*>(out)[i] = o;
}

__global__ __launch_bounds__(256) void cast_hl_kernel(const float* __restrict__ in,
                                                      unsigned short* __restrict__ hi,
                                                      unsigned short* __restrict__ lo) {
  int i = blockIdx.x * 256 + threadIdx.x;
  float4 v = reinterpret_cast<const float4*>(in)[i];
  ushort4 h, l;
  h.x = f2bf(v.x); h.y = f2bf(v.y); h.z = f2bf(v.z); h.w = f2bf(v.w);
  l.x = f2bf(v.x - bfu(h.x)); l.y = f2bf(v.y - bfu(h.y));
  l.z = f2bf(v.z - bfu(h.z)); l.w = f2bf(v.w - bfu(h.w));
  reinterpret_cast<ushort4*>(hi)[i] = h;
  reinterpret_cast<ushort4*>(lo)[i] = l;
}

__global__ __launch_bounds__(256) void cast_wo_kernel(const float* __restrict__ in,
                                                      unsigned short* __restrict__ hi,
                                                      unsigned short* __restrict__ lo) {
  int idx = blockIdx.x * 256 + threadIdx.x;
  int row = idx >> 7;
  int k = (idx & 127) * 4;
  float4 v = (row < cV) ? *reinterpret_cast<const float4*>(&in[(size_t)row * cD + k])
                        : make_float4(0.f, 0.f, 0.f, 0.f);
  ushort4 h, l;
  h.x = f2bf(v.x); h.y = f2bf(v.y); h.z = f2bf(v.z); h.w = f2bf(v.w);
  l.x = f2bf(v.x - bfu(h.x)); l.y = f2bf(v.y - bfu(h.y));
  l.z = f2bf(v.z - bfu(h.z)); l.w = f2bf(v.w - bfu(h.w));
  reinterpret_cast<ushort4*>(hi)[idx] = h;
  reinterpret_cast<ushort4*>(lo)[idx] = l;
}

__global__ __launch_bounds__(256) void fert_kernel(const float* __restrict__ enc,
                                                   const float* __restrict__ W_fert,
                                                   float* __restrict__ inv_fert) {
  int wave = threadIdx.x >> 6, lane = threadIdx.x & 63;
  int row = blockIdx.x * 4 + wave;
  const float* r = enc + (size_t)row * cD;
  float s = 0.0f;
#pragma unroll
  for (int i = 0; i < 8; ++i) s += r[lane + 64 * i] * W_fert[lane + 64 * i];
#pragma unroll
  for (int o = 32; o; o >>= 1) s += __shfl_xor(s, o);
  if (lane == 0) inv_fert[row] = 1.0f / (1.0f + __expf(-s));
}

// shifted embeddings of labels -> hi/lo bf16 [4096][640]
__global__ __launch_bounds__(256) void build_aemb(const float* __restrict__ embed,
                                                  const int* __restrict__ labels,
                                                  unsigned short* __restrict__ Ah,
                                                  unsigned short* __restrict__ Al) {
  int idx = blockIdx.x * 256 + threadIdx.x;  // per 4 elems
  int row = idx / (cE / 4);
  int k = (idx % (cE / 4)) * 4;
  int b = row >> 6, tt = row & 63;
  float4 v = make_float4(0.f, 0.f, 0.f, 0.f);
  if (tt > 0) {
    int lab = labels[b * cN + tt - 1];
    v = *reinterpret_cast<const float4*>(&embed[(size_t)lab * cE + k]);
  }
  ushort4 h, l;
  h.x = f2bf(v.x); h.y = f2bf(v.y); h.z = f2bf(v.z); h.w = f2bf(v.w);
  l.x = f2bf(v.x - bfu(h.x)); l.y = f2bf(v.y - bfu(h.y));
  l.z = f2bf(v.z - bfu(h.z)); l.w = f2bf(v.w - bfu(h.w));
  *reinterpret_cast<ushort4*>(&Ah[(size_t)row * cE + k]) = h;
  *reinterpret_cast<ushort4*>(&Al[(size_t)row * cE + k]) = l;
}

// W_ih rows (i,g,o) x cols [0,640) -> hi/lo bf16 [3072][640] (for embg GEMM)
__global__ __launch_bounds__(256) void cast_wihe(const float* __restrict__ W_ih,
                                                 unsigned short* __restrict__ Wh,
                                                 unsigned short* __restrict__ Wl) {
  int idx = blockIdx.x * 256 + threadIdx.x;
  int jcol = idx / (cE / 4);
  int k = (idx % (cE / 4)) * 4;
  int r = (jcol < cH) ? jcol : jcol + cH;  // i: rows 0..1023; g: 2048..; o: 3072..
  float4 v = *reinterpret_cast<const float4*>(&W_ih[(size_t)r * (cE + cD) + k]);
  ushort4 h, l;
  h.x = f2bf(v.x); h.y = f2bf(v.y); h.z = f2bf(v.z); h.w = f2bf(v.w);
  l.x = f2bf(v.x - bfu(h.x)); l.y = f2bf(v.y - bfu(h.y));
  l.z = f2bf(v.z - bfu(h.z)); l.w = f2bf(v.w - bfu(h.w));
  *reinterpret_cast<ushort4*>(&Wh[(size_t)jcol * cE + k]) = h;
  *reinterpret_cast<ushort4*>(&Wl[(size_t)jcol * cE + k]) = l;
}

// W_ih ctx-half -> packed k-major bf16: WihP[(k4*3072 + col)*4 + (k&3)]
__global__ __launch_bounds__(256) void pack_wih(const float* __restrict__ W_ih,
                                                unsigned short* __restrict__ WihP) {
  int idx = blockIdx.x * 256 + threadIdx.x;   // col*128 + k4
  int col = idx >> 7;
  int k4 = idx & 127;
  int r = (col < cH) ? col : col + cH;
  float4 v = *reinterpret_cast<const float4*>(&W_ih[(size_t)r * (cE + cD) + cE + k4 * 4]);
  ushort4 h;
  h.x = f2bf(v.x); h.y = f2bf(v.y); h.z = f2bf(v.z); h.w = f2bf(v.w);
  *reinterpret_cast<ushort4*>(&WihP[((size_t)k4 * cG3 + col) * 4]) = h;
}

// W_s -> packed k-major bf16: WsP[(k4*1024 + a)*4 + (k&3)]
__global__ __launch_bounds__(256) void pack_ws(const float* __restrict__ W_s,
                                               unsigned short* __restrict__ WsP) {
  int idx = blockIdx.x * 256 + threadIdx.x;   // a*256 + k4
  int a = idx >> 8;
  int k4 = idx & 255;
  float4 v = *reinterpret_cast<const float4*>(&W_s[(size_t)a * cH + k4 * 4]);
  ushort4 h;
  h.x = f2bf(v.x); h.y = f2bf(v.y); h.z = f2bf(v.z); h.w = f2bf(v.w);
  *reinterpret_cast<ushort4*>(&WsP[((size_t)k4 * cA + a) * 4]) = h;
}

// concat(s_seq, emb, ctx_seq) -> Ar hi/lo bf16 [4096][2176]
__global__ __launch_bounds__(256) void build_ar_kernel(
    const float* __restrict__ s_seq, const float* __restrict__ ctx_seq,
    const float* __restrict__ embed, const int* __restrict__ labels,
    unsigned short* __restrict__ Ah, unsigned short* __restrict__ Al) {
  int idx = blockIdx.x * 256 + threadIdx.x;
  int row = idx / (cKr / 4);
  int k = (idx % (cKr / 4)) * 4;
  int b = row >> 6, tt = row & 63;
  float4 v;
  if (k < cH) {
    v = *reinterpret_cast<const float4*>(&s_seq[(size_t)row * cH + k]);
  } else if (k < cH + cE) {
    if (tt == 0) {
      v = make_float4(0.f, 0.f, 0.f, 0.f);
    } else {
      int lab = labels[b * cN + tt - 1];
      v = *reinterpret_cast<const float4*>(&embed[(size_t)lab * cE + (k - cH)]);
    }
  } else {
    v = *reinterpret_cast<const float4*>(&ctx_seq[(size_t)row * cD + (k - cH - cE)]);
  }
  ushort4 h, l;
  h.x = f2bf(v.x); h.y = f2bf(v.y); h.z = f2bf(v.z); h.w = f2bf(v.w);
  l.x = f2bf(v.x - bfu(h.x)); l.y = f2bf(v.y - bfu(h.y));
  l.z = f2bf(v.z - bfu(h.z)); l.w = f2bf(v.w - bfu(h.w));
  *reinterpret_cast<ushort4*>(&Ah[(size_t)row * cKr + k]) = h;
  *reinterpret_cast<ushort4*>(&Al[(size_t)row * cKr + k]) = l;
}

// ---------------- MFMA GEMMs ----------------

// enc_ctx = enc_bf @ W_enc_bf^T + b_enc  -> bf16 [38400][1024]
__global__ __launch_bounds__(256) void mfma_encctx(const unsigned short* __restrict__ A,
                                                   const unsigned short* __restrict__ Bm,
                                                   const float* __restrict__ bias,
                                                   unsigned short* __restrict__ C) {
  __shared__ unsigned short sA[4096], sB[4096];
  constexpr int nbx = cA / 128;
  int bid = xcd_swizzle(blockIdx.x, gridDim.x);
  int by = bid / nbx, bx = bid % nbx;
  int tid = threadIdx.x;
  int w = tid >> 6, l = tid & 63;
  int m0 = by * 128, n0 = bx * 128;
  int wr = w >> 1, wc = w & 1;
  f32x4 acc[4][4] = {};
  int srow = tid >> 2, scol = (tid & 3) * 8;
  for (int k0 = 0; k0 < cD; k0 += 32) {
    __syncthreads();
    GLD(&A[(size_t)(m0 + srow) * cD + k0 + scol], &sA[tid * 8]);
    GLD(&A[(size_t)(m0 + 64 + srow) * cD + k0 + scol], &sA[2048 + tid * 8]);
    GLD(&Bm[(size_t)(n0 + srow) * cD + k0 + scol], &sB[tid * 8]);
    GLD(&Bm[(size_t)(n0 + 64 + srow) * cD + k0 + scol], &sB[2048 + tid * 8]);
    __syncthreads();
    int rA = wr * 64 + (l & 15);
    int rB = wc * 64 + (l & 15);
    int kg = (l >> 4) * 8;
    bf16x8 a[4], b[4];
#pragma unroll
    for (int i = 0; i < 4; ++i) a[i] = *(const bf16x8*)&sA[(rA + i * 16) * 32 + kg];
#pragma unroll
    for (int j = 0; j < 4; ++j) b[j] = *(const bf16x8*)&sB[(rB + j * 16) * 32 + kg];
#pragma unroll
    for (int i = 0; i < 4; ++i)
#pragma unroll
      for (int j = 0; j < 4; ++j)
        acc[i][j] = __builtin_amdgcn_mfma_f32_16x16x32_bf16(a[i], b[j], acc[i][j], 0, 0, 0);
  }
  int rbase = m0 + wr * 64 + ((l >> 4) * 4);
  int cbase = n0 + wc * 64 + (l & 15);
  float bv[4];
#pragma unroll
  for (int j = 0; j < 4; ++j) bv[j] = bias[cbase + j * 16];
#pragma unroll
  for (int i = 0; i < 4; ++i)
#pragma unroll
    for (int q = 0; q < 4; ++q) {
      int row = rbase + i * 16 + q;
#pragma unroll
      for (int j = 0; j < 4; ++j)
        C[(size_t)row * cA + cbase + j * 16] = f2bf(acc[i][j][q] + bv[j]);
    }
}

// C = (Ah+Al)@(Bh+Bl)^T via split-bf16 MFMA products.
// EP=0: readout (bias+maxout -> bf16 hi/lo). EP=1: logits (bias, col<cV, fp32).
// EP=2: embg (no bias, 4 products, row-major fp32 [4096][3072])
template <int EP>
__global__ __launch_bounds__(256) void mfma_gemm3(
    const unsigned short* __restrict__ Ah, const unsigned short* __restrict__ Al,
    const unsigned short* __restrict__ Bh, const unsigned short* __restrict__ Bl,
    const float* __restrict__ bias, void* __restrict__ outv, int K, int nbx) {
  __shared__ unsigned short sAh[4096], sAl[4096], sBh[4096], sBl[4096];
  int bid = xcd_swizzle(blockIdx.x, gridDim.x);
  int by = bid / nbx, bx = bid % nbx;
  int tid = threadIdx.x;
  int w = tid >> 6, l = tid & 63;
  int m0 = by * 128, n0 = bx * 128;
  int wr = w >> 1, wc = w & 1;
  f32x4 acc[4][4] = {};
  int srow = tid >> 2, scol = (tid & 3) * 8;
  for (int k0 = 0; k0 < K; k0 += 32) {
    __syncthreads();
    GLD(&Ah[(size_t)(m0 + srow) * K + k0 + scol], &sAh[tid * 8]);
    GLD(&Ah[(size_t)(m0 + 64 + srow) * K + k0 + scol], &sAh[2048 + tid * 8]);
    GLD(&Al[(size_t)(m0 + srow) * K + k0 + scol], &sAl[tid * 8]);
    GLD(&Al[(size_t)(m0 + 64 + srow) * K + k0 + scol], &sAl[2048 + tid * 8]);
    GLD(&Bh[(size_t)(n0 + srow) * K + k0 + scol], &sBh[tid * 8]);
    GLD(&Bh[(size_t)(n0 + 64 + srow) * K + k0 + scol], &sBh[2048 + tid * 8]);
    GLD(&Bl[(size_t)(n0 + srow) * K + k0 + scol], &sBl[tid * 8]);
    GLD(&Bl[(size_t)(n0 + 64 + srow) * K + k0 + scol], &sBl[2048 + tid * 8]);
    __syncthreads();
    int rA = wr * 64 + (l & 15);
    int rB = wc * 64 + (l & 15);
    int kg = (l >> 4) * 8;
    bf16x8 bh[4], bl[4];
#pragma unroll
    for (int j = 0; j < 4; ++j) {
      bh[j] = *(const bf16x8*)&sBh[(rB + j * 16) * 32 + kg];
      bl[j] = *(const bf16x8*)&sBl[(rB + j * 16) * 32 + kg];
    }
#pragma unroll
    for (int i = 0; i < 4; ++i) {
      bf16x8 ah = *(const bf16x8*)&sAh[(rA + i * 16) * 32 + kg];
      bf16x8 al = *(const bf16x8*)&sAl[(rA + i * 16) * 32 + kg];
#pragma unroll
      for (int j = 0; j < 4; ++j) {
        acc[i][j] = __builtin_amdgcn_mfma_f32_16x16x32_bf16(ah, bh[j], acc[i][j], 0, 0, 0);
        acc[i][j] = __builtin_amdgcn_mfma_f32_16x16x32_bf16(ah, bl[j], acc[i][j], 0, 0, 0);
        acc[i][j] = __builtin_amdgcn_mfma_f32_16x16x32_bf16(al, bh[j], acc[i][j], 0, 0, 0);
        if (EP == 2)
          acc[i][j] = __builtin_amdgcn_mfma_f32_16x16x32_bf16(al, bl[j], acc[i][j], 0, 0, 0);
      }
    }
  }
  int rbase = m0 + wr * 64 + ((l >> 4) * 4);
  int cbase = n0 + wc * 64 + (l & 15);
  if (EP == 0) {
    unsigned short* mo_h = (unsigned short*)outv;
    unsigned short* mo_l = mo_h + (size_t)cM * (cP / 2);
#pragma unroll
    for (int i = 0; i < 4; ++i)
#pragma unroll
      for (int q = 0; q < 4; ++q) {
        int row = rbase + i * 16 + q;
#pragma unroll
        for (int j = 0; j < 4; ++j) {
          float v = acc[i][j][q] + bias[cbase + j * 16];
          float o = fmaxf(v, __shfl_xor(v, 1));
          if (!(l & 1)) {
            int ch = (cbase + j * 16) >> 1;
            unsigned short h = f2bf(o);
            mo_h[(size_t)row * (cP / 2) + ch] = h;
            mo_l[(size_t)row * (cP / 2) + ch] = f2bf(o - bfu(h));
          }
        }
      }
  } else if (EP == 1) {
    float* out = (float*)outv;
#pragma unroll
    for (int i = 0; i < 4; ++i)
#pragma unroll
      for (int q = 0; q < 4; ++q) {
        int row = rbase + i * 16 + q;
#pragma unroll
        for (int j = 0; j < 4; ++j) {
          int col = cbase + j * 16;
          if (col < cV) out[(size_t)row * cV + col] = acc[i][j][q] + bias[col];
        }
      }
  } else {
    float* out = (float*)outv;  // embg [4096 rows][3072]
#pragma unroll
    for (int i = 0; i < 4; ++i)
#pragma unroll
      for (int q = 0; q < 4; ++q) {
        int row = rbase + i * 16 + q;
#pragma unroll
        for (int j = 0; j < 4; ++j)
          out[(size_t)row * cG3 + cbase + j * 16] = acc[i][j][q];
      }
  }
}

// ---------------- the per-batch fused loop: 1 block = 1 batch, no global sync ----------------

struct LoopArgs {
  const unsigned short* enc_ctx;  // bf16 [38400][1024]
  const unsigned short* enc_bf;   // bf16 [38400][512]
  const unsigned short* WihP;     // packed [128][3072][4] bf16
  const unsigned short* WsP;      // packed [256][1024][4] bf16
  const float* b_ih;
  const float* b_hh;
  const float* embg;              // fp32 [4096][3072]
  const float* inv_fert;          // [38400]
  const float* v_att;
  const float* W_fb;
  const int* slen;
  float* s_seq;                   // [4096][1024]
  float* ctx_seq;                 // [4096][512]
};

__global__ __launch_bounds__(1024, 1) void batch_loop(LoopArgs A) {
  __shared__ float ctx_s[cD];
  __shared__ float h_s[cH];
  __shared__ float q_s[cA];
  __shared__ float ew_s[cT];
  __shared__ float acc_s[cT];
  __shared__ float fert_s[cT];
  __shared__ float vatt_s[cA];
  __shared__ float wfb_s[cA];
  __shared__ float red_s[32];
  const int b = blockIdx.x, tid = threadIdx.x;
  const int wv = tid >> 6, ln = tid & 63;
  const int len = A.slen[b];
  const int j = tid;

  if (tid < cD) ctx_s[tid] = 0.f;
  h_s[tid] = 0.f;
  vatt_s[tid] = A.v_att[tid];
  wfb_s[tid] = A.W_fb[tid];
  for (int i = tid; i < cT; i += 1024) {
    acc_s[i] = 0.f;
    fert_s[i] = A.inv_fert[b * cT + i];
  }
  const float bgi = A.b_ih[j] + A.b_hh[j];
  const float bgg = A.b_ih[j + 2048] + A.b_hh[j + 2048];
  const float bgo = A.b_ih[j + 3072] + A.b_hh[j + 3072];
  __syncthreads();

  for (int t = 0; t < cN; ++t) {
    // ---- P1: gates + h (thread j owns hidden unit j) ----
    {
      float ai = 0.f, ag = 0.f, ao = 0.f;
      const unsigned short* p = A.WihP + (size_t)j * 4;
#pragma unroll 4
      for (int k4 = 0; k4 < cD / 4; ++k4) {
        float4 c = *reinterpret_cast<const float4*>(&ctx_s[k4 * 4]);
        ushort4 wi = *reinterpret_cast<const ushort4*>(p);
        ushort4 wg = *reinterpret_cast<const ushort4*>(p + (size_t)1024 * 4);
        ushort4 wo = *reinterpret_cast<const ushort4*>(p + (size_t)2048 * 4);
        ai += bfu(wi.x) * c.x + bfu(wi.y) * c.y + bfu(wi.z) * c.z + bfu(wi.w) * c.w;
        ag += bfu(wg.x) * c.x + bfu(wg.y) * c.y + bfu(wg.z) * c.z + bfu(wg.w) * c.w;
        ao += bfu(wo.x) * c.x + bfu(wo.y) * c.y + bfu(wo.z) * c.z + bfu(wo.w) * c.w;
        p += (size_t)cG3 * 4;
      }
      const float* eg = A.embg + (size_t)(b * cN + t) * cG3;
      float gi = ai + bgi + eg[j];
      float gg = ag + bgg + eg[j + 1024];
      float go = ao + bgo + eg[j + 2048];
      float hnew = fsig(go) * ftanh(fsig(gi) * ftanh(gg));
      float h = 0.05f * h_s[j] + 0.95f * hnew;
      h_s[j] = h;
      A.s_seq[(size_t)(b * cN + t) * cH + j] = h;
    }
    __syncthreads();

    // ---- P2: q (thread a owns attention dim a) ----
    {
      float q = 0.f;
      const unsigned short* p = A.WsP + (size_t)j * 4;
#pragma unroll 4
      for (int k4 = 0; k4 < cH / 4; ++k4) {
        float4 hh = *reinterpret_cast<const float4*>(&h_s[k4 * 4]);
        ushort4 w = *reinterpret_cast<const ushort4*>(p);
        q += bfu(w.x) * hh.x + bfu(w.y) * hh.y + bfu(w.z) * hh.z + bfu(w.w) * hh.w;
        p += (size_t)cA * 4;
      }
      q_s[j] = q;
    }
    __syncthreads();

    // ---- P3: energies (wave wv handles rows tt = wv, wv+16, ...) ----
    for (int tt = wv; tt < cT; tt += 16) {
      if (tt >= len) {
        if (ln == 0) ew_s[tt] = -__builtin_inff();
        continue;
      }
      float fb = acc_s[tt];
      const unsigned short* row = A.enc_ctx + (size_t)(b * cT + tt) * cA + 2 * ln;
      float acc = 0.f;
#pragma unroll
      for (int k2 = 0; k2 < 8; ++k2) {
        int a0 = 2 * ln + 128 * k2;
        unsigned int u = *reinterpret_cast<const unsigned int*>(row + 128 * k2);
        float c0 = __uint_as_float(u << 16);
        float c1 = __uint_as_float(u & 0xffff0000u);
        acc += vatt_s[a0] * ftanh(c0 + q_s[a0] + fb * wfb_s[a0]);
        acc += vatt_s[a0 + 1] * ftanh(c1 + q_s[a0 + 1] + fb * wfb_s[a0 + 1]);
      }
#pragma unroll
      for (int o = 32; o; o >>= 1) acc += __shfl_xor(acc, o);
      if (ln == 0) ew_s[tt] = acc;
    }
    __syncthreads();

    // ---- P4: softmax + ctx + accum ----
    {
      float m = -__builtin_inff();
      for (int i = tid; i < cT; i += 1024) m = fmaxf(m, ew_s[i]);
#pragma unroll
      for (int o = 32; o; o >>= 1) m = fmaxf(m, __shfl_xor(m, o));
      if (ln == 0) red_s[wv] = m;
      __syncthreads();
      m = red_s[0];
#pragma unroll
      for (int w2 = 1; w2 < 16; ++w2) m = fmaxf(m, red_s[w2]);
      float ssum = 0.f;
      for (int i = tid; i < cT; i += 1024) {
        float w = __expf(ew_s[i] - m);
        ew_s[i] = w;
        ssum += w;
      }
#pragma unroll
      for (int o = 32; o; o >>= 1) ssum += __shfl_xor(ssum, o);
      if (ln == 0) red_s[16 + wv] = ssum;
      __syncthreads();
      float tot = red_s[16];
#pragma unroll
      for (int w2 = 1; w2 < 16; ++w2) tot += red_s[16 + w2];
      float invl = 1.0f / tot;

      if (tid < cD) {
        const unsigned short* eb = A.enc_bf + (size_t)b * cT * cD + tid;
        float s0 = 0.f, s1 = 0.f;
#pragma unroll 4
        for (int tt = 0; tt < cT; tt += 2) {
          s0 += ew_s[tt] * bfu(eb[(size_t)tt * cD]);
          s1 += ew_s[tt + 1] * bfu(eb[(size_t)(tt + 1) * cD]);
        }
        float cval = (s0 + s1) * invl;
        ctx_s[tid] = cval;
        A.ctx_seq[(size_t)(b * cN + t) * cD + tid] = cval;
      } else {
        for (int tt = tid - 512; tt < cT; tt += 512)
          acc_s[tt] += ew_s[tt] * invl * fert_s[tt] * 0.5f;
      }
    }
    __syncthreads();
  }
}

// ---------------- launcher ----------------

extern "C" void kernel_launch(void* const* d_in, const int* in_sizes, int n_in,
                              void* d_out, int out_size, void* d_ws, size_t ws_size,
                              hipStream_t stream) {
  (void)in_sizes; (void)n_in; (void)out_size; (void)ws_size;
  const float* enc    = (const float*)d_in[0];
  const int*   labels = (const int*)d_in[1];
  const int*   slen   = (const int*)d_in[2];
  const float* embed  = (const float*)d_in[3];
  const float* W_ih   = (const float*)d_in[4];
  const float* b_ih   = (const float*)d_in[5];
  const float* b_hh   = (const float*)d_in[6];
  const float* W_s    = (const float*)d_in[7];
  const float* W_enc  = (const float*)d_in[8];
  const float* b_enc  = (const float*)d_in[9];
  const float* v_att  = (const float*)d_in[10];
  const float* W_fert = (const float*)d_in[11];
  const float* W_fb   = (const float*)d_in[12];
  const float* W_r    = (const float*)d_in[13];
  const float* b_r    = (const float*)d_in[14];
  const float* W_o    = (const float*)d_in[15];
  const float* b_o    = (const float*)d_in[16];
  float* out = (float*)d_out;

  char* ws = (char*)d_ws;
  size_t off = 0;
  auto alloc = [&](size_t bytes) -> char* {
    char* p = ws + off;
    off = (off + bytes + 255) & ~(size_t)255;
    return p;
  };
  unsigned short* enc_ctx = (unsigned short*)alloc((size_t)cBT * cA * 2);
  unsigned short* enc_bf  = (unsigned short*)alloc((size_t)cBT * cD * 2);
  unsigned short* wencb   = (unsigned short*)alloc((size_t)cA * cD * 2);
  float* inv_fert = (float*)alloc((size_t)cBT * 4);
  unsigned short* WihP = (unsigned short*)alloc((size_t)cD * cG3 * 2);
  unsigned short* WsP  = (unsigned short*)alloc((size_t)cH * cA * 2);
  float* embg     = (float*)alloc((size_t)cM * cG3 * 4);
  float* s_seq    = (float*)alloc((size_t)cM * cH * 4);
  float* ctx_seq  = (float*)alloc((size_t)cM * cD * 4);
  unsigned short* Aemb_h = (unsigned short*)alloc((size_t)cM * cE * 2);
  unsigned short* Aemb_l = (unsigned short*)alloc((size_t)cM * cE * 2);
  unsigned short* Wihe_h = (unsigned short*)alloc((size_t)cG3 * cE * 2);
  unsigned short* Wihe_l = (unsigned short*)alloc((size_t)cG3 * cE * 2);
  unsigned short* Ar_h = (unsigned short*)alloc((size_t)cM * cKr * 2);
  unsigned short* Ar_l = (unsigned short*)alloc((size_t)cM * cKr * 2);
  unsigned short* Wr_h = (unsigned short*)alloc((size_t)cP * cKr * 2);
  unsigned short* Wr_l = (unsigned short*)alloc((size_t)cP * cKr * 2);
  unsigned short* mo_hl = (unsigned short*)alloc((size_t)2 * cM * (cP / 2) * 2);
  unsigned short* Wo_h = (unsigned short*)alloc((size_t)cVp * cD * 2);
  unsigned short* Wo_l = (unsigned short*)alloc((size_t)cVp * cD * 2);

  cast_kernel<<<(cBT * cD) / 1024, 256, 0, stream>>>(enc, enc_bf);
  cast_kernel<<<(cA * cD) / 1024, 256, 0, stream>>>(W_enc, wencb);
  fert_kernel<<<cBT / 4, 256, 0, stream>>>(enc, W_fert, inv_fert);
  mfma_encctx<<<(cBT / 128) * (cA / 128), 256, 0, stream>>>(enc_bf, wencb, b_enc, enc_ctx);
  build_aemb<<<(cM * cE / 4) / 256, 256, 0, stream>>>(embed, labels, Aemb_h, Aemb_l);
  cast_wihe<<<(cG3 * cE / 4) / 256, 256, 0, stream>>>(W_ih, Wihe_h, Wihe_l);
  pack_wih<<<(cG3 * (cD / 4)) / 256, 256, 0, stream>>>(W_ih, WihP);
  pack_ws<<<(cA * (cH / 4)) / 256, 256, 0, stream>>>(W_s, WsP);
  cast_hl_kernel<<<(cP * cKr) / 1024, 256, 0, stream>>>(W_r, Wr_h, Wr_l);
  cast_wo_kernel<<<(cVp * cD) / 1024, 256, 0, stream>>>(W_o, Wo_h, Wo_l);
  mfma_gemm3<2><<<(cM / 128) * (cG3 / 128), 256, 0, stream>>>(
      Aemb_h, Aemb_l, Wihe_h, Wihe_l, nullptr, (void*)embg, cE, cG3 / 128);

  LoopArgs la;
  la.enc_ctx = enc_ctx; la.enc_bf = enc_bf; la.WihP = WihP; la.WsP = WsP;
  la.b_ih = b_ih; la.b_hh = b_hh; la.embg = embg; la.inv_fert = inv_fert;
  la.v_att = v_att; la.W_fb = W_fb; la.slen = slen;
  la.s_seq = s_seq; la.ctx_seq = ctx_seq;
  batch_loop<<<dim3(cB), dim3(1024), 0, stream>>>(la);

  build_ar_kernel<<<(cM * cKr) / 1024, 256, 0, stream>>>(s_seq, ctx_seq, embed, labels,
                                                         Ar_h, Ar_l);
  mfma_gemm3<0><<<(cM / 128) * (cP / 128), 256, 0, stream>>>(Ar_h, Ar_l, Wr_h, Wr_l, b_r,
                                                             (void*)mo_hl, cKr, cP / 128);
  unsigned short* mo_h = mo_hl;
  unsigned short* mo_l = mo_hl + (size_t)cM * (cP / 2);
  mfma_gemm3<1><<<(cM / 128) * (cVp / 128), 256, 0, stream>>>(mo_h, mo_l, Wo_h, Wo_l, b_o,
                                                              (void*)out, cP / 2, cVp / 128);
}

// Round 7
// 10031.400 us; speedup vs baseline: 4.2683x; 1.2992x over previous
//
#include <hip/hip_runtime.h>
#include <math.h>

constexpr int cB = 64, cT = 600, cD = 512, cE = 640, cH = 1024, cA = 1024,
              cP = 1024, cV = 10025, cN = 64;
constexpr int cBT = cB * cT;       // 38400
constexpr int cKr = cH + cE + cD;  // 2176
constexpr int cM  = cB * cN;       // 4096
constexpr int cVp = 10112;         // V padded to 79*128
constexpr int cG3 = 3 * cH;        // 3072 (i,g,o)
constexpr int cTQ = cT / 4;        // 150: T-quarter per block
constexpr int cXCS = 516;          // xc stride: m, s, c[512], pad

typedef __attribute__((ext_vector_type(8))) short bf16x8;
typedef __attribute__((ext_vector_type(4))) float f32x4;

__device__ __forceinline__ float bfu(unsigned short s) {
  return __uint_as_float(((unsigned int)s) << 16);
}
__device__ __forceinline__ unsigned short f2bf(float f) {
  unsigned int x = __float_as_uint(f);
  x += 0x7fffu + ((x >> 16) & 1u);
  return (unsigned short)(x >> 16);
}
__device__ __forceinline__ float fsig(float x) { return 1.0f / (1.0f + __expf(-x)); }
__device__ __forceinline__ float ftanh(float x) {
  float e = __expf(2.0f * x);
  return 1.0f - 2.0f / (e + 1.0f);
}

#define GLD(g, s)                                                          \
  __builtin_amdgcn_global_load_lds(                                       \
      (const __attribute__((address_space(1))) void*)(g),                 \
      (__attribute__((address_space(3))) void*)(s), 16, 0, 0)

__device__ __forceinline__ int xcd_swizzle(int bid, int nwg) {
  int q = nwg >> 3, r = nwg & 7;
  int x = bid & 7, loc = bid >> 3;
  return (x < r ? x * (q + 1) : r * (q + 1) + (x - r) * q) + loc;
}

// device-scope message passing (cross-XCD safe: atomics execute at the
// coherence point; no cache-flushing fences needed)
__device__ __forceinline__ void ast(float* p, float v) {
  __hip_atomic_store(p, v, __ATOMIC_RELAXED, __HIP_MEMORY_SCOPE_AGENT);
}
__device__ __forceinline__ float ald(const float* p) {
  return __hip_atomic_load(p, __ATOMIC_RELAXED, __HIP_MEMORY_SCOPE_AGENT);
}

// ---------------- precompute / casts ----------------

__global__ __launch_bounds__(256) void cast_kernel(const float* __restrict__ in,
                                                   unsigned short* __restrict__ out) {
  int i = blockIdx.x * 256 + threadIdx.x;
  float4 v = reinterpret_cast<const float4*>(in)[i];
  ushort4 o;
  o.x = f2bf(v.x); o.y = f2bf(v.y); o.z = f2bf(v.z); o.w = f2bf(v.w);
  reinterpret_cast<ushort4*>(out)[i] = o;
}

__global__ __launch_bounds__(256) void cast_hl_kernel(const float* __restrict__ in,
                                                      unsigned short* __restrict__ hi,
                                                      unsigned short* __restrict__ lo) {
  int i = blockIdx.x * 256 + threadIdx.x;
  float4 v = reinterpret_cast<const float4*>(in)[i];
  ushort4 h, l;
  h.x = f2bf(v.x); h.y = f2bf(v.y); h.z = f2bf(v.z); h.w = f2bf(v.w);
  l.x = f2bf(v.x - bfu(h.x)); l.y = f2bf(v.y - bfu(h.y));
  l.z = f2bf(v.z - bfu(h.z)); l.w = f2bf(v.w - bfu(h.w));
  reinterpret_cast<ushort4*>(hi)[i] = h;
  reinterpret_cast<ushort4*>(lo)[i] = l;
}

__global__ __launch_bounds__(256) void cast_wo_kernel(const float* __restrict__ in,
                                                      unsigned short* __restrict__ hi,
                                                      unsigned short* __restrict__ lo) {
  int idx = blockIdx.x * 256 + threadIdx.x;
  int row = idx >> 7;
  int k = (idx & 127) * 4;
  float4 v = (row < cV) ? *reinterpret_cast<const float4*>(&in[(size_t)row * cD + k])
                        : make_float4(0.f, 0.f, 0.f, 0.f);
  ushort4 h, l;
  h.x = f2bf(v.x); h.y = f2bf(v.y); h.z = f2bf(v.z); h.w = f2bf(v.w);
  l.x = f2bf(v.x - bfu(h.x)); l.y = f2bf(v.y - bfu(h.y));
  l.z = f2bf(v.z - bfu(h.z)); l.w = f2bf(v.w - bfu(h.w));
  reinterpret_cast<ushort4*>(hi)[idx] = h;
  reinterpret_cast<ushort4*>(lo)[idx] = l;
}

__global__ __launch_bounds__(256) void fert_kernel(const float* __restrict__ enc,
                                                   const float* __restrict__ W_fert,
                                                   float* __restrict__ inv_fert) {
  int wave = threadIdx.x >> 6, lane = threadIdx.x & 63;
  int row = blockIdx.x * 4 + wave;
  const float* r = enc + (size_t)row * cD;
  float s = 0.0f;
#pragma unroll
  for (int i = 0; i < 8; ++i) s += r[lane + 64 * i] * W_fert[lane + 64 * i];
#pragma unroll
  for (int o = 32; o; o >>= 1) s += __shfl_xor(s, o);
  if (lane == 0) inv_fert[row] = 1.0f / (1.0f + __expf(-s));
}

// shifted embeddings of labels -> hi/lo bf16 [4096][640]
__global__ __launch_bounds__(256) void build_aemb(const float* __restrict__ embed,
                                                  const int* __restrict__ labels,
                                                  unsigned short* __restrict__ Ah,
                                                  unsigned short* __restrict__ Al) {
  int idx = blockIdx.x * 256 + threadIdx.x;
  int row = idx / (cE / 4);
  int k = (idx % (cE / 4)) * 4;
  int b = row >> 6, tt = row & 63;
  float4 v = make_float4(0.f, 0.f, 0.f, 0.f);
  if (tt > 0) {
    int lab = labels[b * cN + tt - 1];
    v = *reinterpret_cast<const float4*>(&embed[(size_t)lab * cE + k]);
  }
  ushort4 h, l;
  h.x = f2bf(v.x); h.y = f2bf(v.y); h.z = f2bf(v.z); h.w = f2bf(v.w);
  l.x = f2bf(v.x - bfu(h.x)); l.y = f2bf(v.y - bfu(h.y));
  l.z = f2bf(v.z - bfu(h.z)); l.w = f2bf(v.w - bfu(h.w));
  *reinterpret_cast<ushort4*>(&Ah[(size_t)row * cE + k]) = h;
  *reinterpret_cast<ushort4*>(&Al[(size_t)row * cE + k]) = l;
}

// W_ih rows (i,g,o) x cols [0,640) -> hi/lo bf16 [3072][640] (for embg GEMM)
__global__ __launch_bounds__(256) void cast_wihe(const float* __restrict__ W_ih,
                                                 unsigned short* __restrict__ Wh,
                                                 unsigned short* __restrict__ Wl) {
  int idx = blockIdx.x * 256 + threadIdx.x;
  int jcol = idx / (cE / 4);
  int k = (idx % (cE / 4)) * 4;
  int r = (jcol < cH) ? jcol : jcol + cH;  // i: rows 0..1023; g: 2048..; o: 3072..
  float4 v = *reinterpret_cast<const float4*>(&W_ih[(size_t)r * (cE + cD) + k]);
  ushort4 h, l;
  h.x = f2bf(v.x); h.y = f2bf(v.y); h.z = f2bf(v.z); h.w = f2bf(v.w);
  l.x = f2bf(v.x - bfu(h.x)); l.y = f2bf(v.y - bfu(h.y));
  l.z = f2bf(v.z - bfu(h.z)); l.w = f2bf(v.w - bfu(h.w));
  *reinterpret_cast<ushort4*>(&Wh[(size_t)jcol * cE + k]) = h;
  *reinterpret_cast<ushort4*>(&Wl[(size_t)jcol * cE + k]) = l;
}

// W_ih ctx-half -> packed k-major bf16: WihP[(k4*3072 + col)*4 + (k&3)]
__global__ __launch_bounds__(256) void pack_wih(const float* __restrict__ W_ih,
                                                unsigned short* __restrict__ WihP) {
  int idx = blockIdx.x * 256 + threadIdx.x;   // col*128 + k4
  int col = idx >> 7;
  int k4 = idx & 127;
  int r = (col < cH) ? col : col + cH;
  float4 v = *reinterpret_cast<const float4*>(&W_ih[(size_t)r * (cE + cD) + cE + k4 * 4]);
  ushort4 h;
  h.x = f2bf(v.x); h.y = f2bf(v.y); h.z = f2bf(v.z); h.w = f2bf(v.w);
  *reinterpret_cast<ushort4*>(&WihP[((size_t)k4 * cG3 + col) * 4]) = h;
}

// W_s -> packed k-major bf16: WsP[(k4*1024 + a)*4 + (k&3)]
__global__ __launch_bounds__(256) void pack_ws(const float* __restrict__ W_s,
                                               unsigned short* __restrict__ WsP) {
  int idx = blockIdx.x * 256 + threadIdx.x;   // a*256 + k4
  int a = idx >> 8;
  int k4 = idx & 255;
  float4 v = *reinterpret_cast<const float4*>(&W_s[(size_t)a * cH + k4 * 4]);
  ushort4 h;
  h.x = f2bf(v.x); h.y = f2bf(v.y); h.z = f2bf(v.z); h.w = f2bf(v.w);
  *reinterpret_cast<ushort4*>(&WsP[((size_t)k4 * cA + a) * 4]) = h;
}

// concat(s_seq, emb, ctx_seq) -> Ar hi/lo bf16 [4096][2176]
__global__ __launch_bounds__(256) void build_ar_kernel(
    const float* __restrict__ s_seq, const float* __restrict__ ctx_seq,
    const float* __restrict__ embed, const int* __restrict__ labels,
    unsigned short* __restrict__ Ah, unsigned short* __restrict__ Al) {
  int idx = blockIdx.x * 256 + threadIdx.x;
  int row = idx / (cKr / 4);
  int k = (idx % (cKr / 4)) * 4;
  int b = row >> 6, tt = row & 63;
  float4 v;
  if (k < cH) {
    v = *reinterpret_cast<const float4*>(&s_seq[(size_t)row * cH + k]);
  } else if (k < cH + cE) {
    if (tt == 0) {
      v = make_float4(0.f, 0.f, 0.f, 0.f);
    } else {
      int lab = labels[b * cN + tt - 1];
      v = *reinterpret_cast<const float4*>(&embed[(size_t)lab * cE + (k - cH)]);
    }
  } else {
    v = *reinterpret_cast<const float4*>(&ctx_seq[(size_t)row * cD + (k - cH - cE)]);
  }
  ushort4 h, l;
  h.x = f2bf(v.x); h.y = f2bf(v.y); h.z = f2bf(v.z); h.w = f2bf(v.w);
  l.x = f2bf(v.x - bfu(h.x)); l.y = f2bf(v.y - bfu(h.y));
  l.z = f2bf(v.z - bfu(h.z)); l.w = f2bf(v.w - bfu(h.w));
  *reinterpret_cast<ushort4*>(&Ah[(size_t)row * cKr + k]) = h;
  *reinterpret_cast<ushort4*>(&Al[(size_t)row * cKr + k]) = l;
}

// ---------------- MFMA GEMMs ----------------

__global__ __launch_bounds__(256) void mfma_encctx(const unsigned short* __restrict__ A,
                                                   const unsigned short* __restrict__ Bm,
                                                   const float* __restrict__ bias,
                                                   unsigned short* __restrict__ C) {
  __shared__ unsigned short sA[4096], sB[4096];
  constexpr int nbx = cA / 128;
  int bid = xcd_swizzle(blockIdx.x, gridDim.x);
  int by = bid / nbx, bx = bid % nbx;
  int tid = threadIdx.x;
  int w = tid >> 6, l = tid & 63;
  int m0 = by * 128, n0 = bx * 128;
  int wr = w >> 1, wc = w & 1;
  f32x4 acc[4][4] = {};
  int srow = tid >> 2, scol = (tid & 3) * 8;
  for (int k0 = 0; k0 < cD; k0 += 32) {
    __syncthreads();
    GLD(&A[(size_t)(m0 + srow) * cD + k0 + scol], &sA[tid * 8]);
    GLD(&A[(size_t)(m0 + 64 + srow) * cD + k0 + scol], &sA[2048 + tid * 8]);
    GLD(&Bm[(size_t)(n0 + srow) * cD + k0 + scol], &sB[tid * 8]);
    GLD(&Bm[(size_t)(n0 + 64 + srow) * cD + k0 + scol], &sB[2048 + tid * 8]);
    __syncthreads();
    int rA = wr * 64 + (l & 15);
    int rB = wc * 64 + (l & 15);
    int kg = (l >> 4) * 8;
    bf16x8 a[4], b[4];
#pragma unroll
    for (int i = 0; i < 4; ++i) a[i] = *(const bf16x8*)&sA[(rA + i * 16) * 32 + kg];
#pragma unroll
    for (int j = 0; j < 4; ++j) b[j] = *(const bf16x8*)&sB[(rB + j * 16) * 32 + kg];
#pragma unroll
    for (int i = 0; i < 4; ++i)
#pragma unroll
      for (int j = 0; j < 4; ++j)
        acc[i][j] = __builtin_amdgcn_mfma_f32_16x16x32_bf16(a[i], b[j], acc[i][j], 0, 0, 0);
  }
  int rbase = m0 + wr * 64 + ((l >> 4) * 4);
  int cbase = n0 + wc * 64 + (l & 15);
  float bv[4];
#pragma unroll
  for (int j = 0; j < 4; ++j) bv[j] = bias[cbase + j * 16];
#pragma unroll
  for (int i = 0; i < 4; ++i)
#pragma unroll
    for (int q = 0; q < 4; ++q) {
      int row = rbase + i * 16 + q;
#pragma unroll
      for (int j = 0; j < 4; ++j)
        C[(size_t)row * cA + cbase + j * 16] = f2bf(acc[i][j][q] + bv[j]);
    }
}

template <int EP>
__global__ __launch_bounds__(256) void mfma_gemm3(
    const unsigned short* __restrict__ Ah, const unsigned short* __restrict__ Al,
    const unsigned short* __restrict__ Bh, const unsigned short* __restrict__ Bl,
    const float* __restrict__ bias, void* __restrict__ outv, int K, int nbx) {
  __shared__ unsigned short sAh[4096], sAl[4096], sBh[4096], sBl[4096];
  int bid = xcd_swizzle(blockIdx.x, gridDim.x);
  int by = bid / nbx, bx = bid % nbx;
  int tid = threadIdx.x;
  int w = tid >> 6, l = tid & 63;
  int m0 = by * 128, n0 = bx * 128;
  int wr = w >> 1, wc = w & 1;
  f32x4 acc[4][4] = {};
  int srow = tid >> 2, scol = (tid & 3) * 8;
  for (int k0 = 0; k0 < K; k0 += 32) {
    __syncthreads();
    GLD(&Ah[(size_t)(m0 + srow) * K + k0 + scol], &sAh[tid * 8]);
    GLD(&Ah[(size_t)(m0 + 64 + srow) * K + k0 + scol], &sAh[2048 + tid * 8]);
    GLD(&Al[(size_t)(m0 + srow) * K + k0 + scol], &sAl[tid * 8]);
    GLD(&Al[(size_t)(m0 + 64 + srow) * K + k0 + scol], &sAl[2048 + tid * 8]);
    GLD(&Bh[(size_t)(n0 + srow) * K + k0 + scol], &sBh[tid * 8]);
    GLD(&Bh[(size_t)(n0 + 64 + srow) * K + k0 + scol], &sBh[2048 + tid * 8]);
    GLD(&Bl[(size_t)(n0 + srow) * K + k0 + scol], &sBl[tid * 8]);
    GLD(&Bl[(size_t)(n0 + 64 + srow) * K + k0 + scol], &sBl[2048 + tid * 8]);
    __syncthreads();
    int rA = wr * 64 + (l & 15);
    int rB = wc * 64 + (l & 15);
    int kg = (l >> 4) * 8;
    bf16x8 bh[4], bl[4];
#pragma unroll
    for (int j = 0; j < 4; ++j) {
      bh[j] = *(const bf16x8*)&sBh[(rB + j * 16) * 32 + kg];
      bl[j] = *(const bf16x8*)&sBl[(rB + j * 16) * 32 + kg];
    }
#pragma unroll
    for (int i = 0; i < 4; ++i) {
      bf16x8 ah = *(const bf16x8*)&sAh[(rA + i * 16) * 32 + kg];
      bf16x8 al = *(const bf16x8*)&sAl[(rA + i * 16) * 32 + kg];
#pragma unroll
      for (int j = 0; j < 4; ++j) {
        acc[i][j] = __builtin_amdgcn_mfma_f32_16x16x32_bf16(ah, bh[j], acc[i][j], 0, 0, 0);
        acc[i][j] = __builtin_amdgcn_mfma_f32_16x16x32_bf16(ah, bl[j], acc[i][j], 0, 0, 0);
        acc[i][j] = __builtin_amdgcn_mfma_f32_16x16x32_bf16(al, bh[j], acc[i][j], 0, 0, 0);
        if (EP == 2)
          acc[i][j] = __builtin_amdgcn_mfma_f32_16x16x32_bf16(al, bl[j], acc[i][j], 0, 0, 0);
      }
    }
  }
  int rbase = m0 + wr * 64 + ((l >> 4) * 4);
  int cbase = n0 + wc * 64 + (l & 15);
  if (EP == 0) {
    unsigned short* mo_h = (unsigned short*)outv;
    unsigned short* mo_l = mo_h + (size_t)cM * (cP / 2);
#pragma unroll
    for (int i = 0; i < 4; ++i)
#pragma unroll
      for (int q = 0; q < 4; ++q) {
        int row = rbase + i * 16 + q;
#pragma unroll
        for (int j = 0; j < 4; ++j) {
          float v = acc[i][j][q] + bias[cbase + j * 16];
          float o = fmaxf(v, __shfl_xor(v, 1));
          if (!(l & 1)) {
            int ch = (cbase + j * 16) >> 1;
            unsigned short h = f2bf(o);
            mo_h[(size_t)row * (cP / 2) + ch] = h;
            mo_l[(size_t)row * (cP / 2) + ch] = f2bf(o - bfu(h));
          }
        }
      }
  } else if (EP == 1) {
    float* out = (float*)outv;
#pragma unroll
    for (int i = 0; i < 4; ++i)
#pragma unroll
      for (int q = 0; q < 4; ++q) {
        int row = rbase + i * 16 + q;
#pragma unroll
        for (int j = 0; j < 4; ++j) {
          int col = cbase + j * 16;
          if (col < cV) out[(size_t)row * cV + col] = acc[i][j][q] + bias[col];
        }
      }
  } else {
    float* out = (float*)outv;  // embg [4096 rows][3072]
#pragma unroll
    for (int i = 0; i < 4; ++i)
#pragma unroll
      for (int q = 0; q < 4; ++q) {
        int row = rbase + i * 16 + q;
#pragma unroll
        for (int j = 0; j < 4; ++j)
          out[(size_t)row * cG3 + cbase + j * 16] = acc[i][j][q];
      }
  }
}

// ---------------- split fused loop: 4 blocks per batch, all 256 CUs ----------------

struct LoopArgs {
  const unsigned short* enc_ctx;  // bf16 [38400][1024]
  const unsigned short* enc_bf;   // bf16 [38400][512]
  const unsigned short* WihP;     // packed [128][3072][4] bf16 (k-major)
  const unsigned short* WsP;      // packed [256][1024][4] bf16 (k-major)
  const float* b_ih;
  const float* b_hh;
  const float* embg;              // fp32 [4096][3072]
  const float* inv_fert;          // [38400]
  const float* v_att;
  const float* W_fb;
  const int* slen;
  float* s_seq;                   // [4096][1024]
  float* ctx_seq;                 // [4096][512]
  float* xh;                      // [2][64][1024]  h exchange
  float* xq;                      // [2][64][1024]  q exchange
  float* xc;                      // [2][64][4][516] softmax partials
  unsigned* cnt;                  // [3][64][64] arrival counters (256B stride)
};

__global__ __launch_bounds__(1024, 1) void split_loop(LoopArgs A) {
  __shared__ float ctx_s[cD];
  __shared__ float h_s[cH];
  __shared__ float q_s[cA];
  __shared__ float ew_s[cTQ];
  __shared__ float acc_s[cTQ];
  __shared__ float fert_s[cTQ];
  __shared__ float vatt_s[cA];
  __shared__ float wfb_s[cA];
  __shared__ float cpart[2][cD];
  __shared__ float red_s[16];
  __shared__ float ms_s[8];   // m_i, s_i of the 4 quarters

  // same-quarter blocks grouped per XCD (assumes round-robin bid->XCD; perf-only)
  const int xcd = blockIdx.x & 7, idx = blockIdx.x >> 3;
  const int qd = xcd >> 1;                    // T/j/a quarter 0..3
  const int b = (xcd & 1) * 32 + idx;         // batch 0..63
  const int tid = threadIdx.x;
  const int wv = tid >> 6, ln = tid & 63;
  const int jl = tid >> 2, part = tid & 3;    // 256 outputs x 4 k-parts
  const int q0 = qd * 256;
  const int len = A.slen[b];
  unsigned* cntH = A.cnt + (0 * cB + b) * 64;
  unsigned* cntQ = A.cnt + (1 * cB + b) * 64;
  unsigned* cntS = A.cnt + (2 * cB + b) * 64;

  // init
  if (tid < cD) ctx_s[tid] = 0.f;
  vatt_s[tid] = A.v_att[tid];
  wfb_s[tid] = A.W_fb[tid];
  if (tid < cTQ) {
    acc_s[tid] = 0.f;
    fert_s[tid] = A.inv_fert[b * cT + qd * cTQ + tid];
  }
  float h_my = 0.f, bgi = 0.f, bgg = 0.f, bgo = 0.f;
  if (part == 0) {
    int j = q0 + jl;
    bgi = A.b_ih[j] + A.b_hh[j];
    bgg = A.b_ih[j + 2048] + A.b_hh[j + 2048];
    bgo = A.b_ih[j + 3072] + A.b_hh[j + 3072];
  }
  __syncthreads();

  for (int t = 0; t < cN; ++t) {
    const int par = t & 1;
    const unsigned tgt = 4u * (t + 1);

    // ---- P1: h for j-quarter (thread group of 4 splits k) ----
    {
      float ai = 0.f, ag = 0.f, ao = 0.f;
      const unsigned short* pw = A.WihP + ((size_t)(part * 32) * cG3 + (q0 + jl)) * 4;
#pragma unroll 4
      for (int k4 = 0; k4 < 32; ++k4) {
        float4 c = *reinterpret_cast<const float4*>(&ctx_s[(part * 32 + k4) * 4]);
        ushort4 wi = *reinterpret_cast<const ushort4*>(pw);
        ushort4 wg = *reinterpret_cast<const ushort4*>(pw + (size_t)1024 * 4);
        ushort4 wo = *reinterpret_cast<const ushort4*>(pw + (size_t)2048 * 4);
        ai += bfu(wi.x) * c.x + bfu(wi.y) * c.y + bfu(wi.z) * c.z + bfu(wi.w) * c.w;
        ag += bfu(wg.x) * c.x + bfu(wg.y) * c.y + bfu(wg.z) * c.z + bfu(wg.w) * c.w;
        ao += bfu(wo.x) * c.x + bfu(wo.y) * c.y + bfu(wo.z) * c.z + bfu(wo.w) * c.w;
        pw += (size_t)cG3 * 4;
      }
      ai += __shfl_xor(ai, 1); ai += __shfl_xor(ai, 2);
      ag += __shfl_xor(ag, 1); ag += __shfl_xor(ag, 2);
      ao += __shfl_xor(ao, 1); ao += __shfl_xor(ao, 2);
      if (part == 0) {
        int j = q0 + jl;
        const float* eg = A.embg + (size_t)(b * cN + t) * cG3;
        float gi = ai + bgi + eg[j];
        float gg = ag + bgg + eg[j + 1024];
        float go = ao + bgo + eg[j + 2048];
        float hnew = fsig(go) * ftanh(fsig(gi) * ftanh(gg));
        h_my = 0.05f * h_my + 0.95f * hnew;
        A.s_seq[(size_t)(b * cN + t) * cH + j] = h_my;
        ast(&A.xh[((size_t)par * cB + b) * cH + j], h_my);
      }
    }
    __syncthreads();
    if (tid == 0) {
      __hip_atomic_fetch_add(cntH, 1u, __ATOMIC_RELEASE, __HIP_MEMORY_SCOPE_AGENT);
      while (__hip_atomic_load(cntH, __ATOMIC_ACQUIRE, __HIP_MEMORY_SCOPE_AGENT) < tgt)
        __builtin_amdgcn_s_sleep(2);
    }
    __syncthreads();
    h_s[tid] = ald(&A.xh[((size_t)par * cB + b) * cH + tid]);
    __syncthreads();

    // ---- P2: q for a-quarter ----
    {
      float aq = 0.f;
      const unsigned short* pw = A.WsP + ((size_t)(part * 64) * cA + (q0 + jl)) * 4;
#pragma unroll 4
      for (int k4 = 0; k4 < 64; ++k4) {
        float4 hh = *reinterpret_cast<const float4*>(&h_s[(part * 64 + k4) * 4]);
        ushort4 w = *reinterpret_cast<const ushort4*>(pw);
        aq += bfu(w.x) * hh.x + bfu(w.y) * hh.y + bfu(w.z) * hh.z + bfu(w.w) * hh.w;
        pw += (size_t)cA * 4;
      }
      aq += __shfl_xor(aq, 1); aq += __shfl_xor(aq, 2);
      if (part == 0) ast(&A.xq[((size_t)par * cB + b) * cA + q0 + jl], aq);
    }
    __syncthreads();
    if (tid == 0) {
      __hip_atomic_fetch_add(cntQ, 1u, __ATOMIC_RELEASE, __HIP_MEMORY_SCOPE_AGENT);
      while (__hip_atomic_load(cntQ, __ATOMIC_ACQUIRE, __HIP_MEMORY_SCOPE_AGENT) < tgt)
        __builtin_amdgcn_s_sleep(2);
    }
    __syncthreads();
    q_s[tid] = ald(&A.xq[((size_t)par * cB + b) * cA + tid]);
    __syncthreads();

    // ---- P3: energies for T-quarter ----
    for (int i = wv; i < cTQ; i += 16) {
      int tt = qd * cTQ + i;
      if (tt >= len) {
        if (ln == 0) ew_s[i] = -__builtin_inff();
        continue;
      }
      float fb = acc_s[i];
      const unsigned short* row = A.enc_ctx + (size_t)(b * cT + tt) * cA + 2 * ln;
      float acc = 0.f;
#pragma unroll
      for (int k2 = 0; k2 < 8; ++k2) {
        int a0 = 2 * ln + 128 * k2;
        unsigned int u = *reinterpret_cast<const unsigned int*>(row + 128 * k2);
        float c0 = __uint_as_float(u << 16);
        float c1 = __uint_as_float(u & 0xffff0000u);
        acc += vatt_s[a0] * ftanh(c0 + q_s[a0] + fb * wfb_s[a0]);
        acc += vatt_s[a0 + 1] * ftanh(c1 + q_s[a0 + 1] + fb * wfb_s[a0 + 1]);
      }
#pragma unroll
      for (int o = 32; o; o >>= 1) acc += __shfl_xor(acc, o);
      if (ln == 0) ew_s[i] = acc;
    }
    __syncthreads();

    // ---- local softmax over own quarter ----
    float m_loc;
    {
      float m = (tid < cTQ) ? ew_s[tid] : -__builtin_inff();
#pragma unroll
      for (int o = 32; o; o >>= 1) m = fmaxf(m, __shfl_xor(m, o));
      if (ln == 0) red_s[wv] = m;
      __syncthreads();
      m = red_s[0];
#pragma unroll
      for (int w2 = 1; w2 < 16; ++w2) m = fmaxf(m, red_s[w2]);
      m_loc = m;
      __syncthreads();   // red_s reuse below
      float wn = 0.f;
      if (tid < cTQ) {
        float e = ew_s[tid];
        if (e > -__builtin_inff()) wn = __expf(e - m_loc);
        ew_s[tid] = wn;
      }
      float sp = wn;
#pragma unroll
      for (int o = 32; o; o >>= 1) sp += __shfl_xor(sp, o);
      if (ln == 0) red_s[wv] = sp;
      __syncthreads();
    }
    float s_loc = red_s[0];
#pragma unroll
    for (int w2 = 1; w2 < 16; ++w2) s_loc += red_s[w2];
    __syncthreads();

    // ---- partial ctx over own quarter ----
    {
      int d = (wv & 7) * 64 + ln;
      int half = wv >> 3;
      const unsigned short* eb =
          A.enc_bf + ((size_t)b * cT + qd * cTQ + half * 75) * cD + d;
      float s0 = 0.f;
      for (int i = 0; i < 75; ++i) {
        float wgt = ew_s[half * 75 + i];
        if (wgt != 0.f) s0 += wgt * bfu(eb[(size_t)i * cD]);
      }
      cpart[half][d] = s0;
    }
    __syncthreads();
    {
      float* xcb = A.xc + (((size_t)par * cB + b) * 4 + qd) * cXCS;
      if (tid < cD) ast(&xcb[2 + tid], cpart[0][tid] + cpart[1][tid]);
      if (tid == 0) ast(&xcb[0], m_loc);
      if (tid == 1) ast(&xcb[1], s_loc);
    }
    __syncthreads();
    if (tid == 0) {
      __hip_atomic_fetch_add(cntS, 1u, __ATOMIC_RELEASE, __HIP_MEMORY_SCOPE_AGENT);
      while (__hip_atomic_load(cntS, __ATOMIC_ACQUIRE, __HIP_MEMORY_SCOPE_AGENT) < tgt)
        __builtin_amdgcn_s_sleep(2);
    }
    __syncthreads();

    // ---- combine: M, tot, full ctx; accum update ----
    if (tid < 8) {
      ms_s[tid] =
          ald(&A.xc[(((size_t)par * cB + b) * 4 + (tid >> 1)) * cXCS + (tid & 1)]);
    }
    __syncthreads();
    {
      float M = fmaxf(fmaxf(ms_s[0], ms_s[2]), fmaxf(ms_s[4], ms_s[6]));
      float sc0 = __expf(ms_s[0] - M), sc1 = __expf(ms_s[2] - M);
      float sc2 = __expf(ms_s[4] - M), sc3 = __expf(ms_s[6] - M);
      float tot = ms_s[1] * sc0 + ms_s[3] * sc1 + ms_s[5] * sc2 + ms_s[7] * sc3;
      float invt = 1.0f / tot;
      if (tid < cD) {
        const float* xcb = A.xc + ((size_t)par * cB + b) * 4 * cXCS;
        float cv = ald(&xcb[2 + tid]) * sc0 + ald(&xcb[cXCS + 2 + tid]) * sc1 +
                   ald(&xcb[2 * cXCS + 2 + tid]) * sc2 +
                   ald(&xcb[3 * cXCS + 2 + tid]) * sc3;
        cv *= invt;
        ctx_s[tid] = cv;
        if (qd == 0) A.ctx_seq[(size_t)(b * cN + t) * cD + tid] = cv;
      } else {
        int i = tid - 512;
        if (i < cTQ) {
          float scq = __expf(m_loc - M);
          acc_s[i] += ew_s[i] * scq * invt * fert_s[i] * 0.5f;
        }
      }
    }
    __syncthreads();
  }
}

// ---------------- launcher ----------------

extern "C" void kernel_launch(void* const* d_in, const int* in_sizes, int n_in,
                              void* d_out, int out_size, void* d_ws, size_t ws_size,
                              hipStream_t stream) {
  (void)in_sizes; (void)n_in; (void)out_size; (void)ws_size;
  const float* enc    = (const float*)d_in[0];
  const int*   labels = (const int*)d_in[1];
  const int*   slen   = (const int*)d_in[2];
  const float* embed  = (const float*)d_in[3];
  const float* W_ih   = (const float*)d_in[4];
  const float* b_ih   = (const float*)d_in[5];
  const float* b_hh   = (const float*)d_in[6];
  const float* W_s    = (const float*)d_in[7];
  const float* W_enc  = (const float*)d_in[8];
  const float* b_enc  = (const float*)d_in[9];
  const float* v_att  = (const float*)d_in[10];
  const float* W_fert = (const float*)d_in[11];
  const float* W_fb   = (const float*)d_in[12];
  const float* W_r    = (const float*)d_in[13];
  const float* b_r    = (const float*)d_in[14];
  const float* W_o    = (const float*)d_in[15];
  const float* b_o    = (const float*)d_in[16];
  float* out = (float*)d_out;

  char* ws = (char*)d_ws;
  size_t off = 0;
  auto alloc = [&](size_t bytes) -> char* {
    char* p = ws + off;
    off = (off + bytes + 255) & ~(size_t)255;
    return p;
  };
  unsigned short* enc_ctx = (unsigned short*)alloc((size_t)cBT * cA * 2);
  unsigned short* enc_bf  = (unsigned short*)alloc((size_t)cBT * cD * 2);
  unsigned short* wencb   = (unsigned short*)alloc((size_t)cA * cD * 2);
  float* inv_fert = (float*)alloc((size_t)cBT * 4);
  unsigned short* WihP = (unsigned short*)alloc((size_t)cD * cG3 * 2);
  unsigned short* WsP  = (unsigned short*)alloc((size_t)cH * cA * 2);
  float* embg     = (float*)alloc((size_t)cM * cG3 * 4);
  float* s_seq    = (float*)alloc((size_t)cM * cH * 4);
  float* ctx_seq  = (float*)alloc((size_t)cM * cD * 4);
  float* xh       = (float*)alloc((size_t)2 * cB * cH * 4);
  float* xq       = (float*)alloc((size_t)2 * cB * cA * 4);
  float* xc       = (float*)alloc((size_t)2 * cB * 4 * cXCS * 4);
  unsigned* cnt   = (unsigned*)alloc((size_t)3 * cB * 64 * 4);
  unsigned short* Aemb_h = (unsigned short*)alloc((size_t)cM * cE * 2);
  unsigned short* Aemb_l = (unsigned short*)alloc((size_t)cM * cE * 2);
  unsigned short* Wihe_h = (unsigned short*)alloc((size_t)cG3 * cE * 2);
  unsigned short* Wihe_l = (unsigned short*)alloc((size_t)cG3 * cE * 2);
  unsigned short* Ar_h = (unsigned short*)alloc((size_t)cM * cKr * 2);
  unsigned short* Ar_l = (unsigned short*)alloc((size_t)cM * cKr * 2);
  unsigned short* Wr_h = (unsigned short*)alloc((size_t)cP * cKr * 2);
  unsigned short* Wr_l = (unsigned short*)alloc((size_t)cP * cKr * 2);
  unsigned short* mo_hl = (unsigned short*)alloc((size_t)2 * cM * (cP / 2) * 2);
  unsigned short* Wo_h = (unsigned short*)alloc((size_t)cVp * cD * 2);
  unsigned short* Wo_l = (unsigned short*)alloc((size_t)cVp * cD * 2);

  hipMemsetAsync(cnt, 0, (size_t)3 * cB * 64 * 4, stream);

  cast_kernel<<<(cBT * cD) / 1024, 256, 0, stream>>>(enc, enc_bf);
  cast_kernel<<<(cA * cD) / 1024, 256, 0, stream>>>(W_enc, wencb);
  fert_kernel<<<cBT / 4, 256, 0, stream>>>(enc, W_fert, inv_fert);
  mfma_encctx<<<(cBT / 128) * (cA / 128), 256, 0, stream>>>(enc_bf, wencb, b_enc, enc_ctx);
  build_aemb<<<(cM * cE / 4) / 256, 256, 0, stream>>>(embed, labels, Aemb_h, Aemb_l);
  cast_wihe<<<(cG3 * cE / 4) / 256, 256, 0, stream>>>(W_ih, Wihe_h, Wihe_l);
  pack_wih<<<(cG3 * (cD / 4)) / 256, 256, 0, stream>>>(W_ih, WihP);
  pack_ws<<<(cA * (cH / 4)) / 256, 256, 0, stream>>>(W_s, WsP);
  cast_hl_kernel<<<(cP * cKr) / 1024, 256, 0, stream>>>(W_r, Wr_h, Wr_l);
  cast_wo_kernel<<<(cVp * cD) / 1024, 256, 0, stream>>>(W_o, Wo_h, Wo_l);
  mfma_gemm3<2><<<(cM / 128) * (cG3 / 128), 256, 0, stream>>>(
      Aemb_h, Aemb_l, Wihe_h, Wihe_l, nullptr, (void*)embg, cE, cG3 / 128);

  LoopArgs la;
  la.enc_ctx = enc_ctx; la.enc_bf = enc_bf; la.WihP = WihP; la.WsP = WsP;
  la.b_ih = b_ih; la.b_hh = b_hh; la.embg = embg; la.inv_fert = inv_fert;
  la.v_att = v_att; la.W_fb = W_fb; la.slen = slen;
  la.s_seq = s_seq; la.ctx_seq = ctx_seq;
  la.xh = xh; la.xq = xq; la.xc = xc; la.cnt = cnt;
  split_loop<<<dim3(256), dim3(1024), 0, stream>>>(la);

  build_ar_kernel<<<(cM * cKr) / 1024, 256, 0, stream>>>(s_seq, ctx_seq, embed, labels,
                                                         Ar_h, Ar_l);
  mfma_gemm3<0><<<(cM / 128) * (cP / 128), 256, 0, stream>>>(Ar_h, Ar_l, Wr_h, Wr_l, b_r,
                                                             (void*)mo_hl, cKr, cP / 128);
  unsigned short* mo_h = mo_hl;
  unsigned short* mo_l = mo_hl + (size_t)cM * (cP / 2);
  mfma_gemm3<1><<<(cM / 128) * (cVp / 128), 256, 0, stream>>>(mo_h, mo_l, Wo_h, Wo_l, b_o,
                                                              (void*)out, cP / 2, cVp / 128);
}

// Round 8
// 8504.398 us; speedup vs baseline: 5.0347x; 1.1796x over previous
//
#include <hip/hip_runtime.h>
#include <math.h>

constexpr int cB = 64, cT = 600, cD = 512, cE = 640, cH = 1024, cA = 1024,
              cP = 1024, cV = 10025, cN = 64;
constexpr int cBT = cB * cT;       // 38400
constexpr int cKr = cH + cE + cD;  // 2176
constexpr int cM  = cB * cN;       // 4096
constexpr int cVp = 10112;         // V padded to 79*128
constexpr int cG3 = 3 * cH;        // 3072 (i,g,o)
constexpr int cTQ = cT / 4;        // 150 rows per block (interleaved: tt = 4*i + qd)
constexpr int cXCS = 516;          // xc stride: m, s, c[512], pad

typedef __attribute__((ext_vector_type(8))) short bf16x8;
typedef __attribute__((ext_vector_type(4))) float f32x4;

__device__ __forceinline__ float bfu(unsigned short s) {
  return __uint_as_float(((unsigned int)s) << 16);
}
__device__ __forceinline__ unsigned short f2bf(float f) {
  unsigned int x = __float_as_uint(f);
  x += 0x7fffu + ((x >> 16) & 1u);
  return (unsigned short)(x >> 16);
}
__device__ __forceinline__ float fsig(float x) { return 1.0f / (1.0f + __expf(-x)); }
__device__ __forceinline__ float ftanh(float x) {
  float e = __expf(2.0f * x);
  return 1.0f - 2.0f / (e + 1.0f);
}

#define GLD(g, s)                                                          \
  __builtin_amdgcn_global_load_lds(                                       \
      (const __attribute__((address_space(1))) void*)(g),                 \
      (__attribute__((address_space(3))) void*)(s), 16, 0, 0)

__device__ __forceinline__ int xcd_swizzle(int bid, int nwg) {
  int q = nwg >> 3, r = nwg & 7;
  int x = bid & 7, loc = bid >> 3;
  return (x < r ? x * (q + 1) : r * (q + 1) + (x - r) * q) + loc;
}

// device-scope message passing (round-7-verified pattern)
__device__ __forceinline__ void ast(float* p, float v) {
  __hip_atomic_store(p, v, __ATOMIC_RELAXED, __HIP_MEMORY_SCOPE_AGENT);
}
__device__ __forceinline__ float ald(const float* p) {
  return __hip_atomic_load(p, __ATOMIC_RELAXED, __HIP_MEMORY_SCOPE_AGENT);
}
__device__ __forceinline__ void arrive_wait(unsigned* c, unsigned target) {
  __syncthreads();
  if (threadIdx.x == 0) {
    __hip_atomic_fetch_add(c, 1u, __ATOMIC_RELEASE, __HIP_MEMORY_SCOPE_AGENT);
    while (__hip_atomic_load(c, __ATOMIC_ACQUIRE, __HIP_MEMORY_SCOPE_AGENT) < target)
      __builtin_amdgcn_s_sleep(2);
  }
  __syncthreads();
}

// ---------------- precompute / casts ----------------

__global__ __launch_bounds__(256) void cast_kernel(const float* __restrict__ in,
                                                   unsigned short* __restrict__ out) {
  int i = blockIdx.x * 256 + threadIdx.x;
  float4 v = reinterpret_cast<const float4*>(in)[i];
  ushort4 o;
  o.x = f2bf(v.x); o.y = f2bf(v.y); o.z = f2bf(v.z); o.w = f2bf(v.w);
  reinterpret_cast<ushort4*>(out)[i] = o;
}

__global__ __launch_bounds__(256) void cast_hl_kernel(const float* __restrict__ in,
                                                      unsigned short* __restrict__ hi,
                                                      unsigned short* __restrict__ lo) {
  int i = blockIdx.x * 256 + threadIdx.x;
  float4 v = reinterpret_cast<const float4*>(in)[i];
  ushort4 h, l;
  h.x = f2bf(v.x); h.y = f2bf(v.y); h.z = f2bf(v.z); h.w = f2bf(v.w);
  l.x = f2bf(v.x - bfu(h.x)); l.y = f2bf(v.y - bfu(h.y));
  l.z = f2bf(v.z - bfu(h.z)); l.w = f2bf(v.w - bfu(h.w));
  reinterpret_cast<ushort4*>(hi)[i] = h;
  reinterpret_cast<ushort4*>(lo)[i] = l;
}

__global__ __launch_bounds__(256) void cast_wo_kernel(const float* __restrict__ in,
                                                      unsigned short* __restrict__ hi,
                                                      unsigned short* __restrict__ lo) {
  int idx = blockIdx.x * 256 + threadIdx.x;
  int row = idx >> 7;
  int k = (idx & 127) * 4;
  float4 v = (row < cV) ? *reinterpret_cast<const float4*>(&in[(size_t)row * cD + k])
                        : make_float4(0.f, 0.f, 0.f, 0.f);
  ushort4 h, l;
  h.x = f2bf(v.x); h.y = f2bf(v.y); h.z = f2bf(v.z); h.w = f2bf(v.w);
  l.x = f2bf(v.x - bfu(h.x)); l.y = f2bf(v.y - bfu(h.y));
  l.z = f2bf(v.z - bfu(h.z)); l.w = f2bf(v.w - bfu(h.w));
  reinterpret_cast<ushort4*>(hi)[idx] = h;
  reinterpret_cast<ushort4*>(lo)[idx] = l;
}

__global__ __launch_bounds__(256) void fert_kernel(const float* __restrict__ enc,
                                                   const float* __restrict__ W_fert,
                                                   float* __restrict__ inv_fert) {
  int wave = threadIdx.x >> 6, lane = threadIdx.x & 63;
  int row = blockIdx.x * 4 + wave;
  const float* r = enc + (size_t)row * cD;
  float s = 0.0f;
#pragma unroll
  for (int i = 0; i < 8; ++i) s += r[lane + 64 * i] * W_fert[lane + 64 * i];
#pragma unroll
  for (int o = 32; o; o >>= 1) s += __shfl_xor(s, o);
  if (lane == 0) inv_fert[row] = 1.0f / (1.0f + __expf(-s));
}

// shifted embeddings of labels -> hi/lo bf16 [4096][640]
__global__ __launch_bounds__(256) void build_aemb(const float* __restrict__ embed,
                                                  const int* __restrict__ labels,
                                                  unsigned short* __restrict__ Ah,
                                                  unsigned short* __restrict__ Al) {
  int idx = blockIdx.x * 256 + threadIdx.x;
  int row = idx / (cE / 4);
  int k = (idx % (cE / 4)) * 4;
  int b = row >> 6, tt = row & 63;
  float4 v = make_float4(0.f, 0.f, 0.f, 0.f);
  if (tt > 0) {
    int lab = labels[b * cN + tt - 1];
    v = *reinterpret_cast<const float4*>(&embed[(size_t)lab * cE + k]);
  }
  ushort4 h, l;
  h.x = f2bf(v.x); h.y = f2bf(v.y); h.z = f2bf(v.z); h.w = f2bf(v.w);
  l.x = f2bf(v.x - bfu(h.x)); l.y = f2bf(v.y - bfu(h.y));
  l.z = f2bf(v.z - bfu(h.z)); l.w = f2bf(v.w - bfu(h.w));
  *reinterpret_cast<ushort4*>(&Ah[(size_t)row * cE + k]) = h;
  *reinterpret_cast<ushort4*>(&Al[(size_t)row * cE + k]) = l;
}

// W_ih rows (i,g,o) x cols [0,640) -> hi/lo bf16 [3072][640] (for embg GEMM)
__global__ __launch_bounds__(256) void cast_wihe(const float* __restrict__ W_ih,
                                                 unsigned short* __restrict__ Wh,
                                                 unsigned short* __restrict__ Wl) {
  int idx = blockIdx.x * 256 + threadIdx.x;
  int jcol = idx / (cE / 4);
  int k = (idx % (cE / 4)) * 4;
  int r = (jcol < cH) ? jcol : jcol + cH;
  float4 v = *reinterpret_cast<const float4*>(&W_ih[(size_t)r * (cE + cD) + k]);
  ushort4 h, l;
  h.x = f2bf(v.x); h.y = f2bf(v.y); h.z = f2bf(v.z); h.w = f2bf(v.w);
  l.x = f2bf(v.x - bfu(h.x)); l.y = f2bf(v.y - bfu(h.y));
  l.z = f2bf(v.z - bfu(h.z)); l.w = f2bf(v.w - bfu(h.w));
  *reinterpret_cast<ushort4*>(&Wh[(size_t)jcol * cE + k]) = h;
  *reinterpret_cast<ushort4*>(&Wl[(size_t)jcol * cE + k]) = l;
}

// W_ih ctx-half -> packed k-major bf16: WihP[(k4*3072 + col)*4 + (k&3)]
__global__ __launch_bounds__(256) void pack_wih(const float* __restrict__ W_ih,
                                                unsigned short* __restrict__ WihP) {
  int idx = blockIdx.x * 256 + threadIdx.x;
  int col = idx >> 7;
  int k4 = idx & 127;
  int r = (col < cH) ? col : col + cH;
  float4 v = *reinterpret_cast<const float4*>(&W_ih[(size_t)r * (cE + cD) + cE + k4 * 4]);
  ushort4 h;
  h.x = f2bf(v.x); h.y = f2bf(v.y); h.z = f2bf(v.z); h.w = f2bf(v.w);
  *reinterpret_cast<ushort4*>(&WihP[((size_t)k4 * cG3 + col) * 4]) = h;
}

// W_s -> packed k-major bf16: WsP[(k4*1024 + a)*4 + (k&3)]
__global__ __launch_bounds__(256) void pack_ws(const float* __restrict__ W_s,
                                               unsigned short* __restrict__ WsP) {
  int idx = blockIdx.x * 256 + threadIdx.x;
  int a = idx >> 8;
  int k4 = idx & 255;
  float4 v = *reinterpret_cast<const float4*>(&W_s[(size_t)a * cH + k4 * 4]);
  ushort4 h;
  h.x = f2bf(v.x); h.y = f2bf(v.y); h.z = f2bf(v.z); h.w = f2bf(v.w);
  *reinterpret_cast<ushort4*>(&WsP[((size_t)k4 * cA + a) * 4]) = h;
}

// concat(s_seq, emb, ctx_seq) -> Ar hi/lo bf16 [4096][2176]
__global__ __launch_bounds__(256) void build_ar_kernel(
    const float* __restrict__ s_seq, const float* __restrict__ ctx_seq,
    const float* __restrict__ embed, const int* __restrict__ labels,
    unsigned short* __restrict__ Ah, unsigned short* __restrict__ Al) {
  int idx = blockIdx.x * 256 + threadIdx.x;
  int row = idx / (cKr / 4);
  int k = (idx % (cKr / 4)) * 4;
  int b = row >> 6, tt = row & 63;
  float4 v;
  if (k < cH) {
    v = *reinterpret_cast<const float4*>(&s_seq[(size_t)row * cH + k]);
  } else if (k < cH + cE) {
    if (tt == 0) {
      v = make_float4(0.f, 0.f, 0.f, 0.f);
    } else {
      int lab = labels[b * cN + tt - 1];
      v = *reinterpret_cast<const float4*>(&embed[(size_t)lab * cE + (k - cH)]);
    }
  } else {
    v = *reinterpret_cast<const float4*>(&ctx_seq[(size_t)row * cD + (k - cH - cE)]);
  }
  ushort4 h, l;
  h.x = f2bf(v.x); h.y = f2bf(v.y); h.z = f2bf(v.z); h.w = f2bf(v.w);
  l.x = f2bf(v.x - bfu(h.x)); l.y = f2bf(v.y - bfu(h.y));
  l.z = f2bf(v.z - bfu(h.z)); l.w = f2bf(v.w - bfu(h.w));
  *reinterpret_cast<ushort4*>(&Ah[(size_t)row * cKr + k]) = h;
  *reinterpret_cast<ushort4*>(&Al[(size_t)row * cKr + k]) = l;
}

// ---------------- MFMA GEMMs ----------------

// enc_ctx = enc_bf @ W_enc_bf^T + b_enc -> bf16 [38400][1024], PAIRED column layout:
// column c stored at position (c<512) ? 2c : 2(c-512)+1  (uint holds {a, a+512})
__global__ __launch_bounds__(256) void mfma_encctx(const unsigned short* __restrict__ A,
                                                   const unsigned short* __restrict__ Bm,
                                                   const float* __restrict__ bias,
                                                   unsigned short* __restrict__ C) {
  __shared__ unsigned short sA[4096], sB[4096];
  constexpr int nbx = cA / 128;
  int bid = xcd_swizzle(blockIdx.x, gridDim.x);
  int by = bid / nbx, bx = bid % nbx;
  int tid = threadIdx.x;
  int w = tid >> 6, l = tid & 63;
  int m0 = by * 128, n0 = bx * 128;
  int wr = w >> 1, wc = w & 1;
  f32x4 acc[4][4] = {};
  int srow = tid >> 2, scol = (tid & 3) * 8;
  for (int k0 = 0; k0 < cD; k0 += 32) {
    __syncthreads();
    GLD(&A[(size_t)(m0 + srow) * cD + k0 + scol], &sA[tid * 8]);
    GLD(&A[(size_t)(m0 + 64 + srow) * cD + k0 + scol], &sA[2048 + tid * 8]);
    GLD(&Bm[(size_t)(n0 + srow) * cD + k0 + scol], &sB[tid * 8]);
    GLD(&Bm[(size_t)(n0 + 64 + srow) * cD + k0 + scol], &sB[2048 + tid * 8]);
    __syncthreads();
    int rA = wr * 64 + (l & 15);
    int rB = wc * 64 + (l & 15);
    int kg = (l >> 4) * 8;
    bf16x8 a[4], b[4];
#pragma unroll
    for (int i = 0; i < 4; ++i) a[i] = *(const bf16x8*)&sA[(rA + i * 16) * 32 + kg];
#pragma unroll
    for (int j = 0; j < 4; ++j) b[j] = *(const bf16x8*)&sB[(rB + j * 16) * 32 + kg];
#pragma unroll
    for (int i = 0; i < 4; ++i)
#pragma unroll
      for (int j = 0; j < 4; ++j)
        acc[i][j] = __builtin_amdgcn_mfma_f32_16x16x32_bf16(a[i], b[j], acc[i][j], 0, 0, 0);
  }
  int rbase = m0 + wr * 64 + ((l >> 4) * 4);
  int cbase = n0 + wc * 64 + (l & 15);
  float bv[4];
#pragma unroll
  for (int j = 0; j < 4; ++j) bv[j] = bias[cbase + j * 16];
#pragma unroll
  for (int i = 0; i < 4; ++i)
#pragma unroll
    for (int q = 0; q < 4; ++q) {
      int row = rbase + i * 16 + q;
#pragma unroll
      for (int j = 0; j < 4; ++j) {
        int col = cbase + j * 16;
        int pos = (col < 512) ? (2 * col) : (2 * (col - 512) + 1);
        C[(size_t)row * cA + pos] = f2bf(acc[i][j][q] + bv[j]);
      }
    }
}

template <int EP>
__global__ __launch_bounds__(256) void mfma_gemm3(
    const unsigned short* __restrict__ Ah, const unsigned short* __restrict__ Al,
    const unsigned short* __restrict__ Bh, const unsigned short* __restrict__ Bl,
    const float* __restrict__ bias, void* __restrict__ outv, int K, int nbx) {
  __shared__ unsigned short sAh[4096], sAl[4096], sBh[4096], sBl[4096];
  int bid = xcd_swizzle(blockIdx.x, gridDim.x);
  int by = bid / nbx, bx = bid % nbx;
  int tid = threadIdx.x;
  int w = tid >> 6, l = tid & 63;
  int m0 = by * 128, n0 = bx * 128;
  int wr = w >> 1, wc = w & 1;
  f32x4 acc[4][4] = {};
  int srow = tid >> 2, scol = (tid & 3) * 8;
  for (int k0 = 0; k0 < K; k0 += 32) {
    __syncthreads();
    GLD(&Ah[(size_t)(m0 + srow) * K + k0 + scol], &sAh[tid * 8]);
    GLD(&Ah[(size_t)(m0 + 64 + srow) * K + k0 + scol], &sAh[2048 + tid * 8]);
    GLD(&Al[(size_t)(m0 + srow) * K + k0 + scol], &sAl[tid * 8]);
    GLD(&Al[(size_t)(m0 + 64 + srow) * K + k0 + scol], &sAl[2048 + tid * 8]);
    GLD(&Bh[(size_t)(n0 + srow) * K + k0 + scol], &sBh[tid * 8]);
    GLD(&Bh[(size_t)(n0 + 64 + srow) * K + k0 + scol], &sBh[2048 + tid * 8]);
    GLD(&Bl[(size_t)(n0 + srow) * K + k0 + scol], &sBl[tid * 8]);
    GLD(&Bl[(size_t)(n0 + 64 + srow) * K + k0 + scol], &sBl[2048 + tid * 8]);
    __syncthreads();
    int rA = wr * 64 + (l & 15);
    int rB = wc * 64 + (l & 15);
    int kg = (l >> 4) * 8;
    bf16x8 bh[4], bl[4];
#pragma unroll
    for (int j = 0; j < 4; ++j) {
      bh[j] = *(const bf16x8*)&sBh[(rB + j * 16) * 32 + kg];
      bl[j] = *(const bf16x8*)&sBl[(rB + j * 16) * 32 + kg];
    }
#pragma unroll
    for (int i = 0; i < 4; ++i) {
      bf16x8 ah = *(const bf16x8*)&sAh[(rA + i * 16) * 32 + kg];
      bf16x8 al = *(const bf16x8*)&sAl[(rA + i * 16) * 32 + kg];
#pragma unroll
      for (int j = 0; j < 4; ++j) {
        acc[i][j] = __builtin_amdgcn_mfma_f32_16x16x32_bf16(ah, bh[j], acc[i][j], 0, 0, 0);
        acc[i][j] = __builtin_amdgcn_mfma_f32_16x16x32_bf16(ah, bl[j], acc[i][j], 0, 0, 0);
        acc[i][j] = __builtin_amdgcn_mfma_f32_16x16x32_bf16(al, bh[j], acc[i][j], 0, 0, 0);
        if (EP == 2)
          acc[i][j] = __builtin_amdgcn_mfma_f32_16x16x32_bf16(al, bl[j], acc[i][j], 0, 0, 0);
      }
    }
  }
  int rbase = m0 + wr * 64 + ((l >> 4) * 4);
  int cbase = n0 + wc * 64 + (l & 15);
  if (EP == 0) {
    unsigned short* mo_h = (unsigned short*)outv;
    unsigned short* mo_l = mo_h + (size_t)cM * (cP / 2);
#pragma unroll
    for (int i = 0; i < 4; ++i)
#pragma unroll
      for (int q = 0; q < 4; ++q) {
        int row = rbase + i * 16 + q;
#pragma unroll
        for (int j = 0; j < 4; ++j) {
          float v = acc[i][j][q] + bias[cbase + j * 16];
          float o = fmaxf(v, __shfl_xor(v, 1));
          if (!(l & 1)) {
            int ch = (cbase + j * 16) >> 1;
            unsigned short h = f2bf(o);
            mo_h[(size_t)row * (cP / 2) + ch] = h;
            mo_l[(size_t)row * (cP / 2) + ch] = f2bf(o - bfu(h));
          }
        }
      }
  } else if (EP == 1) {
    float* out = (float*)outv;
#pragma unroll
    for (int i = 0; i < 4; ++i)
#pragma unroll
      for (int q = 0; q < 4; ++q) {
        int row = rbase + i * 16 + q;
#pragma unroll
        for (int j = 0; j < 4; ++j) {
          int col = cbase + j * 16;
          if (col < cV) out[(size_t)row * cV + col] = acc[i][j][q] + bias[col];
        }
      }
  } else {
    float* out = (float*)outv;  // embg [4096 rows][3072]
#pragma unroll
    for (int i = 0; i < 4; ++i)
#pragma unroll
      for (int q = 0; q < 4; ++q) {
        int row = rbase + i * 16 + q;
#pragma unroll
        for (int j = 0; j < 4; ++j)
          out[(size_t)row * cG3 + cbase + j * 16] = acc[i][j][q];
      }
  }
}

// ---------------- split fused loop: 4 blocks/batch, T-interleaved, 2 rendezvous/step ----------------

struct LoopArgs {
  const unsigned short* enc_ctx;  // bf16 [38400][1024] paired-column layout
  const unsigned short* enc_bf;   // bf16 [38400][512]
  const unsigned short* WihP;     // packed [128][3072][4] bf16 (k-major)
  const unsigned short* WsP;      // packed [256][1024][4] bf16 (k-major)
  const float* b_ih;
  const float* b_hh;
  const float* embg;              // fp32 [4096][3072]
  const float* inv_fert;          // [38400]
  const float* v_att;
  const float* W_fb;
  const int* slen;
  float* s_seq;                   // [4096][1024]
  float* ctx_seq;                 // [4096][512]
  float* xq;                      // [2][64][4][1024] q partials
  float* xc;                      // [2][64][4][516] softmax partials
  unsigned* cnt;                  // [2][64][64] arrival counters (256B stride)
};

__global__ __launch_bounds__(1024, 1) void split_loop(LoopArgs A) {
  __shared__ float ctx_s[cD];
  __shared__ float h_s[256];       // own j-quarter of h
  __shared__ float q_s[cA];
  __shared__ float ew_s[cTQ];
  __shared__ float acc_s[cTQ];
  __shared__ float fert_s[cTQ];
  __shared__ float vatt_s[cA];
  __shared__ float wfb_s[cA];
  __shared__ float cpart[2][cD];
  __shared__ float red_s[16];
  __shared__ float ms_s[8];

  const int xcd = blockIdx.x & 7, idx = blockIdx.x >> 3;
  const int qd = xcd >> 1;                    // quarter 0..3 (same-qd blocks share XCD pair)
  const int b = (xcd & 1) * 32 + idx;         // batch 0..63
  const int tid = threadIdx.x;
  const int wv = tid >> 6, ln = tid & 63;
  const int jl = tid >> 2, part = tid & 3;
  const int q0 = qd * 256;
  const int len = A.slen[b];
  unsigned* cntQ = A.cnt + (0 * cB + b) * 64;
  unsigned* cntS = A.cnt + (1 * cB + b) * 64;

  // init
  if (tid < cD) ctx_s[tid] = 0.f;
  vatt_s[tid] = A.v_att[tid];
  wfb_s[tid] = A.W_fb[tid];
  if (tid < cTQ) {
    acc_s[tid] = 0.f;
    fert_s[tid] = A.inv_fert[b * cT + 4 * tid + qd];
  }
  float h_my = 0.f, bgi = 0.f, bgg = 0.f, bgo = 0.f;
  if (part == 0) {
    int j = q0 + jl;
    bgi = A.b_ih[j] + A.b_hh[j];
    bgg = A.b_ih[j + 2048] + A.b_hh[j + 2048];
    bgo = A.b_ih[j + 3072] + A.b_hh[j + 3072];
  }

  // pin even-i' enc_ctx rows in registers (read-only across all 64 steps)
  unsigned ec[5][8];
#pragma unroll
  for (int ip2 = 0; ip2 < 5; ++ip2) {
    int i = wv + 32 * ip2;                    // i' = 2*ip2, i = wv + 16*i' < 150 always
    const unsigned* rowp =
        (const unsigned*)(A.enc_ctx + (size_t)(b * cT + 4 * i + qd) * cA);
#pragma unroll
    for (int k2 = 0; k2 < 8; ++k2) ec[ip2][k2] = rowp[ln + 64 * k2];
  }
  __syncthreads();

  for (int t = 0; t < cN; ++t) {
    const int par = t & 1;
    const unsigned tgt = 4u * (t + 1);

    // ---- P1: h for j-quarter (4-lane k-split) ----
    {
      float ai = 0.f, ag = 0.f, ao = 0.f;
      const unsigned short* pw = A.WihP + ((size_t)(part * 32) * cG3 + (q0 + jl)) * 4;
#pragma unroll 4
      for (int k4 = 0; k4 < 32; ++k4) {
        float4 c = *reinterpret_cast<const float4*>(&ctx_s[(part * 32 + k4) * 4]);
        ushort4 wi = *reinterpret_cast<const ushort4*>(pw);
        ushort4 wg = *reinterpret_cast<const ushort4*>(pw + (size_t)1024 * 4);
        ushort4 wo = *reinterpret_cast<const ushort4*>(pw + (size_t)2048 * 4);
        ai += bfu(wi.x) * c.x + bfu(wi.y) * c.y + bfu(wi.z) * c.z + bfu(wi.w) * c.w;
        ag += bfu(wg.x) * c.x + bfu(wg.y) * c.y + bfu(wg.z) * c.z + bfu(wg.w) * c.w;
        ao += bfu(wo.x) * c.x + bfu(wo.y) * c.y + bfu(wo.z) * c.z + bfu(wo.w) * c.w;
        pw += (size_t)cG3 * 4;
      }
      ai += __shfl_xor(ai, 1); ai += __shfl_xor(ai, 2);
      ag += __shfl_xor(ag, 1); ag += __shfl_xor(ag, 2);
      ao += __shfl_xor(ao, 1); ao += __shfl_xor(ao, 2);
      if (part == 0) {
        int j = q0 + jl;
        const float* eg = A.embg + (size_t)(b * cN + t) * cG3;
        float gi = ai + bgi + eg[j];
        float gg = ag + bgg + eg[j + 1024];
        float go = ao + bgo + eg[j + 2048];
        float hnew = fsig(go) * ftanh(fsig(gi) * ftanh(gg));
        h_my = 0.05f * h_my + 0.95f * hnew;
        A.s_seq[(size_t)(b * cN + t) * cH + j] = h_my;
        h_s[jl] = h_my;
      }
    }
    __syncthreads();

    // ---- P2: partial q over ALL a from own k-quarter (no h exchange) ----
    {
      float aq = 0.f;
      const unsigned short* pw = A.WsP + ((size_t)(qd * 64) * cA + tid) * 4;
#pragma unroll 8
      for (int kk = 0; kk < 64; ++kk) {
        float4 hh = *reinterpret_cast<const float4*>(&h_s[kk * 4]);
        ushort4 w = *reinterpret_cast<const ushort4*>(pw);
        aq += bfu(w.x) * hh.x + bfu(w.y) * hh.y + bfu(w.z) * hh.z + bfu(w.w) * hh.w;
        pw += (size_t)cA * 4;
      }
      ast(&A.xq[(((size_t)par * cB + b) * 4 + qd) * cA + tid], aq);
    }
    arrive_wait(cntQ, tgt);
    {
      const float* xb = A.xq + ((size_t)par * cB + b) * 4 * cA;
      q_s[tid] = ald(&xb[tid]) + ald(&xb[cA + tid]) + ald(&xb[2 * cA + tid]) +
                 ald(&xb[3 * cA + tid]);
    }
    __syncthreads();

    // ---- P3: energies for interleaved T rows (tt = 4*i + qd) ----
#pragma unroll
    for (int ip = 0; ip < 10; ++ip) {
      int i = wv + 16 * ip;
      if (ip == 9 && i >= cTQ) continue;
      int tt = 4 * i + qd;
      if (tt >= len) {
        if (ln == 0) ew_s[i] = -__builtin_inff();
        continue;
      }
      float fb = acc_s[i];
      float acc = 0.f;
      if ((ip & 1) == 0) {
        const int ip2 = ip >> 1;
#pragma unroll
        for (int k2 = 0; k2 < 8; ++k2) {
          unsigned u = ec[ip2][k2];
          int a0 = ln + 64 * k2;
          float c0 = __uint_as_float(u << 16);
          float c1 = __uint_as_float(u & 0xffff0000u);
          acc += vatt_s[a0] * ftanh(c0 + q_s[a0] + fb * wfb_s[a0]);
          acc += vatt_s[a0 + 512] * ftanh(c1 + q_s[a0 + 512] + fb * wfb_s[a0 + 512]);
        }
      } else {
        const unsigned* rowp =
            (const unsigned*)(A.enc_ctx + (size_t)(b * cT + tt) * cA);
#pragma unroll
        for (int k2 = 0; k2 < 8; ++k2) {
          unsigned u = rowp[ln + 64 * k2];
          int a0 = ln + 64 * k2;
          float c0 = __uint_as_float(u << 16);
          float c1 = __uint_as_float(u & 0xffff0000u);
          acc += vatt_s[a0] * ftanh(c0 + q_s[a0] + fb * wfb_s[a0]);
          acc += vatt_s[a0 + 512] * ftanh(c1 + q_s[a0 + 512] + fb * wfb_s[a0 + 512]);
        }
      }
#pragma unroll
      for (int o = 32; o; o >>= 1) acc += __shfl_xor(acc, o);
      if (ln == 0) ew_s[i] = acc;
    }
    __syncthreads();

    // ---- local softmax over own rows ----
    float m_loc;
    {
      float m = (tid < cTQ) ? ew_s[tid] : -__builtin_inff();
#pragma unroll
      for (int o = 32; o; o >>= 1) m = fmaxf(m, __shfl_xor(m, o));
      if (ln == 0) red_s[wv] = m;
      __syncthreads();
      m = red_s[0];
#pragma unroll
      for (int w2 = 1; w2 < 16; ++w2) m = fmaxf(m, red_s[w2]);
      m_loc = m;
      __syncthreads();
      float wn = 0.f;
      if (tid < cTQ) {
        float e = ew_s[tid];
        if (e > -__builtin_inff()) wn = __expf(e - m_loc);
        ew_s[tid] = wn;
      }
      float sp = wn;
#pragma unroll
      for (int o = 32; o; o >>= 1) sp += __shfl_xor(sp, o);
      if (ln == 0) red_s[wv] = sp;
      __syncthreads();
    }
    float s_loc = red_s[0];
#pragma unroll
    for (int w2 = 1; w2 < 16; ++w2) s_loc += red_s[w2];
    __syncthreads();

    // ---- partial ctx over own rows ----
    {
      int d = (wv & 7) * 64 + ln;
      int half = wv >> 3;
      float s0 = 0.f;
      for (int i2 = 0; i2 < 75; ++i2) {
        int i = half * 75 + i2;
        float wgt = ew_s[i];
        if (wgt != 0.f)
          s0 += wgt * bfu(A.enc_bf[((size_t)b * cT + 4 * i + qd) * cD + d]);
      }
      cpart[half][d] = s0;
    }
    __syncthreads();
    {
      float* xcb = A.xc + (((size_t)par * cB + b) * 4 + qd) * cXCS;
      if (tid < cD) ast(&xcb[2 + tid], cpart[0][tid] + cpart[1][tid]);
      if (tid == 0) ast(&xcb[0], m_loc);
      if (tid == 1) ast(&xcb[1], s_loc);
    }
    arrive_wait(cntS, tgt);

    // ---- combine: M, tot, full ctx; accum update ----
    if (tid < 8) {
      ms_s[tid] =
          ald(&A.xc[(((size_t)par * cB + b) * 4 + (tid >> 1)) * cXCS + (tid & 1)]);
    }
    __syncthreads();
    {
      float M = fmaxf(fmaxf(ms_s[0], ms_s[2]), fmaxf(ms_s[4], ms_s[6]));
      float sc0 = __expf(ms_s[0] - M), sc1 = __expf(ms_s[2] - M);
      float sc2 = __expf(ms_s[4] - M), sc3 = __expf(ms_s[6] - M);
      float tot = ms_s[1] * sc0 + ms_s[3] * sc1 + ms_s[5] * sc2 + ms_s[7] * sc3;
      float invt = 1.0f / tot;
      if (tid < cD) {
        const float* xcb = A.xc + ((size_t)par * cB + b) * 4 * cXCS;
        float cv = ald(&xcb[2 + tid]) * sc0 + ald(&xcb[cXCS + 2 + tid]) * sc1 +
                   ald(&xcb[2 * cXCS + 2 + tid]) * sc2 +
                   ald(&xcb[3 * cXCS + 2 + tid]) * sc3;
        cv *= invt;
        ctx_s[tid] = cv;
        if (qd == 0) A.ctx_seq[(size_t)(b * cN + t) * cD + tid] = cv;
      } else {
        int i = tid - 512;
        if (i < cTQ) {
          float scq = __expf(m_loc - M);
          acc_s[i] += ew_s[i] * scq * invt * fert_s[i] * 0.5f;
        }
      }
    }
    __syncthreads();
  }
}

// ---------------- launcher ----------------

extern "C" void kernel_launch(void* const* d_in, const int* in_sizes, int n_in,
                              void* d_out, int out_size, void* d_ws, size_t ws_size,
                              hipStream_t stream) {
  (void)in_sizes; (void)n_in; (void)out_size; (void)ws_size;
  const float* enc    = (const float*)d_in[0];
  const int*   labels = (const int*)d_in[1];
  const int*   slen   = (const int*)d_in[2];
  const float* embed  = (const float*)d_in[3];
  const float* W_ih   = (const float*)d_in[4];
  const float* b_ih   = (const float*)d_in[5];
  const float* b_hh   = (const float*)d_in[6];
  const float* W_s    = (const float*)d_in[7];
  const float* W_enc  = (const float*)d_in[8];
  const float* b_enc  = (const float*)d_in[9];
  const float* v_att  = (const float*)d_in[10];
  const float* W_fert = (const float*)d_in[11];
  const float* W_fb   = (const float*)d_in[12];
  const float* W_r    = (const float*)d_in[13];
  const float* b_r    = (const float*)d_in[14];
  const float* W_o    = (const float*)d_in[15];
  const float* b_o    = (const float*)d_in[16];
  float* out = (float*)d_out;

  char* ws = (char*)d_ws;
  size_t off = 0;
  auto alloc = [&](size_t bytes) -> char* {
    char* p = ws + off;
    off = (off + bytes + 255) & ~(size_t)255;
    return p;
  };
  unsigned short* enc_ctx = (unsigned short*)alloc((size_t)cBT * cA * 2);
  unsigned short* enc_bf  = (unsigned short*)alloc((size_t)cBT * cD * 2);
  unsigned short* wencb   = (unsigned short*)alloc((size_t)cA * cD * 2);
  float* inv_fert = (float*)alloc((size_t)cBT * 4);
  unsigned short* WihP = (unsigned short*)alloc((size_t)cD * cG3 * 2);
  unsigned short* WsP  = (unsigned short*)alloc((size_t)cH * cA * 2);
  float* embg     = (float*)alloc((size_t)cM * cG3 * 4);
  float* s_seq    = (float*)alloc((size_t)cM * cH * 4);
  float* ctx_seq  = (float*)alloc((size_t)cM * cD * 4);
  float* xq       = (float*)alloc((size_t)2 * cB * 4 * cA * 4);
  float* xc       = (float*)alloc((size_t)2 * cB * 4 * cXCS * 4);
  unsigned* cnt   = (unsigned*)alloc((size_t)2 * cB * 64 * 4);
  unsigned short* Aemb_h = (unsigned short*)alloc((size_t)cM * cE * 2);
  unsigned short* Aemb_l = (unsigned short*)alloc((size_t)cM * cE * 2);
  unsigned short* Wihe_h = (unsigned short*)alloc((size_t)cG3 * cE * 2);
  unsigned short* Wihe_l = (unsigned short*)alloc((size_t)cG3 * cE * 2);
  unsigned short* Ar_h = (unsigned short*)alloc((size_t)cM * cKr * 2);
  unsigned short* Ar_l = (unsigned short*)alloc((size_t)cM * cKr * 2);
  unsigned short* Wr_h = (unsigned short*)alloc((size_t)cP * cKr * 2);
  unsigned short* Wr_l = (unsigned short*)alloc((size_t)cP * cKr * 2);
  unsigned short* mo_hl = (unsigned short*)alloc((size_t)2 * cM * (cP / 2) * 2);
  unsigned short* Wo_h = (unsigned short*)alloc((size_t)cVp * cD * 2);
  unsigned short* Wo_l = (unsigned short*)alloc((size_t)cVp * cD * 2);

  hipMemsetAsync(cnt, 0, (size_t)2 * cB * 64 * 4, stream);

  cast_kernel<<<(cBT * cD) / 1024, 256, 0, stream>>>(enc, enc_bf);
  cast_kernel<<<(cA * cD) / 1024, 256, 0, stream>>>(W_enc, wencb);
  fert_kernel<<<cBT / 4, 256, 0, stream>>>(enc, W_fert, inv_fert);
  mfma_encctx<<<(cBT / 128) * (cA / 128), 256, 0, stream>>>(enc_bf, wencb, b_enc, enc_ctx);
  build_aemb<<<(cM * cE / 4) / 256, 256, 0, stream>>>(embed, labels, Aemb_h, Aemb_l);
  cast_wihe<<<(cG3 * cE / 4) / 256, 256, 0, stream>>>(W_ih, Wihe_h, Wihe_l);
  pack_wih<<<(cG3 * (cD / 4)) / 256, 256, 0, stream>>>(W_ih, WihP);
  pack_ws<<<(cA * (cH / 4)) / 256, 256, 0, stream>>>(W_s, WsP);
  cast_hl_kernel<<<(cP * cKr) / 1024, 256, 0, stream>>>(W_r, Wr_h, Wr_l);
  cast_wo_kernel<<<(cVp * cD) / 1024, 256, 0, stream>>>(W_o, Wo_h, Wo_l);
  mfma_gemm3<2><<<(cM / 128) * (cG3 / 128), 256, 0, stream>>>(
      Aemb_h, Aemb_l, Wihe_h, Wihe_l, nullptr, (void*)embg, cE, cG3 / 128);

  LoopArgs la;
  la.enc_ctx = enc_ctx; la.enc_bf = enc_bf; la.WihP = WihP; la.WsP = WsP;
  la.b_ih = b_ih; la.b_hh = b_hh; la.embg = embg; la.inv_fert = inv_fert;
  la.v_att = v_att; la.W_fb = W_fb; la.slen = slen;
  la.s_seq = s_seq; la.ctx_seq = ctx_seq;
  la.xq = xq; la.xc = xc; la.cnt = cnt;
  split_loop<<<dim3(256), dim3(1024), 0, stream>>>(la);

  build_ar_kernel<<<(cM * cKr) / 1024, 256, 0, stream>>>(s_seq, ctx_seq, embed, labels,
                                                         Ar_h, Ar_l);
  mfma_gemm3<0><<<(cM / 128) * (cP / 128), 256, 0, stream>>>(Ar_h, Ar_l, Wr_h, Wr_l, b_r,
                                                             (void*)mo_hl, cKr, cP / 128);
  unsigned short* mo_h = mo_hl;
  unsigned short* mo_l = mo_hl + (size_t)cM * (cP / 2);
  mfma_gemm3<1><<<(cM / 128) * (cVp / 128), 256, 0, stream>>>(mo_h, mo_l, Wo_h, Wo_l, b_o,
                                                              (void*)out, cP / 2, cVp / 128);
}

// Round 9
// 8104.243 us; speedup vs baseline: 5.2833x; 1.0494x over previous
//
#include <hip/hip_runtime.h>
#include <math.h>

constexpr int cB = 64, cT = 600, cD = 512, cE = 640, cH = 1024, cA = 1024,
              cP = 1024, cV = 10025, cN = 64;
constexpr int cBT = cB * cT;       // 38400
constexpr int cKr = cH + cE + cD;  // 2176
constexpr int cM  = cB * cN;       // 4096
constexpr int cVp = 10112;         // V padded to 79*128
constexpr int cG3 = 3 * cH;        // 3072 (i,g,o)
constexpr int cTQ = cT / 4;        // 150 rows per block (interleaved: tt = 4*i + qd)
constexpr int cXCS = 516;          // xc stride: m, s, c[512], pad

typedef __attribute__((ext_vector_type(8))) short bf16x8;
typedef __attribute__((ext_vector_type(4))) float f32x4;

__device__ __forceinline__ float bfu(unsigned short s) {
  return __uint_as_float(((unsigned int)s) << 16);
}
__device__ __forceinline__ unsigned short f2bf(float f) {
  unsigned int x = __float_as_uint(f);
  x += 0x7fffu + ((x >> 16) & 1u);
  return (unsigned short)(x >> 16);
}
__device__ __forceinline__ float fsig(float x) { return 1.0f / (1.0f + __expf(-x)); }
__device__ __forceinline__ float ftanh(float x) {
  float e = __expf(2.0f * x);
  return 1.0f - 2.0f / (e + 1.0f);
}

#define GLD(g, s)                                                          \
  __builtin_amdgcn_global_load_lds(                                       \
      (const __attribute__((address_space(1))) void*)(g),                 \
      (__attribute__((address_space(3))) void*)(s), 16, 0, 0)

__device__ __forceinline__ int xcd_swizzle(int bid, int nwg) {
  int q = nwg >> 3, r = nwg & 7;
  int x = bid & 7, loc = bid >> 3;
  return (x < r ? x * (q + 1) : r * (q + 1) + (x - r) * q) + loc;
}

// device-scope message passing (round-7-verified pattern)
__device__ __forceinline__ void ast(float* p, float v) {
  __hip_atomic_store(p, v, __ATOMIC_RELAXED, __HIP_MEMORY_SCOPE_AGENT);
}
__device__ __forceinline__ float ald(const float* p) {
  return __hip_atomic_load(p, __ATOMIC_RELAXED, __HIP_MEMORY_SCOPE_AGENT);
}
__device__ __forceinline__ void arrive_wait(unsigned* c, unsigned target) {
  __syncthreads();
  if (threadIdx.x == 0) {
    __hip_atomic_fetch_add(c, 1u, __ATOMIC_RELEASE, __HIP_MEMORY_SCOPE_AGENT);
    while (__hip_atomic_load(c, __ATOMIC_ACQUIRE, __HIP_MEMORY_SCOPE_AGENT) < target)
      __builtin_amdgcn_s_sleep(2);
  }
  __syncthreads();
}

// ---------------- precompute / casts ----------------

__global__ __launch_bounds__(256) void cast_kernel(const float* __restrict__ in,
                                                   unsigned short* __restrict__ out) {
  int i = blockIdx.x * 256 + threadIdx.x;
  float4 v = reinterpret_cast<const float4*>(in)[i];
  ushort4 o;
  o.x = f2bf(v.x); o.y = f2bf(v.y); o.z = f2bf(v.z); o.w = f2bf(v.w);
  reinterpret_cast<ushort4*>(out)[i] = o;
}

__global__ __launch_bounds__(256) void cast_hl_kernel(const float* __restrict__ in,
                                                      unsigned short* __restrict__ hi,
                                                      unsigned short* __restrict__ lo) {
  int i = blockIdx.x * 256 + threadIdx.x;
  float4 v = reinterpret_cast<const float4*>(in)[i];
  ushort4 h, l;
  h.x = f2bf(v.x); h.y = f2bf(v.y); h.z = f2bf(v.z); h.w = f2bf(v.w);
  l.x = f2bf(v.x - bfu(h.x)); l.y = f2bf(v.y - bfu(h.y));
  l.z = f2bf(v.z - bfu(h.z)); l.w = f2bf(v.w - bfu(h.w));
  reinterpret_cast<ushort4*>(hi)[i] = h;
  reinterpret_cast<ushort4*>(lo)[i] = l;
}

__global__ __launch_bounds__(256) void cast_wo_kernel(const float* __restrict__ in,
                                                      unsigned short* __restrict__ hi,
                                                      unsigned short* __restrict__ lo) {
  int idx = blockIdx.x * 256 + threadIdx.x;
  int row = idx >> 7;
  int k = (idx & 127) * 4;
  float4 v = (row < cV) ? *reinterpret_cast<const float4*>(&in[(size_t)row * cD + k])
                        : make_float4(0.f, 0.f, 0.f, 0.f);
  ushort4 h, l;
  h.x = f2bf(v.x); h.y = f2bf(v.y); h.z = f2bf(v.z); h.w = f2bf(v.w);
  l.x = f2bf(v.x - bfu(h.x)); l.y = f2bf(v.y - bfu(h.y));
  l.z = f2bf(v.z - bfu(h.z)); l.w = f2bf(v.w - bfu(h.w));
  reinterpret_cast<ushort4*>(hi)[idx] = h;
  reinterpret_cast<ushort4*>(lo)[idx] = l;
}

__global__ __launch_bounds__(256) void fert_kernel(const float* __restrict__ enc,
                                                   const float* __restrict__ W_fert,
                                                   float* __restrict__ inv_fert) {
  int wave = threadIdx.x >> 6, lane = threadIdx.x & 63;
  int row = blockIdx.x * 4 + wave;
  const float* r = enc + (size_t)row * cD;
  float s = 0.0f;
#pragma unroll
  for (int i = 0; i < 8; ++i) s += r[lane + 64 * i] * W_fert[lane + 64 * i];
#pragma unroll
  for (int o = 32; o; o >>= 1) s += __shfl_xor(s, o);
  if (lane == 0) inv_fert[row] = 1.0f / (1.0f + __expf(-s));
}

// shifted embeddings of labels -> hi/lo bf16 [4096][640]
__global__ __launch_bounds__(256) void build_aemb(const float* __restrict__ embed,
                                                  const int* __restrict__ labels,
                                                  unsigned short* __restrict__ Ah,
                                                  unsigned short* __restrict__ Al) {
  int idx = blockIdx.x * 256 + threadIdx.x;
  int row = idx / (cE / 4);
  int k = (idx % (cE / 4)) * 4;
  int b = row >> 6, tt = row & 63;
  float4 v = make_float4(0.f, 0.f, 0.f, 0.f);
  if (tt > 0) {
    int lab = labels[b * cN + tt - 1];
    v = *reinterpret_cast<const float4*>(&embed[(size_t)lab * cE + k]);
  }
  ushort4 h, l;
  h.x = f2bf(v.x); h.y = f2bf(v.y); h.z = f2bf(v.z); h.w = f2bf(v.w);
  l.x = f2bf(v.x - bfu(h.x)); l.y = f2bf(v.y - bfu(h.y));
  l.z = f2bf(v.z - bfu(h.z)); l.w = f2bf(v.w - bfu(h.w));
  *reinterpret_cast<ushort4*>(&Ah[(size_t)row * cE + k]) = h;
  *reinterpret_cast<ushort4*>(&Al[(size_t)row * cE + k]) = l;
}

// W_ih rows (i,g,o) x cols [0,640) -> hi/lo bf16 [3072][640] (for embg GEMM)
__global__ __launch_bounds__(256) void cast_wihe(const float* __restrict__ W_ih,
                                                 unsigned short* __restrict__ Wh,
                                                 unsigned short* __restrict__ Wl) {
  int idx = blockIdx.x * 256 + threadIdx.x;
  int jcol = idx / (cE / 4);
  int k = (idx % (cE / 4)) * 4;
  int r = (jcol < cH) ? jcol : jcol + cH;
  float4 v = *reinterpret_cast<const float4*>(&W_ih[(size_t)r * (cE + cD) + k]);
  ushort4 h, l;
  h.x = f2bf(v.x); h.y = f2bf(v.y); h.z = f2bf(v.z); h.w = f2bf(v.w);
  l.x = f2bf(v.x - bfu(h.x)); l.y = f2bf(v.y - bfu(h.y));
  l.z = f2bf(v.z - bfu(h.z)); l.w = f2bf(v.w - bfu(h.w));
  *reinterpret_cast<ushort4*>(&Wh[(size_t)jcol * cE + k]) = h;
  *reinterpret_cast<ushort4*>(&Wl[(size_t)jcol * cE + k]) = l;
}

// W_ih ctx-half -> packed k-major bf16: WihP[(k4*3072 + col)*4 + (k&3)]
__global__ __launch_bounds__(256) void pack_wih(const float* __restrict__ W_ih,
                                                unsigned short* __restrict__ WihP) {
  int idx = blockIdx.x * 256 + threadIdx.x;
  int col = idx >> 7;
  int k4 = idx & 127;
  int r = (col < cH) ? col : col + cH;
  float4 v = *reinterpret_cast<const float4*>(&W_ih[(size_t)r * (cE + cD) + cE + k4 * 4]);
  ushort4 h;
  h.x = f2bf(v.x); h.y = f2bf(v.y); h.z = f2bf(v.z); h.w = f2bf(v.w);
  *reinterpret_cast<ushort4*>(&WihP[((size_t)k4 * cG3 + col) * 4]) = h;
}

// W_s -> packed k-major bf16: WsP[(k4*1024 + a)*4 + (k&3)]
__global__ __launch_bounds__(256) void pack_ws(const float* __restrict__ W_s,
                                               unsigned short* __restrict__ WsP) {
  int idx = blockIdx.x * 256 + threadIdx.x;
  int a = idx >> 8;
  int k4 = idx & 255;
  float4 v = *reinterpret_cast<const float4*>(&W_s[(size_t)a * cH + k4 * 4]);
  ushort4 h;
  h.x = f2bf(v.x); h.y = f2bf(v.y); h.z = f2bf(v.z); h.w = f2bf(v.w);
  *reinterpret_cast<ushort4*>(&WsP[((size_t)k4 * cA + a) * 4]) = h;
}

// concat(s_seq, emb, ctx_seq) -> Ar hi/lo bf16 [4096][2176]
__global__ __launch_bounds__(256) void build_ar_kernel(
    const float* __restrict__ s_seq, const float* __restrict__ ctx_seq,
    const float* __restrict__ embed, const int* __restrict__ labels,
    unsigned short* __restrict__ Ah, unsigned short* __restrict__ Al) {
  int idx = blockIdx.x * 256 + threadIdx.x;
  int row = idx / (cKr / 4);
  int k = (idx % (cKr / 4)) * 4;
  int b = row >> 6, tt = row & 63;
  float4 v;
  if (k < cH) {
    v = *reinterpret_cast<const float4*>(&s_seq[(size_t)row * cH + k]);
  } else if (k < cH + cE) {
    if (tt == 0) {
      v = make_float4(0.f, 0.f, 0.f, 0.f);
    } else {
      int lab = labels[b * cN + tt - 1];
      v = *reinterpret_cast<const float4*>(&embed[(size_t)lab * cE + (k - cH)]);
    }
  } else {
    v = *reinterpret_cast<const float4*>(&ctx_seq[(size_t)row * cD + (k - cH - cE)]);
  }
  ushort4 h, l;
  h.x = f2bf(v.x); h.y = f2bf(v.y); h.z = f2bf(v.z); h.w = f2bf(v.w);
  l.x = f2bf(v.x - bfu(h.x)); l.y = f2bf(v.y - bfu(h.y));
  l.z = f2bf(v.z - bfu(h.z)); l.w = f2bf(v.w - bfu(h.w));
  *reinterpret_cast<ushort4*>(&Ah[(size_t)row * cKr + k]) = h;
  *reinterpret_cast<ushort4*>(&Al[(size_t)row * cKr + k]) = l;
}

// ---------------- MFMA GEMMs ----------------

// enc_ctx = enc_bf @ W_enc_bf^T + b_enc -> bf16 [38400][1024], PAIRED column layout:
// column c stored at position (c<512) ? 2c : 2(c-512)+1  (uint holds {a, a+512})
__global__ __launch_bounds__(256) void mfma_encctx(const unsigned short* __restrict__ A,
                                                   const unsigned short* __restrict__ Bm,
                                                   const float* __restrict__ bias,
                                                   unsigned short* __restrict__ C) {
  __shared__ unsigned short sA[4096], sB[4096];
  constexpr int nbx = cA / 128;
  int bid = xcd_swizzle(blockIdx.x, gridDim.x);
  int by = bid / nbx, bx = bid % nbx;
  int tid = threadIdx.x;
  int w = tid >> 6, l = tid & 63;
  int m0 = by * 128, n0 = bx * 128;
  int wr = w >> 1, wc = w & 1;
  f32x4 acc[4][4] = {};
  int srow = tid >> 2, scol = (tid & 3) * 8;
  for (int k0 = 0; k0 < cD; k0 += 32) {
    __syncthreads();
    GLD(&A[(size_t)(m0 + srow) * cD + k0 + scol], &sA[tid * 8]);
    GLD(&A[(size_t)(m0 + 64 + srow) * cD + k0 + scol], &sA[2048 + tid * 8]);
    GLD(&Bm[(size_t)(n0 + srow) * cD + k0 + scol], &sB[tid * 8]);
    GLD(&Bm[(size_t)(n0 + 64 + srow) * cD + k0 + scol], &sB[2048 + tid * 8]);
    __syncthreads();
    int rA = wr * 64 + (l & 15);
    int rB = wc * 64 + (l & 15);
    int kg = (l >> 4) * 8;
    bf16x8 a[4], b[4];
#pragma unroll
    for (int i = 0; i < 4; ++i) a[i] = *(const bf16x8*)&sA[(rA + i * 16) * 32 + kg];
#pragma unroll
    for (int j = 0; j < 4; ++j) b[j] = *(const bf16x8*)&sB[(rB + j * 16) * 32 + kg];
#pragma unroll
    for (int i = 0; i < 4; ++i)
#pragma unroll
      for (int j = 0; j < 4; ++j)
        acc[i][j] = __builtin_amdgcn_mfma_f32_16x16x32_bf16(a[i], b[j], acc[i][j], 0, 0, 0);
  }
  int rbase = m0 + wr * 64 + ((l >> 4) * 4);
  int cbase = n0 + wc * 64 + (l & 15);
  float bv[4];
#pragma unroll
  for (int j = 0; j < 4; ++j) bv[j] = bias[cbase + j * 16];
#pragma unroll
  for (int i = 0; i < 4; ++i)
#pragma unroll
    for (int q = 0; q < 4; ++q) {
      int row = rbase + i * 16 + q;
#pragma unroll
      for (int j = 0; j < 4; ++j) {
        int col = cbase + j * 16;
        int pos = (col < 512) ? (2 * col) : (2 * (col - 512) + 1);
        C[(size_t)row * cA + pos] = f2bf(acc[i][j][q] + bv[j]);
      }
    }
}

template <int EP>
__global__ __launch_bounds__(256) void mfma_gemm3(
    const unsigned short* __restrict__ Ah, const unsigned short* __restrict__ Al,
    const unsigned short* __restrict__ Bh, const unsigned short* __restrict__ Bl,
    const float* __restrict__ bias, void* __restrict__ outv, int K, int nbx) {
  __shared__ unsigned short sAh[4096], sAl[4096], sBh[4096], sBl[4096];
  int bid = xcd_swizzle(blockIdx.x, gridDim.x);
  int by = bid / nbx, bx = bid % nbx;
  int tid = threadIdx.x;
  int w = tid >> 6, l = tid & 63;
  int m0 = by * 128, n0 = bx * 128;
  int wr = w >> 1, wc = w & 1;
  f32x4 acc[4][4] = {};
  int srow = tid >> 2, scol = (tid & 3) * 8;
  for (int k0 = 0; k0 < K; k0 += 32) {
    __syncthreads();
    GLD(&Ah[(size_t)(m0 + srow) * K + k0 + scol], &sAh[tid * 8]);
    GLD(&Ah[(size_t)(m0 + 64 + srow) * K + k0 + scol], &sAh[2048 + tid * 8]);
    GLD(&Al[(size_t)(m0 + srow) * K + k0 + scol], &sAl[tid * 8]);
    GLD(&Al[(size_t)(m0 + 64 + srow) * K + k0 + scol], &sAl[2048 + tid * 8]);
    GLD(&Bh[(size_t)(n0 + srow) * K + k0 + scol], &sBh[tid * 8]);
    GLD(&Bh[(size_t)(n0 + 64 + srow) * K + k0 + scol], &sBh[2048 + tid * 8]);
    GLD(&Bl[(size_t)(n0 + srow) * K + k0 + scol], &sBl[tid * 8]);
    GLD(&Bl[(size_t)(n0 + 64 + srow) * K + k0 + scol], &sBl[2048 + tid * 8]);
    __syncthreads();
    int rA = wr * 64 + (l & 15);
    int rB = wc * 64 + (l & 15);
    int kg = (l >> 4) * 8;
    bf16x8 bh[4], bl[4];
#pragma unroll
    for (int j = 0; j < 4; ++j) {
      bh[j] = *(const bf16x8*)&sBh[(rB + j * 16) * 32 + kg];
      bl[j] = *(const bf16x8*)&sBl[(rB + j * 16) * 32 + kg];
    }
#pragma unroll
    for (int i = 0; i < 4; ++i) {
      bf16x8 ah = *(const bf16x8*)&sAh[(rA + i * 16) * 32 + kg];
      bf16x8 al = *(const bf16x8*)&sAl[(rA + i * 16) * 32 + kg];
#pragma unroll
      for (int j = 0; j < 4; ++j) {
        acc[i][j] = __builtin_amdgcn_mfma_f32_16x16x32_bf16(ah, bh[j], acc[i][j], 0, 0, 0);
        acc[i][j] = __builtin_amdgcn_mfma_f32_16x16x32_bf16(ah, bl[j], acc[i][j], 0, 0, 0);
        acc[i][j] = __builtin_amdgcn_mfma_f32_16x16x32_bf16(al, bh[j], acc[i][j], 0, 0, 0);
        if (EP == 2)
          acc[i][j] = __builtin_amdgcn_mfma_f32_16x16x32_bf16(al, bl[j], acc[i][j], 0, 0, 0);
      }
    }
  }
  int rbase = m0 + wr * 64 + ((l >> 4) * 4);
  int cbase = n0 + wc * 64 + (l & 15);
  if (EP == 0) {
    unsigned short* mo_h = (unsigned short*)outv;
    unsigned short* mo_l = mo_h + (size_t)cM * (cP / 2);
#pragma unroll
    for (int i = 0; i < 4; ++i)
#pragma unroll
      for (int q = 0; q < 4; ++q) {
        int row = rbase + i * 16 + q;
#pragma unroll
        for (int j = 0; j < 4; ++j) {
          float v = acc[i][j][q] + bias[cbase + j * 16];
          float o = fmaxf(v, __shfl_xor(v, 1));
          if (!(l & 1)) {
            int ch = (cbase + j * 16) >> 1;
            unsigned short h = f2bf(o);
            mo_h[(size_t)row * (cP / 2) + ch] = h;
            mo_l[(size_t)row * (cP / 2) + ch] = f2bf(o - bfu(h));
          }
        }
      }
  } else if (EP == 1) {
    float* out = (float*)outv;
#pragma unroll
    for (int i = 0; i < 4; ++i)
#pragma unroll
      for (int q = 0; q < 4; ++q) {
        int row = rbase + i * 16 + q;
#pragma unroll
        for (int j = 0; j < 4; ++j) {
          int col = cbase + j * 16;
          if (col < cV) out[(size_t)row * cV + col] = acc[i][j][q] + bias[col];
        }
      }
  } else {
    float* out = (float*)outv;  // embg [4096 rows][3072]
#pragma unroll
    for (int i = 0; i < 4; ++i)
#pragma unroll
      for (int q = 0; q < 4; ++q) {
        int row = rbase + i * 16 + q;
#pragma unroll
        for (int j = 0; j < 4; ++j)
          out[(size_t)row * cG3 + cbase + j * 16] = acc[i][j][q];
      }
  }
}

// ---------------- split fused loop: 4 blocks/batch, register-pinned streams ----------------

struct LoopArgs {
  const unsigned short* enc_ctx;  // bf16 [38400][1024] paired-column layout
  const unsigned short* enc_bf;   // bf16 [38400][512]
  const unsigned short* WihP;     // packed [128][3072][4] bf16 (k-major)
  const unsigned short* WsP;      // packed [256][1024][4] bf16 (k-major)
  const float* b_ih;
  const float* b_hh;
  const float* embg;              // fp32 [4096][3072]
  const float* inv_fert;          // [38400]
  const float* v_att;
  const float* W_fb;
  const int* slen;
  float* s_seq;                   // [4096][1024]
  float* ctx_seq;                 // [4096][512]
  float* xq;                      // [2][64][4][1024] q partials
  float* xc;                      // [2][64][4][516] softmax partials
  unsigned* cnt;                  // [2][64][64] arrival counters (256B stride)
};

__global__ __launch_bounds__(1024, 1) void split_loop(LoopArgs A) {
  __shared__ float ctx_s[cD];
  __shared__ float h_s[256];       // own j-quarter of h
  __shared__ float q_s[cA];
  __shared__ float ew_s[cTQ + 2];  // padded; pads stay 0
  __shared__ float acc_s[cTQ];
  __shared__ float fert_s[cTQ];
  __shared__ float vatt_s[cA];
  __shared__ float wfb_s[cA];
  __shared__ float cpartL[4][256];
  __shared__ float cpartH[4][256];
  __shared__ float red_s[16];
  __shared__ float ms_s[8];

  const int xcd = blockIdx.x & 7, idx = blockIdx.x >> 3;
  const int qd = xcd >> 1;                    // quarter 0..3
  const int b = (xcd & 1) * 32 + idx;         // batch 0..63
  const int tid = threadIdx.x;
  const int wv = tid >> 6, ln = tid & 63;
  const int jl = tid >> 2, part = tid & 3;
  const int gp = tid >> 8;                    // row-group 0..3 (P4)
  const int pp = tid & 255;                   // d-pair 0..255 (P4)
  const int q0 = qd * 256;
  const int len = A.slen[b];
  unsigned* cntQ = A.cnt + (0 * cB + b) * 64;
  unsigned* cntS = A.cnt + (1 * cB + b) * 64;

  // init
  if (tid < cD) ctx_s[tid] = 0.f;
  vatt_s[tid] = A.v_att[tid];
  wfb_s[tid] = A.W_fb[tid];
  if (tid < cTQ) {
    acc_s[tid] = 0.f;
    fert_s[tid] = A.inv_fert[b * cT + 4 * tid + qd];
  }
  if (tid >= cTQ && tid < cTQ + 2) ew_s[tid] = 0.f;  // pads, never rewritten
  float h_my = 0.f, bgi = 0.f, bgg = 0.f, bgo = 0.f;
  if (part == 0) {
    int j = q0 + jl;
    bgi = A.b_ih[j] + A.b_hh[j];
    bgg = A.b_ih[j + 2048] + A.b_hh[j + 2048];
    bgo = A.b_ih[j + 3072] + A.b_hh[j + 3072];
  }

  // pin enc_ctx rows for ip in {0,2,4,6} (read-only across all 64 steps)
  unsigned ec[4][8];
#pragma unroll
  for (int ip2 = 0; ip2 < 4; ++ip2) {
    int i = wv + 32 * ip2;
    const unsigned* rowp =
        (const unsigned*)(A.enc_ctx + (size_t)(b * cT + 4 * i + qd) * cA);
#pragma unroll
    for (int k2 = 0; k2 < 8; ++k2) ec[ip2][k2] = rowp[ln + 64 * k2];
  }

  // pin the block's entire enc_bf slice: thread (gp,pp) holds rows i ≡ gp (mod 4)
  unsigned ebr[38];
#pragma unroll
  for (int ii = 0; ii < 38; ++ii) {
    int i = gp + 4 * ii;
    ebr[ii] = (i < cTQ)
                  ? ((const unsigned*)(A.enc_bf + ((size_t)b * cT + 4 * i + qd) * cD))[pp]
                  : 0u;
  }
  __syncthreads();

  for (int t = 0; t < cN; ++t) {
    const int par = t & 1;
    const unsigned tgt = 4u * (t + 1);

    // ---- P1: h for j-quarter (4-lane k-split) ----
    {
      float ai = 0.f, ag = 0.f, ao = 0.f;
      const unsigned short* pw = A.WihP + ((size_t)(part * 32) * cG3 + (q0 + jl)) * 4;
#pragma unroll 4
      for (int k4 = 0; k4 < 32; ++k4) {
        float4 c = *reinterpret_cast<const float4*>(&ctx_s[(part * 32 + k4) * 4]);
        ushort4 wi = *reinterpret_cast<const ushort4*>(pw);
        ushort4 wg = *reinterpret_cast<const ushort4*>(pw + (size_t)1024 * 4);
        ushort4 wo = *reinterpret_cast<const ushort4*>(pw + (size_t)2048 * 4);
        ai += bfu(wi.x) * c.x + bfu(wi.y) * c.y + bfu(wi.z) * c.z + bfu(wi.w) * c.w;
        ag += bfu(wg.x) * c.x + bfu(wg.y) * c.y + bfu(wg.z) * c.z + bfu(wg.w) * c.w;
        ao += bfu(wo.x) * c.x + bfu(wo.y) * c.y + bfu(wo.z) * c.z + bfu(wo.w) * c.w;
        pw += (size_t)cG3 * 4;
      }
      ai += __shfl_xor(ai, 1); ai += __shfl_xor(ai, 2);
      ag += __shfl_xor(ag, 1); ag += __shfl_xor(ag, 2);
      ao += __shfl_xor(ao, 1); ao += __shfl_xor(ao, 2);
      if (part == 0) {
        int j = q0 + jl;
        const float* eg = A.embg + (size_t)(b * cN + t) * cG3;
        float gi = ai + bgi + eg[j];
        float gg = ag + bgg + eg[j + 1024];
        float go = ao + bgo + eg[j + 2048];
        float hnew = fsig(go) * ftanh(fsig(gi) * ftanh(gg));
        h_my = 0.05f * h_my + 0.95f * hnew;
        A.s_seq[(size_t)(b * cN + t) * cH + j] = h_my;
        h_s[jl] = h_my;
      }
    }
    __syncthreads();

    // ---- P2: partial q over ALL a from own k-quarter ----
    {
      float aq = 0.f;
      const unsigned short* pw = A.WsP + ((size_t)(qd * 64) * cA + tid) * 4;
#pragma unroll 8
      for (int kk = 0; kk < 64; ++kk) {
        float4 hh = *reinterpret_cast<const float4*>(&h_s[kk * 4]);
        ushort4 w = *reinterpret_cast<const ushort4*>(pw);
        aq += bfu(w.x) * hh.x + bfu(w.y) * hh.y + bfu(w.z) * hh.z + bfu(w.w) * hh.w;
        pw += (size_t)cA * 4;
      }
      ast(&A.xq[(((size_t)par * cB + b) * 4 + qd) * cA + tid], aq);
    }
    arrive_wait(cntQ, tgt);
    {
      const float* xb = A.xq + ((size_t)par * cB + b) * 4 * cA;
      q_s[tid] = ald(&xb[tid]) + ald(&xb[cA + tid]) + ald(&xb[2 * cA + tid]) +
                 ald(&xb[3 * cA + tid]);
    }
    __syncthreads();

    // ---- P3: energies for interleaved T rows (tt = 4*i + qd) ----
#pragma unroll
    for (int ip = 0; ip < 10; ++ip) {
      int i = wv + 16 * ip;
      if (ip == 9 && i >= cTQ) continue;
      int tt = 4 * i + qd;
      if (tt >= len) {
        if (ln == 0) ew_s[i] = -__builtin_inff();
        continue;
      }
      float fb = acc_s[i];
      float acc = 0.f;
      if ((ip & 1) == 0 && ip < 8) {
        const int ip2 = ip >> 1;
#pragma unroll
        for (int k2 = 0; k2 < 8; ++k2) {
          unsigned u = ec[ip2][k2];
          int a0 = ln + 64 * k2;
          float c0 = __uint_as_float(u << 16);
          float c1 = __uint_as_float(u & 0xffff0000u);
          acc += vatt_s[a0] * ftanh(c0 + q_s[a0] + fb * wfb_s[a0]);
          acc += vatt_s[a0 + 512] * ftanh(c1 + q_s[a0 + 512] + fb * wfb_s[a0 + 512]);
        }
      } else {
        const unsigned* rowp =
            (const unsigned*)(A.enc_ctx + (size_t)(b * cT + tt) * cA);
#pragma unroll
        for (int k2 = 0; k2 < 8; ++k2) {
          unsigned u = rowp[ln + 64 * k2];
          int a0 = ln + 64 * k2;
          float c0 = __uint_as_float(u << 16);
          float c1 = __uint_as_float(u & 0xffff0000u);
          acc += vatt_s[a0] * ftanh(c0 + q_s[a0] + fb * wfb_s[a0]);
          acc += vatt_s[a0 + 512] * ftanh(c1 + q_s[a0 + 512] + fb * wfb_s[a0 + 512]);
        }
      }
#pragma unroll
      for (int o = 32; o; o >>= 1) acc += __shfl_xor(acc, o);
      if (ln == 0) ew_s[i] = acc;
    }
    __syncthreads();

    // ---- local softmax over own rows ----
    float m_loc;
    {
      float m = (tid < cTQ) ? ew_s[tid] : -__builtin_inff();
#pragma unroll
      for (int o = 32; o; o >>= 1) m = fmaxf(m, __shfl_xor(m, o));
      if (ln == 0) red_s[wv] = m;
      __syncthreads();
      m = red_s[0];
#pragma unroll
      for (int w2 = 1; w2 < 16; ++w2) m = fmaxf(m, red_s[w2]);
      m_loc = m;
      __syncthreads();
      float wn = 0.f;
      if (tid < cTQ) {
        float e = ew_s[tid];
        if (e > -__builtin_inff()) wn = __expf(e - m_loc);
        ew_s[tid] = wn;
      }
      float sp = wn;
#pragma unroll
      for (int o = 32; o; o >>= 1) sp += __shfl_xor(sp, o);
      if (ln == 0) red_s[wv] = sp;
      __syncthreads();
    }
    float s_loc = red_s[0];
#pragma unroll
    for (int w2 = 1; w2 < 16; ++w2) s_loc += red_s[w2];
    __syncthreads();

    // ---- partial ctx over own rows (register-resident enc_bf, branchless) ----
    {
      float s0 = 0.f, s1 = 0.f;
#pragma unroll
      for (int ii = 0; ii < 38; ++ii) {
        float wgt = ew_s[gp + 4 * ii];     // pads (i>=150) are 0
        unsigned u = ebr[ii];
        s0 += wgt * __uint_as_float(u << 16);
        s1 += wgt * __uint_as_float(u & 0xffff0000u);
      }
      cpartL[gp][pp] = s0;
      cpartH[gp][pp] = s1;
    }
    __syncthreads();
    {
      float* xcb = A.xc + (((size_t)par * cB + b) * 4 + qd) * cXCS;
      if (tid < cD) {
        int p2 = tid >> 1;
        float v = (tid & 1)
                      ? (cpartH[0][p2] + cpartH[1][p2] + cpartH[2][p2] + cpartH[3][p2])
                      : (cpartL[0][p2] + cpartL[1][p2] + cpartL[2][p2] + cpartL[3][p2]);
        ast(&xcb[2 + tid], v);
      }
      if (tid == 0) ast(&xcb[0], m_loc);
      if (tid == 1) ast(&xcb[1], s_loc);
    }
    arrive_wait(cntS, tgt);

    // ---- combine: M, tot, full ctx; accum update ----
    if (tid < 8) {
      ms_s[tid] =
          ald(&A.xc[(((size_t)par * cB + b) * 4 + (tid >> 1)) * cXCS + (tid & 1)]);
    }
    __syncthreads();
    {
      float M = fmaxf(fmaxf(ms_s[0], ms_s[2]), fmaxf(ms_s[4], ms_s[6]));
      float sc0 = __expf(ms_s[0] - M), sc1 = __expf(ms_s[2] - M);
      float sc2 = __expf(ms_s[4] - M), sc3 = __expf(ms_s[6] - M);
      float tot = ms_s[1] * sc0 + ms_s[3] * sc1 + ms_s[5] * sc2 + ms_s[7] * sc3;
      float invt = 1.0f / tot;
      if (tid < cD) {
        const float* xcb = A.xc + ((size_t)par * cB + b) * 4 * cXCS;
        float cv = ald(&xcb[2 + tid]) * sc0 + ald(&xcb[cXCS + 2 + tid]) * sc1 +
                   ald(&xcb[2 * cXCS + 2 + tid]) * sc2 +
                   ald(&xcb[3 * cXCS + 2 + tid]) * sc3;
        cv *= invt;
        ctx_s[tid] = cv;
        if (qd == 0) A.ctx_seq[(size_t)(b * cN + t) * cD + tid] = cv;
      } else {
        int i = tid - 512;
        if (i < cTQ) {
          float scq = __expf(m_loc - M);
          acc_s[i] += ew_s[i] * scq * invt * fert_s[i] * 0.5f;
        }
      }
    }
    __syncthreads();
  }
}

// ---------------- launcher ----------------

extern "C" void kernel_launch(void* const* d_in, const int* in_sizes, int n_in,
                              void* d_out, int out_size, void* d_ws, size_t ws_size,
                              hipStream_t stream) {
  (void)in_sizes; (void)n_in; (void)out_size; (void)ws_size;
  const float* enc    = (const float*)d_in[0];
  const int*   labels = (const int*)d_in[1];
  const int*   slen   = (const int*)d_in[2];
  const float* embed  = (const float*)d_in[3];
  const float* W_ih   = (const float*)d_in[4];
  const float* b_ih   = (const float*)d_in[5];
  const float* b_hh   = (const float*)d_in[6];
  const float* W_s    = (const float*)d_in[7];
  const float* W_enc  = (const float*)d_in[8];
  const float* b_enc  = (const float*)d_in[9];
  const float* v_att  = (const float*)d_in[10];
  const float* W_fert = (const float*)d_in[11];
  const float* W_fb   = (const float*)d_in[12];
  const float* W_r    = (const float*)d_in[13];
  const float* b_r    = (const float*)d_in[14];
  const float* W_o    = (const float*)d_in[15];
  const float* b_o    = (const float*)d_in[16];
  float* out = (float*)d_out;

  char* ws = (char*)d_ws;
  size_t off = 0;
  auto alloc = [&](size_t bytes) -> char* {
    char* p = ws + off;
    off = (off + bytes + 255) & ~(size_t)255;
    return p;
  };
  unsigned short* enc_ctx = (unsigned short*)alloc((size_t)cBT * cA * 2);
  unsigned short* enc_bf  = (unsigned short*)alloc((size_t)cBT * cD * 2);
  unsigned short* wencb   = (unsigned short*)alloc((size_t)cA * cD * 2);
  float* inv_fert = (float*)alloc((size_t)cBT * 4);
  unsigned short* WihP = (unsigned short*)alloc((size_t)cD * cG3 * 2);
  unsigned short* WsP  = (unsigned short*)alloc((size_t)cH * cA * 2);
  float* embg     = (float*)alloc((size_t)cM * cG3 * 4);
  float* s_seq    = (float*)alloc((size_t)cM * cH * 4);
  float* ctx_seq  = (float*)alloc((size_t)cM * cD * 4);
  float* xq       = (float*)alloc((size_t)2 * cB * 4 * cA * 4);
  float* xc       = (float*)alloc((size_t)2 * cB * 4 * cXCS * 4);
  unsigned* cnt   = (unsigned*)alloc((size_t)2 * cB * 64 * 4);
  unsigned short* Aemb_h = (unsigned short*)alloc((size_t)cM * cE * 2);
  unsigned short* Aemb_l = (unsigned short*)alloc((size_t)cM * cE * 2);
  unsigned short* Wihe_h = (unsigned short*)alloc((size_t)cG3 * cE * 2);
  unsigned short* Wihe_l = (unsigned short*)alloc((size_t)cG3 * cE * 2);
  unsigned short* Ar_h = (unsigned short*)alloc((size_t)cM * cKr * 2);
  unsigned short* Ar_l = (unsigned short*)alloc((size_t)cM * cKr * 2);
  unsigned short* Wr_h = (unsigned short*)alloc((size_t)cP * cKr * 2);
  unsigned short* Wr_l = (unsigned short*)alloc((size_t)cP * cKr * 2);
  unsigned short* mo_hl = (unsigned short*)alloc((size_t)2 * cM * (cP / 2) * 2);
  unsigned short* Wo_h = (unsigned short*)alloc((size_t)cVp * cD * 2);
  unsigned short* Wo_l = (unsigned short*)alloc((size_t)cVp * cD * 2);

  hipMemsetAsync(cnt, 0, (size_t)2 * cB * 64 * 4, stream);

  cast_kernel<<<(cBT * cD) / 1024, 256, 0, stream>>>(enc, enc_bf);
  cast_kernel<<<(cA * cD) / 1024, 256, 0, stream>>>(W_enc, wencb);
  fert_kernel<<<cBT / 4, 256, 0, stream>>>(enc, W_fert, inv_fert);
  mfma_encctx<<<(cBT / 128) * (cA / 128), 256, 0, stream>>>(enc_bf, wencb, b_enc, enc_ctx);
  build_aemb<<<(cM * cE / 4) / 256, 256, 0, stream>>>(embed, labels, Aemb_h, Aemb_l);
  cast_wihe<<<(cG3 * cE / 4) / 256, 256, 0, stream>>>(W_ih, Wihe_h, Wihe_l);
  pack_wih<<<(cG3 * (cD / 4)) / 256, 256, 0, stream>>>(W_ih, WihP);
  pack_ws<<<(cA * (cH / 4)) / 256, 256, 0, stream>>>(W_s, WsP);
  cast_hl_kernel<<<(cP * cKr) / 1024, 256, 0, stream>>>(W_r, Wr_h, Wr_l);
  cast_wo_kernel<<<(cVp * cD) / 1024, 256, 0, stream>>>(W_o, Wo_h, Wo_l);
  mfma_gemm3<2><<<(cM / 128) * (cG3 / 128), 256, 0, stream>>>(
      Aemb_h, Aemb_l, Wihe_h, Wihe_l, nullptr, (void*)embg, cE, cG3 / 128);

  LoopArgs la;
  la.enc_ctx = enc_ctx; la.enc_bf = enc_bf; la.WihP = WihP; la.WsP = WsP;
  la.b_ih = b_ih; la.b_hh = b_hh; la.embg = embg; la.inv_fert = inv_fert;
  la.v_att = v_att; la.W_fb = W_fb; la.slen = slen;
  la.s_seq = s_seq; la.ctx_seq = ctx_seq;
  la.xq = xq; la.xc = xc; la.cnt = cnt;
  split_loop<<<dim3(256), dim3(1024), 0, stream>>>(la);

  build_ar_kernel<<<(cM * cKr) / 1024, 256, 0, stream>>>(s_seq, ctx_seq, embed, labels,
                                                         Ar_h, Ar_l);
  mfma_gemm3<0><<<(cM / 128) * (cP / 128), 256, 0, stream>>>(Ar_h, Ar_l, Wr_h, Wr_l, b_r,
                                                             (void*)mo_hl, cKr, cP / 128);
  unsigned short* mo_h = mo_hl;
  unsigned short* mo_l = mo_hl + (size_t)cM * (cP / 2);
  mfma_gemm3<1><<<(cM / 128) * (cVp / 128), 256, 0, stream>>>(mo_h, mo_l, Wo_h, Wo_l, b_o,
                                                              (void*)out, cP / 2, cVp / 128);
}

// Round 10
// 7984.730 us; speedup vs baseline: 5.3624x; 1.0150x over previous
//
#include <hip/hip_runtime.h>
#include <math.h>

constexpr int cB = 64, cT = 600, cD = 512, cE = 640, cH = 1024, cA = 1024,
              cP = 1024, cV = 10025, cN = 64;
constexpr int cBT = cB * cT;       // 38400
constexpr int cKr = cH + cE + cD;  // 2176
constexpr int cM  = cB * cN;       // 4096
constexpr int cVp = 10112;         // V padded to 79*128
constexpr int cG3 = 3 * cH;        // 3072 (i,g,o)
constexpr int cTQ = cT / 4;        // 150 rows per block (interleaved: tt = 4*i + qd)
constexpr int cXCS = 516;          // xc stride: m, s, c[512], pad

typedef __attribute__((ext_vector_type(8))) short bf16x8;
typedef __attribute__((ext_vector_type(4))) float f32x4;

__device__ __forceinline__ float bfu(unsigned short s) {
  return __uint_as_float(((unsigned int)s) << 16);
}
__device__ __forceinline__ unsigned short f2bf(float f) {
  unsigned int x = __float_as_uint(f);
  x += 0x7fffu + ((x >> 16) & 1u);
  return (unsigned short)(x >> 16);
}
__device__ __forceinline__ float fsig(float x) { return 1.0f / (1.0f + __expf(-x)); }
__device__ __forceinline__ float ftanh(float x) {
  float e = __expf(2.0f * x);
  return 1.0f - 2.0f / (e + 1.0f);
}

#define GLD(g, s)                                                          \
  __builtin_amdgcn_global_load_lds(                                       \
      (const __attribute__((address_space(1))) void*)(g),                 \
      (__attribute__((address_space(3))) void*)(s), 16, 0, 0)

__device__ __forceinline__ int xcd_swizzle(int bid, int nwg) {
  int q = nwg >> 3, r = nwg & 7;
  int x = bid & 7, loc = bid >> 3;
  return (x < r ? x * (q + 1) : r * (q + 1) + (x - r) * q) + loc;
}

// device-scope message passing (round-7-verified pattern)
__device__ __forceinline__ void ast(float* p, float v) {
  __hip_atomic_store(p, v, __ATOMIC_RELAXED, __HIP_MEMORY_SCOPE_AGENT);
}
__device__ __forceinline__ float ald(const float* p) {
  return __hip_atomic_load(p, __ATOMIC_RELAXED, __HIP_MEMORY_SCOPE_AGENT);
}
__device__ __forceinline__ void arrive_wait(unsigned* c, unsigned target) {
  __syncthreads();
  if (threadIdx.x == 0) {
    __hip_atomic_fetch_add(c, 1u, __ATOMIC_RELEASE, __HIP_MEMORY_SCOPE_AGENT);
    while (__hip_atomic_load(c, __ATOMIC_ACQUIRE, __HIP_MEMORY_SCOPE_AGENT) < target)
      __builtin_amdgcn_s_sleep(2);
  }
  __syncthreads();
}

// ---------------- precompute / casts ----------------

__global__ __launch_bounds__(256) void cast_kernel(const float* __restrict__ in,
                                                   unsigned short* __restrict__ out) {
  int i = blockIdx.x * 256 + threadIdx.x;
  float4 v = reinterpret_cast<const float4*>(in)[i];
  ushort4 o;
  o.x = f2bf(v.x); o.y = f2bf(v.y); o.z = f2bf(v.z); o.w = f2bf(v.w);
  reinterpret_cast<ushort4*>(out)[i] = o;
}

__global__ __launch_bounds__(256) void cast_hl_kernel(const float* __restrict__ in,
                                                      unsigned short* __restrict__ hi,
                                                      unsigned short* __restrict__ lo) {
  int i = blockIdx.x * 256 + threadIdx.x;
  float4 v = reinterpret_cast<const float4*>(in)[i];
  ushort4 h, l;
  h.x = f2bf(v.x); h.y = f2bf(v.y); h.z = f2bf(v.z); h.w = f2bf(v.w);
  l.x = f2bf(v.x - bfu(h.x)); l.y = f2bf(v.y - bfu(h.y));
  l.z = f2bf(v.z - bfu(h.z)); l.w = f2bf(v.w - bfu(h.w));
  reinterpret_cast<ushort4*>(hi)[i] = h;
  reinterpret_cast<ushort4*>(lo)[i] = l;
}

__global__ __launch_bounds__(256) void cast_wo_kernel(const float* __restrict__ in,
                                                      unsigned short* __restrict__ hi,
                                                      unsigned short* __restrict__ lo) {
  int idx = blockIdx.x * 256 + threadIdx.x;
  int row = idx >> 7;
  int k = (idx & 127) * 4;
  float4 v = (row < cV) ? *reinterpret_cast<const float4*>(&in[(size_t)row * cD + k])
                        : make_float4(0.f, 0.f, 0.f, 0.f);
  ushort4 h, l;
  h.x = f2bf(v.x); h.y = f2bf(v.y); h.z = f2bf(v.z); h.w = f2bf(v.w);
  l.x = f2bf(v.x - bfu(h.x)); l.y = f2bf(v.y - bfu(h.y));
  l.z = f2bf(v.z - bfu(h.z)); l.w = f2bf(v.w - bfu(h.w));
  reinterpret_cast<ushort4*>(hi)[idx] = h;
  reinterpret_cast<ushort4*>(lo)[idx] = l;
}

__global__ __launch_bounds__(256) void fert_kernel(const float* __restrict__ enc,
                                                   const float* __restrict__ W_fert,
                                                   float* __restrict__ inv_fert) {
  int wave = threadIdx.x >> 6, lane = threadIdx.x & 63;
  int row = blockIdx.x * 4 + wave;
  const float* r = enc + (size_t)row * cD;
  float s = 0.0f;
#pragma unroll
  for (int i = 0; i < 8; ++i) s += r[lane + 64 * i] * W_fert[lane + 64 * i];
#pragma unroll
  for (int o = 32; o; o >>= 1) s += __shfl_xor(s, o);
  if (lane == 0) inv_fert[row] = 1.0f / (1.0f + __expf(-s));
}

// shifted embeddings of labels -> hi/lo bf16 [4096][640]
__global__ __launch_bounds__(256) void build_aemb(const float* __restrict__ embed,
                                                  const int* __restrict__ labels,
                                                  unsigned short* __restrict__ Ah,
                                                  unsigned short* __restrict__ Al) {
  int idx = blockIdx.x * 256 + threadIdx.x;
  int row = idx / (cE / 4);
  int k = (idx % (cE / 4)) * 4;
  int b = row >> 6, tt = row & 63;
  float4 v = make_float4(0.f, 0.f, 0.f, 0.f);
  if (tt > 0) {
    int lab = labels[b * cN + tt - 1];
    v = *reinterpret_cast<const float4*>(&embed[(size_t)lab * cE + k]);
  }
  ushort4 h, l;
  h.x = f2bf(v.x); h.y = f2bf(v.y); h.z = f2bf(v.z); h.w = f2bf(v.w);
  l.x = f2bf(v.x - bfu(h.x)); l.y = f2bf(v.y - bfu(h.y));
  l.z = f2bf(v.z - bfu(h.z)); l.w = f2bf(v.w - bfu(h.w));
  *reinterpret_cast<ushort4*>(&Ah[(size_t)row * cE + k]) = h;
  *reinterpret_cast<ushort4*>(&Al[(size_t)row * cE + k]) = l;
}

// W_ih rows (i,g,o) x cols [0,640) -> hi/lo bf16 [3072][640] (for embg GEMM)
__global__ __launch_bounds__(256) void cast_wihe(const float* __restrict__ W_ih,
                                                 unsigned short* __restrict__ Wh,
                                                 unsigned short* __restrict__ Wl) {
  int idx = blockIdx.x * 256 + threadIdx.x;
  int jcol = idx / (cE / 4);
  int k = (idx % (cE / 4)) * 4;
  int r = (jcol < cH) ? jcol : jcol + cH;
  float4 v = *reinterpret_cast<const float4*>(&W_ih[(size_t)r * (cE + cD) + k]);
  ushort4 h, l;
  h.x = f2bf(v.x); h.y = f2bf(v.y); h.z = f2bf(v.z); h.w = f2bf(v.w);
  l.x = f2bf(v.x - bfu(h.x)); l.y = f2bf(v.y - bfu(h.y));
  l.z = f2bf(v.z - bfu(h.z)); l.w = f2bf(v.w - bfu(h.w));
  *reinterpret_cast<ushort4*>(&Wh[(size_t)jcol * cE + k]) = h;
  *reinterpret_cast<ushort4*>(&Wl[(size_t)jcol * cE + k]) = l;
}

// W_ih ctx-half -> packed k-major bf16: WihP[(k4*3072 + col)*4 + (k&3)]
__global__ __launch_bounds__(256) void pack_wih(const float* __restrict__ W_ih,
                                                unsigned short* __restrict__ WihP) {
  int idx = blockIdx.x * 256 + threadIdx.x;
  int col = idx >> 7;
  int k4 = idx & 127;
  int r = (col < cH) ? col : col + cH;
  float4 v = *reinterpret_cast<const float4*>(&W_ih[(size_t)r * (cE + cD) + cE + k4 * 4]);
  ushort4 h;
  h.x = f2bf(v.x); h.y = f2bf(v.y); h.z = f2bf(v.z); h.w = f2bf(v.w);
  *reinterpret_cast<ushort4*>(&WihP[((size_t)k4 * cG3 + col) * 4]) = h;
}

// W_s -> packed k-major bf16: WsP[(k4*1024 + a)*4 + (k&3)]
__global__ __launch_bounds__(256) void pack_ws(const float* __restrict__ W_s,
                                               unsigned short* __restrict__ WsP) {
  int idx = blockIdx.x * 256 + threadIdx.x;
  int a = idx >> 8;
  int k4 = idx & 255;
  float4 v = *reinterpret_cast<const float4*>(&W_s[(size_t)a * cH + k4 * 4]);
  ushort4 h;
  h.x = f2bf(v.x); h.y = f2bf(v.y); h.z = f2bf(v.z); h.w = f2bf(v.w);
  *reinterpret_cast<ushort4*>(&WsP[((size_t)k4 * cA + a) * 4]) = h;
}

// concat(s_seq, emb, ctx_seq) -> Ar hi/lo bf16 [4096][2176]
__global__ __launch_bounds__(256) void build_ar_kernel(
    const float* __restrict__ s_seq, const float* __restrict__ ctx_seq,
    const float* __restrict__ embed, const int* __restrict__ labels,
    unsigned short* __restrict__ Ah, unsigned short* __restrict__ Al) {
  int idx = blockIdx.x * 256 + threadIdx.x;
  int row = idx / (cKr / 4);
  int k = (idx % (cKr / 4)) * 4;
  int b = row >> 6, tt = row & 63;
  float4 v;
  if (k < cH) {
    v = *reinterpret_cast<const float4*>(&s_seq[(size_t)row * cH + k]);
  } else if (k < cH + cE) {
    if (tt == 0) {
      v = make_float4(0.f, 0.f, 0.f, 0.f);
    } else {
      int lab = labels[b * cN + tt - 1];
      v = *reinterpret_cast<const float4*>(&embed[(size_t)lab * cE + (k - cH)]);
    }
  } else {
    v = *reinterpret_cast<const float4*>(&ctx_seq[(size_t)row * cD + (k - cH - cE)]);
  }
  ushort4 h, l;
  h.x = f2bf(v.x); h.y = f2bf(v.y); h.z = f2bf(v.z); h.w = f2bf(v.w);
  l.x = f2bf(v.x - bfu(h.x)); l.y = f2bf(v.y - bfu(h.y));
  l.z = f2bf(v.z - bfu(h.z)); l.w = f2bf(v.w - bfu(h.w));
  *reinterpret_cast<ushort4*>(&Ah[(size_t)row * cKr + k]) = h;
  *reinterpret_cast<ushort4*>(&Al[(size_t)row * cKr + k]) = l;
}

// ---------------- MFMA GEMMs ----------------

// enc_ctx = enc_bf @ W_enc_bf^T + b_enc -> bf16 [38400][1024], PAIRED column layout:
// column c stored at position (c<512) ? 2c : 2(c-512)+1  (uint holds {a, a+512})
__global__ __launch_bounds__(256) void mfma_encctx(const unsigned short* __restrict__ A,
                                                   const unsigned short* __restrict__ Bm,
                                                   const float* __restrict__ bias,
                                                   unsigned short* __restrict__ C) {
  __shared__ unsigned short sA[4096], sB[4096];
  constexpr int nbx = cA / 128;
  int bid = xcd_swizzle(blockIdx.x, gridDim.x);
  int by = bid / nbx, bx = bid % nbx;
  int tid = threadIdx.x;
  int w = tid >> 6, l = tid & 63;
  int m0 = by * 128, n0 = bx * 128;
  int wr = w >> 1, wc = w & 1;
  f32x4 acc[4][4] = {};
  int srow = tid >> 2, scol = (tid & 3) * 8;
  for (int k0 = 0; k0 < cD; k0 += 32) {
    __syncthreads();
    GLD(&A[(size_t)(m0 + srow) * cD + k0 + scol], &sA[tid * 8]);
    GLD(&A[(size_t)(m0 + 64 + srow) * cD + k0 + scol], &sA[2048 + tid * 8]);
    GLD(&Bm[(size_t)(n0 + srow) * cD + k0 + scol], &sB[tid * 8]);
    GLD(&Bm[(size_t)(n0 + 64 + srow) * cD + k0 + scol], &sB[2048 + tid * 8]);
    __syncthreads();
    int rA = wr * 64 + (l & 15);
    int rB = wc * 64 + (l & 15);
    int kg = (l >> 4) * 8;
    bf16x8 a[4], b[4];
#pragma unroll
    for (int i = 0; i < 4; ++i) a[i] = *(const bf16x8*)&sA[(rA + i * 16) * 32 + kg];
#pragma unroll
    for (int j = 0; j < 4; ++j) b[j] = *(const bf16x8*)&sB[(rB + j * 16) * 32 + kg];
#pragma unroll
    for (int i = 0; i < 4; ++i)
#pragma unroll
      for (int j = 0; j < 4; ++j)
        acc[i][j] = __builtin_amdgcn_mfma_f32_16x16x32_bf16(a[i], b[j], acc[i][j], 0, 0, 0);
  }
  int rbase = m0 + wr * 64 + ((l >> 4) * 4);
  int cbase = n0 + wc * 64 + (l & 15);
  float bv[4];
#pragma unroll
  for (int j = 0; j < 4; ++j) bv[j] = bias[cbase + j * 16];
#pragma unroll
  for (int i = 0; i < 4; ++i)
#pragma unroll
    for (int q = 0; q < 4; ++q) {
      int row = rbase + i * 16 + q;
#pragma unroll
      for (int j = 0; j < 4; ++j) {
        int col = cbase + j * 16;
        int pos = (col < 512) ? (2 * col) : (2 * (col - 512) + 1);
        C[(size_t)row * cA + pos] = f2bf(acc[i][j][q] + bv[j]);
      }
    }
}

template <int EP>
__global__ __launch_bounds__(256) void mfma_gemm3(
    const unsigned short* __restrict__ Ah, const unsigned short* __restrict__ Al,
    const unsigned short* __restrict__ Bh, const unsigned short* __restrict__ Bl,
    const float* __restrict__ bias, void* __restrict__ outv, int K, int nbx) {
  __shared__ unsigned short sAh[4096], sAl[4096], sBh[4096], sBl[4096];
  int bid = xcd_swizzle(blockIdx.x, gridDim.x);
  int by = bid / nbx, bx = bid % nbx;
  int tid = threadIdx.x;
  int w = tid >> 6, l = tid & 63;
  int m0 = by * 128, n0 = bx * 128;
  int wr = w >> 1, wc = w & 1;
  f32x4 acc[4][4] = {};
  int srow = tid >> 2, scol = (tid & 3) * 8;
  for (int k0 = 0; k0 < K; k0 += 32) {
    __syncthreads();
    GLD(&Ah[(size_t)(m0 + srow) * K + k0 + scol], &sAh[tid * 8]);
    GLD(&Ah[(size_t)(m0 + 64 + srow) * K + k0 + scol], &sAh[2048 + tid * 8]);
    GLD(&Al[(size_t)(m0 + srow) * K + k0 + scol], &sAl[tid * 8]);
    GLD(&Al[(size_t)(m0 + 64 + srow) * K + k0 + scol], &sAl[2048 + tid * 8]);
    GLD(&Bh[(size_t)(n0 + srow) * K + k0 + scol], &sBh[tid * 8]);
    GLD(&Bh[(size_t)(n0 + 64 + srow) * K + k0 + scol], &sBh[2048 + tid * 8]);
    GLD(&Bl[(size_t)(n0 + srow) * K + k0 + scol], &sBl[tid * 8]);
    GLD(&Bl[(size_t)(n0 + 64 + srow) * K + k0 + scol], &sBl[2048 + tid * 8]);
    __syncthreads();
    int rA = wr * 64 + (l & 15);
    int rB = wc * 64 + (l & 15);
    int kg = (l >> 4) * 8;
    bf16x8 bh[4], bl[4];
#pragma unroll
    for (int j = 0; j < 4; ++j) {
      bh[j] = *(const bf16x8*)&sBh[(rB + j * 16) * 32 + kg];
      bl[j] = *(const bf16x8*)&sBl[(rB + j * 16) * 32 + kg];
    }
#pragma unroll
    for (int i = 0; i < 4; ++i) {
      bf16x8 ah = *(const bf16x8*)&sAh[(rA + i * 16) * 32 + kg];
      bf16x8 al = *(const bf16x8*)&sAl[(rA + i * 16) * 32 + kg];
#pragma unroll
      for (int j = 0; j < 4; ++j) {
        acc[i][j] = __builtin_amdgcn_mfma_f32_16x16x32_bf16(ah, bh[j], acc[i][j], 0, 0, 0);
        acc[i][j] = __builtin_amdgcn_mfma_f32_16x16x32_bf16(ah, bl[j], acc[i][j], 0, 0, 0);
        acc[i][j] = __builtin_amdgcn_mfma_f32_16x16x32_bf16(al, bh[j], acc[i][j], 0, 0, 0);
        if (EP == 2)
          acc[i][j] = __builtin_amdgcn_mfma_f32_16x16x32_bf16(al, bl[j], acc[i][j], 0, 0, 0);
      }
    }
  }
  int rbase = m0 + wr * 64 + ((l >> 4) * 4);
  int cbase = n0 + wc * 64 + (l & 15);
  if (EP == 0) {
    unsigned short* mo_h = (unsigned short*)outv;
    unsigned short* mo_l = mo_h + (size_t)cM * (cP / 2);
#pragma unroll
    for (int i = 0; i < 4; ++i)
#pragma unroll
      for (int q = 0; q < 4; ++q) {
        int row = rbase + i * 16 + q;
#pragma unroll
        for (int j = 0; j < 4; ++j) {
          float v = acc[i][j][q] + bias[cbase + j * 16];
          float o = fmaxf(v, __shfl_xor(v, 1));
          if (!(l & 1)) {
            int ch = (cbase + j * 16) >> 1;
            unsigned short h = f2bf(o);
            mo_h[(size_t)row * (cP / 2) + ch] = h;
            mo_l[(size_t)row * (cP / 2) + ch] = f2bf(o - bfu(h));
          }
        }
      }
  } else if (EP == 1) {
    float* out = (float*)outv;
#pragma unroll
    for (int i = 0; i < 4; ++i)
#pragma unroll
      for (int q = 0; q < 4; ++q) {
        int row = rbase + i * 16 + q;
#pragma unroll
        for (int j = 0; j < 4; ++j) {
          int col = cbase + j * 16;
          if (col < cV) out[(size_t)row * cV + col] = acc[i][j][q] + bias[col];
        }
      }
  } else {
    float* out = (float*)outv;  // embg [4096 rows][3072]
#pragma unroll
    for (int i = 0; i < 4; ++i)
#pragma unroll
      for (int q = 0; q < 4; ++q) {
        int row = rbase + i * 16 + q;
#pragma unroll
        for (int j = 0; j < 4; ++j)
          out[(size_t)row * cG3 + cbase + j * 16] = acc[i][j][q];
      }
  }
}

// ---------------- split fused loop: 4 blocks/batch, register-pinned streams ----------------

struct LoopArgs {
  const unsigned short* enc_ctx;  // bf16 [38400][1024] paired-column layout
  const unsigned short* enc_bf;   // bf16 [38400][512]
  const unsigned short* WihP;     // packed [128][3072][4] bf16 (k-major)
  const unsigned short* WsP;      // packed [256][1024][4] bf16 (k-major)
  const float* b_ih;
  const float* b_hh;
  const float* embg;              // fp32 [4096][3072]
  const float* inv_fert;          // [38400]
  const float* v_att;
  const float* W_fb;
  const int* slen;
  float* s_seq;                   // [4096][1024]
  float* ctx_seq;                 // [4096][512]
  float* xq;                      // [2][64][4][1024] q partials
  float* xc;                      // [2][64][4][516] softmax partials
  unsigned* cnt;                  // [2][64][64] arrival counters (256B stride)
};

__global__ __launch_bounds__(1024)
__attribute__((amdgpu_waves_per_eu(4, 4)))  // 4 waves/SIMD target -> 128-VGPR budget, no spill
void split_loop(LoopArgs A) {
  __shared__ float ctx_s[cD];
  __shared__ float h_s[256];       // own j-quarter of h
  __shared__ float q_s[cA];
  __shared__ float ew_s[cTQ + 2];  // padded; pads stay 0
  __shared__ float acc_s[cTQ];
  __shared__ float fert_s[cTQ];
  __shared__ float vatt_s[cA];
  __shared__ float wfb_s[cA];
  __shared__ float cpartL[4][256];
  __shared__ float cpartH[4][256];
  __shared__ float red_s[16];
  __shared__ float ms_s[8];

  const int xcd = blockIdx.x & 7, idx = blockIdx.x >> 3;
  const int qd = xcd >> 1;                    // quarter 0..3
  const int b = (xcd & 1) * 32 + idx;         // batch 0..63
  const int tid = threadIdx.x;
  const int wv = tid >> 6, ln = tid & 63;
  const int jl = tid >> 2, part = tid & 3;
  const int gp = tid >> 8;                    // row-group 0..3 (P4)
  const int pp = tid & 255;                   // d-pair 0..255 (P4)
  const int q0 = qd * 256;
  const int len = A.slen[b];
  unsigned* cntQ = A.cnt + (0 * cB + b) * 64;
  unsigned* cntS = A.cnt + (1 * cB + b) * 64;

  // init
  if (tid < cD) ctx_s[tid] = 0.f;
  vatt_s[tid] = A.v_att[tid];
  wfb_s[tid] = A.W_fb[tid];
  if (tid < cTQ) {
    acc_s[tid] = 0.f;
    fert_s[tid] = A.inv_fert[b * cT + 4 * tid + qd];
  }
  if (tid >= cTQ && tid < cTQ + 2) ew_s[tid] = 0.f;  // pads, never rewritten
  float h_my = 0.f, bgi = 0.f, bgg = 0.f, bgo = 0.f;
  if (part == 0) {
    int j = q0 + jl;
    bgi = A.b_ih[j] + A.b_hh[j];
    bgg = A.b_ih[j + 2048] + A.b_hh[j + 2048];
    bgo = A.b_ih[j + 3072] + A.b_hh[j + 3072];
  }

  // pin enc_ctx rows for ip in {0,2,4,6} (read-only across all 64 steps)
  unsigned ec[4][8];
#pragma unroll
  for (int ip2 = 0; ip2 < 4; ++ip2) {
    int i = wv + 32 * ip2;
    const unsigned* rowp =
        (const unsigned*)(A.enc_ctx + (size_t)(b * cT + 4 * i + qd) * cA);
#pragma unroll
    for (int k2 = 0; k2 < 8; ++k2) ec[ip2][k2] = rowp[ln + 64 * k2];
  }

  // pin the block's entire enc_bf slice: thread (gp,pp) holds rows i ≡ gp (mod 4)
  unsigned ebr[38];
#pragma unroll
  for (int ii = 0; ii < 38; ++ii) {
    int i = gp + 4 * ii;
    ebr[ii] = (i < cTQ)
                  ? ((const unsigned*)(A.enc_bf + ((size_t)b * cT + 4 * i + qd) * cD))[pp]
                  : 0u;
  }
  __syncthreads();

  for (int t = 0; t < cN; ++t) {
    const int par = t & 1;
    const unsigned tgt = 4u * (t + 1);

    // ---- P1: h for j-quarter (4-lane k-split; bank-staggered ctx reads) ----
    {
      float ai = 0.f, ag = 0.f, ao = 0.f;
      const unsigned short* wbase = A.WihP + (size_t)(q0 + jl) * 4;
#pragma unroll 4
      for (int k4 = 0; k4 < 32; ++k4) {
        int kk = (k4 + 2 * part) & 31;           // bank offsets 0/8/16/24 per part
        int row = part * 32 + kk;
        float4 c = *reinterpret_cast<const float4*>(&ctx_s[row * 4]);
        const unsigned short* pw = wbase + (size_t)row * (cG3 * 4);
        ushort4 wi = *reinterpret_cast<const ushort4*>(pw);
        ushort4 wg = *reinterpret_cast<const ushort4*>(pw + (size_t)1024 * 4);
        ushort4 wo = *reinterpret_cast<const ushort4*>(pw + (size_t)2048 * 4);
        ai += bfu(wi.x) * c.x + bfu(wi.y) * c.y + bfu(wi.z) * c.z + bfu(wi.w) * c.w;
        ag += bfu(wg.x) * c.x + bfu(wg.y) * c.y + bfu(wg.z) * c.z + bfu(wg.w) * c.w;
        ao += bfu(wo.x) * c.x + bfu(wo.y) * c.y + bfu(wo.z) * c.z + bfu(wo.w) * c.w;
      }
      ai += __shfl_xor(ai, 1); ai += __shfl_xor(ai, 2);
      ag += __shfl_xor(ag, 1); ag += __shfl_xor(ag, 2);
      ao += __shfl_xor(ao, 1); ao += __shfl_xor(ao, 2);
      if (part == 0) {
        int j = q0 + jl;
        const float* eg = A.embg + (size_t)(b * cN + t) * cG3;
        float gi = ai + bgi + eg[j];
        float gg = ag + bgg + eg[j + 1024];
        float go = ao + bgo + eg[j + 2048];
        float hnew = fsig(go) * ftanh(fsig(gi) * ftanh(gg));
        h_my = 0.05f * h_my + 0.95f * hnew;
        A.s_seq[(size_t)(b * cN + t) * cH + j] = h_my;
        h_s[jl] = h_my;
      }
    }
    __syncthreads();

    // ---- P2: partial q over ALL a from own k-quarter ----
    {
      float aq = 0.f;
      const unsigned short* pw = A.WsP + ((size_t)(qd * 64) * cA + tid) * 4;
#pragma unroll 8
      for (int kk = 0; kk < 64; ++kk) {
        float4 hh = *reinterpret_cast<const float4*>(&h_s[kk * 4]);
        ushort4 w = *reinterpret_cast<const ushort4*>(pw);
        aq += bfu(w.x) * hh.x + bfu(w.y) * hh.y + bfu(w.z) * hh.z + bfu(w.w) * hh.w;
        pw += (size_t)cA * 4;
      }
      ast(&A.xq[(((size_t)par * cB + b) * 4 + qd) * cA + tid], aq);
    }
    arrive_wait(cntQ, tgt);
    {
      const float* xb = A.xq + ((size_t)par * cB + b) * 4 * cA;
      q_s[tid] = ald(&xb[tid]) + ald(&xb[cA + tid]) + ald(&xb[2 * cA + tid]) +
                 ald(&xb[3 * cA + tid]);
    }
    __syncthreads();

    // ---- P3: energies for interleaved T rows (tt = 4*i + qd) ----
#pragma unroll
    for (int ip = 0; ip < 10; ++ip) {
      int i = wv + 16 * ip;
      if (ip == 9 && i >= cTQ) continue;
      int tt = 4 * i + qd;
      if (tt >= len) {
        if (ln == 0) ew_s[i] = -__builtin_inff();
        continue;
      }
      float fb = acc_s[i];
      float acc = 0.f;
      if ((ip & 1) == 0 && ip < 8) {
        const int ip2 = ip >> 1;
#pragma unroll
        for (int k2 = 0; k2 < 8; ++k2) {
          unsigned u = ec[ip2][k2];
          int a0 = ln + 64 * k2;
          float c0 = __uint_as_float(u << 16);
          float c1 = __uint_as_float(u & 0xffff0000u);
          acc += vatt_s[a0] * ftanh(c0 + q_s[a0] + fb * wfb_s[a0]);
          acc += vatt_s[a0 + 512] * ftanh(c1 + q_s[a0 + 512] + fb * wfb_s[a0 + 512]);
        }
      } else {
        const unsigned* rowp =
            (const unsigned*)(A.enc_ctx + (size_t)(b * cT + tt) * cA);
#pragma unroll
        for (int k2 = 0; k2 < 8; ++k2) {
          unsigned u = rowp[ln + 64 * k2];
          int a0 = ln + 64 * k2;
          float c0 = __uint_as_float(u << 16);
          float c1 = __uint_as_float(u & 0xffff0000u);
          acc += vatt_s[a0] * ftanh(c0 + q_s[a0] + fb * wfb_s[a0]);
          acc += vatt_s[a0 + 512] * ftanh(c1 + q_s[a0 + 512] + fb * wfb_s[a0 + 512]);
        }
      }
#pragma unroll
      for (int o = 32; o; o >>= 1) acc += __shfl_xor(acc, o);
      if (ln == 0) ew_s[i] = acc;
    }
    __syncthreads();

    // ---- local softmax over own rows ----
    float m_loc;
    {
      float m = (tid < cTQ) ? ew_s[tid] : -__builtin_inff();
#pragma unroll
      for (int o = 32; o; o >>= 1) m = fmaxf(m, __shfl_xor(m, o));
      if (ln == 0) red_s[wv] = m;
      __syncthreads();
      m = red_s[0];
#pragma unroll
      for (int w2 = 1; w2 < 16; ++w2) m = fmaxf(m, red_s[w2]);
      m_loc = m;
      __syncthreads();
      float wn = 0.f;
      if (tid < cTQ) {
        float e = ew_s[tid];
        if (e > -__builtin_inff()) wn = __expf(e - m_loc);
        ew_s[tid] = wn;
      }
      float sp = wn;
#pragma unroll
      for (int o = 32; o; o >>= 1) sp += __shfl_xor(sp, o);
      if (ln == 0) red_s[wv] = sp;
      __syncthreads();
    }
    float s_loc = red_s[0];
#pragma unroll
    for (int w2 = 1; w2 < 16; ++w2) s_loc += red_s[w2];
    __syncthreads();

    // ---- partial ctx over own rows (register-resident enc_bf, branchless) ----
    {
      float s0 = 0.f, s1 = 0.f;
#pragma unroll
      for (int ii = 0; ii < 38; ++ii) {
        float wgt = ew_s[gp + 4 * ii];     // pads (i>=150) are 0
        unsigned u = ebr[ii];
        s0 += wgt * __uint_as_float(u << 16);
        s1 += wgt * __uint_as_float(u & 0xffff0000u);
      }
      cpartL[gp][pp] = s0;
      cpartH[gp][pp] = s1;
    }
    __syncthreads();
    {
      float* xcb = A.xc + (((size_t)par * cB + b) * 4 + qd) * cXCS;
      if (tid < cD) {
        int p2 = tid >> 1;
        float v = (tid & 1)
                      ? (cpartH[0][p2] + cpartH[1][p2] + cpartH[2][p2] + cpartH[3][p2])
                      : (cpartL[0][p2] + cpartL[1][p2] + cpartL[2][p2] + cpartL[3][p2]);
        ast(&xcb[2 + tid], v);
      }
      if (tid == 0) ast(&xcb[0], m_loc);
      if (tid == 1) ast(&xcb[1], s_loc);
    }
    arrive_wait(cntS, tgt);

    // ---- combine: M, tot, full ctx; accum update ----
    if (tid < 8) {
      ms_s[tid] =
          ald(&A.xc[(((size_t)par * cB + b) * 4 + (tid >> 1)) * cXCS + (tid & 1)]);
    }
    __syncthreads();
    {
      float M = fmaxf(fmaxf(ms_s[0], ms_s[2]), fmaxf(ms_s[4], ms_s[6]));
      float sc0 = __expf(ms_s[0] - M), sc1 = __expf(ms_s[2] - M);
      float sc2 = __expf(ms_s[4] - M), sc3 = __expf(ms_s[6] - M);
      float tot = ms_s[1] * sc0 + ms_s[3] * sc1 + ms_s[5] * sc2 + ms_s[7] * sc3;
      float invt = 1.0f / tot;
      if (tid < cD) {
        const float* xcb = A.xc + ((size_t)par * cB + b) * 4 * cXCS;
        float cv = ald(&xcb[2 + tid]) * sc0 + ald(&xcb[cXCS + 2 + tid]) * sc1 +
                   ald(&xcb[2 * cXCS + 2 + tid]) * sc2 +
                   ald(&xcb[3 * cXCS + 2 + tid]) * sc3;
        cv *= invt;
        ctx_s[tid] = cv;
        if (qd == 0) A.ctx_seq[(size_t)(b * cN + t) * cD + tid] = cv;
      } else {
        int i = tid - 512;
        if (i < cTQ) {
          float scq = __expf(m_loc - M);
          acc_s[i] += ew_s[i] * scq * invt * fert_s[i] * 0.5f;
        }
      }
    }
    __syncthreads();
  }
}

// ---------------- launcher ----------------

extern "C" void kernel_launch(void* const* d_in, const int* in_sizes, int n_in,
                              void* d_out, int out_size, void* d_ws, size_t ws_size,
                              hipStream_t stream) {
  (void)in_sizes; (void)n_in; (void)out_size; (void)ws_size;
  const float* enc    = (const float*)d_in[0];
  const int*   labels = (const int*)d_in[1];
  const int*   slen   = (const int*)d_in[2];
  const float* embed  = (const float*)d_in[3];
  const float* W_ih   = (const float*)d_in[4];
  const float* b_ih   = (const float*)d_in[5];
  const float* b_hh   = (const float*)d_in[6];
  const float* W_s    = (const float*)d_in[7];
  const float* W_enc  = (const float*)d_in[8];
  const float* b_enc  = (const float*)d_in[9];
  const float* v_att  = (const float*)d_in[10];
  const float* W_fert = (const float*)d_in[11];
  const float* W_fb   = (const float*)d_in[12];
  const float* W_r    = (const float*)d_in[13];
  const float* b_r    = (const float*)d_in[14];
  const float* W_o    = (const float*)d_in[15];
  const float* b_o    = (const float*)d_in[16];
  float* out = (float*)d_out;

  char* ws = (char*)d_ws;
  size_t off = 0;
  auto alloc = [&](size_t bytes) -> char* {
    char* p = ws + off;
    off = (off + bytes + 255) & ~(size_t)255;
    return p;
  };
  unsigned short* enc_ctx = (unsigned short*)alloc((size_t)cBT * cA * 2);
  unsigned short* enc_bf  = (unsigned short*)alloc((size_t)cBT * cD * 2);
  unsigned short* wencb   = (unsigned short*)alloc((size_t)cA * cD * 2);
  float* inv_fert = (float*)alloc((size_t)cBT * 4);
  unsigned short* WihP = (unsigned short*)alloc((size_t)cD * cG3 * 2);
  unsigned short* WsP  = (unsigned short*)alloc((size_t)cH * cA * 2);
  float* embg     = (float*)alloc((size_t)cM * cG3 * 4);
  float* s_seq    = (float*)alloc((size_t)cM * cH * 4);
  float* ctx_seq  = (float*)alloc((size_t)cM * cD * 4);
  float* xq       = (float*)alloc((size_t)2 * cB * 4 * cA * 4);
  float* xc       = (float*)alloc((size_t)2 * cB * 4 * cXCS * 4);
  unsigned* cnt   = (unsigned*)alloc((size_t)2 * cB * 64 * 4);
  unsigned short* Aemb_h = (unsigned short*)alloc((size_t)cM * cE * 2);
  unsigned short* Aemb_l = (unsigned short*)alloc((size_t)cM * cE * 2);
  unsigned short* Wihe_h = (unsigned short*)alloc((size_t)cG3 * cE * 2);
  unsigned short* Wihe_l = (unsigned short*)alloc((size_t)cG3 * cE * 2);
  unsigned short* Ar_h = (unsigned short*)alloc((size_t)cM * cKr * 2);
  unsigned short* Ar_l = (unsigned short*)alloc((size_t)cM * cKr * 2);
  unsigned short* Wr_h = (unsigned short*)alloc((size_t)cP * cKr * 2);
  unsigned short* Wr_l = (unsigned short*)alloc((size_t)cP * cKr * 2);
  unsigned short* mo_hl = (unsigned short*)alloc((size_t)2 * cM * (cP / 2) * 2);
  unsigned short* Wo_h = (unsigned short*)alloc((size_t)cVp * cD * 2);
  unsigned short* Wo_l = (unsigned short*)alloc((size_t)cVp * cD * 2);

  hipMemsetAsync(cnt, 0, (size_t)2 * cB * 64 * 4, stream);

  cast_kernel<<<(cBT * cD) / 1024, 256, 0, stream>>>(enc, enc_bf);
  cast_kernel<<<(cA * cD) / 1024, 256, 0, stream>>>(W_enc, wencb);
  fert_kernel<<<cBT / 4, 256, 0, stream>>>(enc, W_fert, inv_fert);
  mfma_encctx<<<(cBT / 128) * (cA / 128), 256, 0, stream>>>(enc_bf, wencb, b_enc, enc_ctx);
  build_aemb<<<(cM * cE / 4) / 256, 256, 0, stream>>>(embed, labels, Aemb_h, Aemb_l);
  cast_wihe<<<(cG3 * cE / 4) / 256, 256, 0, stream>>>(W_ih, Wihe_h, Wihe_l);
  pack_wih<<<(cG3 * (cD / 4)) / 256, 256, 0, stream>>>(W_ih, WihP);
  pack_ws<<<(cA * (cH / 4)) / 256, 256, 0, stream>>>(W_s, WsP);
  cast_hl_kernel<<<(cP * cKr) / 1024, 256, 0, stream>>>(W_r, Wr_h, Wr_l);
  cast_wo_kernel<<<(cVp * cD) / 1024, 256, 0, stream>>>(W_o, Wo_h, Wo_l);
  mfma_gemm3<2><<<(cM / 128) * (cG3 / 128), 256, 0, stream>>>(
      Aemb_h, Aemb_l, Wihe_h, Wihe_l, nullptr, (void*)embg, cE, cG3 / 128);

  LoopArgs la;
  la.enc_ctx = enc_ctx; la.enc_bf = enc_bf; la.WihP = WihP; la.WsP = WsP;
  la.b_ih = b_ih; la.b_hh = b_hh; la.embg = embg; la.inv_fert = inv_fert;
  la.v_att = v_att; la.W_fb = W_fb; la.slen = slen;
  la.s_seq = s_seq; la.ctx_seq = ctx_seq;
  la.xq = xq; la.xc = xc; la.cnt = cnt;
  split_loop<<<dim3(256), dim3(1024), 0, stream>>>(la);

  build_ar_kernel<<<(cM * cKr) / 1024, 256, 0, stream>>>(s_seq, ctx_seq, embed, labels,
                                                         Ar_h, Ar_l);
  mfma_gemm3<0><<<(cM / 128) * (cP / 128), 256, 0, stream>>>(Ar_h, Ar_l, Wr_h, Wr_l, b_r,
                                                             (void*)mo_hl, cKr, cP / 128);
  unsigned short* mo_h = mo_hl;
  unsigned short* mo_l = mo_hl + (size_t)cM * (cP / 2);
  mfma_gemm3<1><<<(cM / 128) * (cVp / 128), 256, 0, stream>>>(mo_h, mo_l, Wo_h, Wo_l, b_o,
                                                              (void*)out, cP / 2, cVp / 128);
}